// Round 5
// baseline (818.010 us; speedup 1.0000x reference)
//
#include <hip/hip_runtime.h>
#include <hip/hip_bf16.h>
#include <stdint.h>

typedef unsigned short ushort_t;
typedef __attribute__((ext_vector_type(8))) short short8;
typedef __attribute__((ext_vector_type(4))) short short4v;
typedef __attribute__((ext_vector_type(4))) float f32x4;
typedef __attribute__((ext_vector_type(4))) int int4v;

#define N_NODES 20000
#define N_EDGES 320000
#define D 128
#define XSTRIDE 136   // padded LDS row stride (ushorts)

#define GAS __attribute__((address_space(1)))
#define LAS __attribute__((address_space(3)))

__device__ __forceinline__ float b2f(ushort_t u) {
    union { float f; uint32_t i; } v; v.i = ((uint32_t)u) << 16; return v.f;
}
__device__ __forceinline__ ushort_t f2b(float f) {
    union { float f; uint32_t i; } v; v.f = f;
    uint32_t r = v.i + 0x7FFFu + ((v.i >> 16) & 1u);
    return (ushort_t)(r >> 16);
}
// dtype-flexible scalar load: raw input arrays may be f32 or bf16 (runtime-detected)
__device__ __forceinline__ float ldf(const void* p, size_t i, bool f32) {
    return f32 ? ((const float*)p)[i] : b2f(((const ushort_t*)p)[i]);
}
// dtype-flexible 8-element A-fragment load (8 consecutive elements, 8-aligned index)
__device__ __forceinline__ short8 lda8(const void* p, size_t i, bool f32) {
    if (f32) {
        const float* fp = (const float*)p + i;
        f32x4 v0 = *(const f32x4*)fp;
        f32x4 v1 = *(const f32x4*)(fp + 4);
        short8 a;
#pragma unroll
        for (int j = 0; j < 4; ++j) {
            a[j]     = (short)f2b(v0[j]);
            a[j + 4] = (short)f2b(v1[j]);
        }
        return a;
    }
    return *(const short8*)((const ushort_t*)p + i);
}
__device__ __forceinline__ float gelu_tanh(float x) {
    float u = 0.7978845608028654f * (x + 0.044715f * x * x * x);
    u = fminf(fmaxf(u, -15.f), 15.f);
    float e = __expf(2.f * u);
    float t = (e - 1.f) / (e + 1.f);
    return 0.5f * x * (1.f + t);
}
__device__ __forceinline__ int clampi(int v, int hi) {  // [0, hi)
    return v < 0 ? 0 : (v >= hi ? hi - 1 : v);
}
// async 16B global->LDS (linear dest, lane-ordered — matches wave-uniform-base+lane*16)
__device__ __forceinline__ void gload_lds16(const void* g, void* l) {
    __builtin_amdgcn_global_load_lds((const GAS uint32_t*)g, (LAS uint32_t*)l, 16, 0, 0);
}

// row-wise LN over 128 cols spread as x[n] on 16 lanes (same quad group)
__device__ __forceinline__ void ln8(float x[8], const float gv[8], const float bv[8]) {
    float s1 = 0.f, s2 = 0.f;
#pragma unroll
    for (int n = 0; n < 8; ++n) { s1 += x[n]; s2 += x[n] * x[n]; }
#pragma unroll
    for (int m = 1; m < 16; m <<= 1) {
        s1 += __shfl_xor(s1, m, 64);
        s2 += __shfl_xor(s2, m, 64);
    }
    float mean = s1 * (1.f / 128.f);
    float var  = fmaxf(s2 * (1.f / 128.f) - mean * mean, 0.f);
    float rs   = rsqrtf(var + 1e-5f);
#pragma unroll
    for (int n = 0; n < 8; ++n) x[n] = (x[n] - mean) * rs * gv[n] + bv[n];
}

// Detect whether float inputs are f32 (flag=1) or bf16 (flag=0).
__global__ void k_detect(const uint32_t* __restrict__ raw, int* __restrict__ flag) {
    int t = blockIdx.x * blockDim.x + threadIdx.x;   // 65536 threads
    uint32_t u = raw[t];
    int e_lo = (u >> 7)  & 0xFF;
    int e_hi = (u >> 23) & 0xFF;
    if (e_lo == 0xFF || e_hi == 0xFF) atomicOr(flag, 1);
}

// ---------------- consolidated setup: bias packs + projT + all B-fragment transforms ----------------
// region 0: [0, 4224)            bias/gamma/beta packs into bvec slots
// region 1: [4224, 7296)         proj_w [128x24] -> wT [24x128]
// region 2: [7296, 7296+43520)   6 weights -> MFMA B-fragment arena (contiguous)
struct SetupArgs {
    const void* psrc[13];
    int         pn[13];
    int         pdst[13];
    const void* fsrc[6];
    int         fkb[6];
    int         fdst[6];     // dst offset into frag arena (ushort units)
    const void* projw;
};

__global__ void k_setup(SetupArgs a, ushort_t* __restrict__ bvec, ushort_t* __restrict__ frag,
                        ushort_t* __restrict__ wT, const int* __restrict__ dflag) {
    const bool f32 = *dflag != 0;
    int t = blockIdx.x * blockDim.x + threadIdx.x;
    if (t < 4224) {                      // bias packs
        int i = t, d = 0;
        while (i >= a.pn[d]) { i -= a.pn[d]; ++d; }
        bvec[(size_t)a.pdst[d] * 128 + i] = f2b(ldf(a.psrc[d], i, f32));
        return;
    }
    t -= 4224;
    if (t < 3072) {                      // projT
        int p = t >> 7, k = t & 127;
        wT[p * 128 + k] = f2b(ldf(a.projw, (size_t)k * 24 + p, f32));
        return;
    }
    t -= 3072;
    if (t >= 43520) return;              // bfrag region: sum(fkb)=85 -> 85*512 groups
    int g = t, d = 0;
    while (g >= a.fkb[d] * 512) { g -= a.fkb[d] * 512; ++d; }
    const void* src = a.fsrc[d];
    int kblk = g >> 9;
    int rem  = g & 511;
    int nt   = rem >> 6;
    int lane = rem & 63;
    int krow = kblk * 32 + ((lane >> 4) << 3);
    int col  = nt * 16 + (lane & 15);
    short8 v;
#pragma unroll
    for (int j = 0; j < 8; ++j) v[j] = (short)f2b(ldf(src, (size_t)(krow + j) * 128 + col, f32));
    *(short8*)(frag + (size_t)a.fdst[d] + (size_t)g * 8) = v;
}

// ---------------- CSR build for receiver-side aggregation ----------------
__global__ void k_counti(const int* __restrict__ recv, int* __restrict__ cnti, int E) {
    int i = blockIdx.x * blockDim.x + threadIdx.x;
    if (i < E) atomicAdd(&cnti[clampi(recv[i], N_NODES)], 1);
}

// single-block exclusive scan of cnti -> offs (and cursor copy)
__global__ void k_scan(const int* __restrict__ cnti, int* __restrict__ offs,
                       int* __restrict__ cursor) {
    __shared__ int part[1024];
    const int t = threadIdx.x;           // blockDim = 1024
    const int base = t * 20;             // 1024*20 = 20480 >= N_NODES
    int s = 0;
#pragma unroll 4
    for (int j = 0; j < 20; ++j) {
        int idx = base + j;
        if (idx < N_NODES) s += cnti[idx];
    }
    part[t] = s;
    __syncthreads();
    for (int off = 1; off < 1024; off <<= 1) {
        int v = (t >= off) ? part[t - off] : 0;
        __syncthreads();
        part[t] += v;
        __syncthreads();
    }
    int run = (t == 0) ? 0 : part[t - 1];   // exclusive prefix
    for (int j = 0; j < 20; ++j) {
        int idx = base + j;
        if (idx < N_NODES) {
            offs[idx]   = run;
            cursor[idx] = run;
            run += cnti[idx];
        }
    }
}

__global__ void k_fill(const int* __restrict__ recv, int* __restrict__ cursor,
                       int* __restrict__ eid, int E) {
    int i = blockIdx.x * blockDim.x + threadIdx.x;
    if (i < E) {
        int r = clampi(recv[i], N_NODES);
        int pos = atomicAdd(&cursor[r], 1);
        eid[pos] = i;
    }
}

// gather-mean aggregation: agg[n] = mean over incident edges of e[eid] (bf16 out)
__global__ void k_agg(const ushort_t* __restrict__ e, const int* __restrict__ offs,
                      const int* __restrict__ cnti, const int* __restrict__ eid,
                      ushort_t* __restrict__ agg) {
    const int tid = threadIdx.x;
    const int n = blockIdx.x * 8 + (tid >> 5);   // 8 nodes / 256-thread block
    const int l = tid & 31;                      // 32 lanes x 4 cols = 128 cols
    if (n >= N_NODES) return;
    const int start = offs[n], deg = cnti[n];
    float s0 = 0.f, s1 = 0.f, s2 = 0.f, s3 = 0.f;
    for (int j = 0; j < deg; ++j) {
        const ushort_t* row = e + (size_t)eid[start + j] * 128 + l * 4;
        short4v v = *(const short4v*)row;
        s0 += b2f((ushort_t)v[0]);
        s1 += b2f((ushort_t)v[1]);
        s2 += b2f((ushort_t)v[2]);
        s3 += b2f((ushort_t)v[3]);
    }
    const float inv = 1.f / (float)(deg < 1 ? 1 : deg);
    short4v o;
    o[0] = (short)f2b(s0 * inv);
    o[1] = (short)f2b(s1 * inv);
    o[2] = (short)f2b(s2 * inv);
    o[3] = (short)f2b(s3 * inv);
    *(short4v*)(agg + (size_t)n * 128 + l * 4) = o;
}

// ---------------- generic GEMM (node embedding) ----------------
template<int NC, bool LN>
__global__ __launch_bounds__(256, 2) void k_gemm(
    const ushort_t* __restrict__ bfrag,
    const void* s0, int isf0, int st0, int ko0, int kl0,
    const void* s1, int isf1, int st1, int ko1, int kl1,
    const void* s2, int isf2, int st2, int ko2, int kl2,
    int rows,
    const ushort_t* __restrict__ bias,
    const ushort_t* __restrict__ gamma,
    const ushort_t* __restrict__ betap,
    ushort_t* out,
    const int* __restrict__ dflag)
{
    __shared__ __align__(16) ushort_t lds_b[128 * 128];
    const bool f32g = *dflag != 0;
    const int tid  = threadIdx.x;
    const int wave = tid >> 6, lane = tid & 63;
    const int quad = lane >> 4, l16 = lane & 15;
    const int row0 = blockIdx.x * 128 + wave * 32;

    f32x4 acc[2][8];
#pragma unroll
    for (int t = 0; t < 2; ++t)
#pragma unroll
        for (int n = 0; n < 8; ++n) acc[t][n] = (f32x4){0.f, 0.f, 0.f, 0.f};

    const ushort_t* bptr = bfrag;
#pragma unroll
    for (int c = 0; c < NC; ++c) {
        const void* src  = (c == 0) ? s0 : ((c == 1) ? s1 : s2);
        const bool  eff  = (((c == 0) ? isf0 : ((c == 1) ? isf1 : isf2)) != 0) && f32g;
        const int stride = (c == 0) ? st0 : ((c == 1) ? st1 : st2);
        const int koff   = (c == 0) ? ko0 : ((c == 1) ? ko1 : ko2);
        const int klen   = (c == 0) ? kl0 : ((c == 1) ? kl1 : kl2);

        if (c) __syncthreads();
        {
            const int ngrp = klen * 16;
            for (int g = tid; g < ngrp; g += 256)
                gload_lds16(bptr + (size_t)g * 8, lds_b + (size_t)g * 8);
        }
        __syncthreads();   // full drain: staging resident

        size_t aoff[2];
#pragma unroll
        for (int t = 0; t < 2; ++t) {
            int r  = row0 + t * 16 + l16;
            int rr = r < rows ? r : rows - 1;
            aoff[t] = (size_t)rr * stride + koff + quad * 8;
        }
        const int ksteps = klen >> 5;
        for (int ks = 0; ks < ksteps; ++ks) {
            short8 af[2];
#pragma unroll
            for (int t = 0; t < 2; ++t)
                af[t] = lda8(src, aoff[t] + ks * 32, eff);
#pragma unroll
            for (int n = 0; n < 8; ++n) {
                short8 bf = *(const short8*)(lds_b + (size_t)((ks * 8 + n) * 64 + lane) * 8);
                acc[0][n] = __builtin_amdgcn_mfma_f32_16x16x32_bf16(af[0], bf, acc[0][n], 0, 0, 0);
                acc[1][n] = __builtin_amdgcn_mfma_f32_16x16x32_bf16(af[1], bf, acc[1][n], 0, 0, 0);
            }
        }
        bptr += (size_t)klen * 128;
    }

    float bv[8], gv[8], btv[8];
#pragma unroll
    for (int n = 0; n < 8; ++n) {
        int col = n * 16 + l16;
        bv[n] = b2f(bias[col]);
        if (LN) { gv[n] = b2f(gamma[col]); btv[n] = b2f(betap[col]); }
    }
#pragma unroll
    for (int t = 0; t < 2; ++t) {
#pragma unroll
        for (int r = 0; r < 4; ++r) {
            int row = row0 + t * 16 + quad * 4 + r;
            float x[8];
#pragma unroll
            for (int n = 0; n < 8; ++n) x[n] = acc[t][n][r] + bv[n];
            if (LN) {
#pragma unroll
                for (int n = 0; n < 8; ++n) x[n] = gelu_tanh(x[n]);
                ln8(x, gv, btv);
            }
            if (row < rows) {
#pragma unroll
                for (int n = 0; n < 8; ++n)
                    out[(size_t)row * 128 + n * 16 + l16] = f2b(x[n]);
            }
        }
    }
}

// ---------------- fused output: mlp_out GEMM + gelu + LN + projection to d_out ----------------
__global__ __launch_bounds__(256, 2) void k_out(
    const ushort_t* __restrict__ bfrag,     // bf_mlpout
    const ushort_t* __restrict__ h,
    const ushort_t* __restrict__ bias,
    const ushort_t* __restrict__ gamma,
    const ushort_t* __restrict__ betap,
    const ushort_t* __restrict__ wT,        // [24][128] bf16
    const void* __restrict__ pb,            // proj_b raw
    void* __restrict__ out, int rows,
    const int* __restrict__ dflag)
{
    __shared__ __align__(16) ushort_t lds_b[128 * 128];
    __shared__ __align__(16) ushort_t lds_x[128 * XSTRIDE];
    const bool f32g = *dflag != 0;
    const int tid  = threadIdx.x;
    const int wave = tid >> 6, lane = tid & 63;
    const int quad = lane >> 4, l16 = lane & 15;
    const int row0  = blockIdx.x * 128;
    const int lrow0 = wave * 32;

    for (int g = tid; g < 2048; g += 256)
        gload_lds16(bfrag + (size_t)g * 8, lds_b + (size_t)g * 8);
    __syncthreads();

    f32x4 acc[2][8];
#pragma unroll
    for (int t = 0; t < 2; ++t)
#pragma unroll
        for (int n = 0; n < 8; ++n) acc[t][n] = (f32x4){0.f, 0.f, 0.f, 0.f};

    const ushort_t* ap[2];
#pragma unroll
    for (int t = 0; t < 2; ++t) {
        int grow = row0 + lrow0 + t * 16 + l16;
        int rr = grow < rows ? grow : rows - 1;
        ap[t] = h + (size_t)rr * 128 + quad * 8;
    }
    for (int ks = 0; ks < 4; ++ks) {
        short8 af[2];
#pragma unroll
        for (int t = 0; t < 2; ++t) af[t] = *(const short8*)(ap[t] + ks * 32);
#pragma unroll
        for (int n = 0; n < 8; ++n) {
            short8 bf = *(const short8*)(lds_b + (size_t)((ks * 8 + n) * 64 + lane) * 8);
            acc[0][n] = __builtin_amdgcn_mfma_f32_16x16x32_bf16(af[0], bf, acc[0][n], 0, 0, 0);
            acc[1][n] = __builtin_amdgcn_mfma_f32_16x16x32_bf16(af[1], bf, acc[1][n], 0, 0, 0);
        }
    }

    {
        float bv[8], gv[8], btv[8];
#pragma unroll
        for (int n = 0; n < 8; ++n) {
            int col = n * 16 + l16;
            bv[n] = b2f(bias[col]); gv[n] = b2f(gamma[col]); btv[n] = b2f(betap[col]);
        }
#pragma unroll
        for (int t = 0; t < 2; ++t)
#pragma unroll
            for (int r = 0; r < 4; ++r) {
                int lrow = lrow0 + t * 16 + quad * 4 + r;
                float x[8];
#pragma unroll
                for (int n = 0; n < 8; ++n) x[n] = gelu_tanh(acc[t][n][r] + bv[n]);
                ln8(x, gv, btv);
#pragma unroll
                for (int n = 0; n < 8; ++n)
                    lds_x[lrow * XSTRIDE + n * 16 + l16] = f2b(x[n]);
            }
    }
    __syncthreads();

    // projection: 128 rows x 24 outputs = 3072 -> 12 per thread
#pragma unroll
    for (int it = 0; it < 12; ++it) {
        int idx  = it * 256 + tid;
        int lrow = idx / 24;
        int p    = idx - lrow * 24;
        int grow = row0 + lrow;
        if (grow < rows) {
            float a2 = ldf(pb, p, f32g);
            const ushort_t* xp = lds_x + lrow * XSTRIDE;
            const ushort_t* wp = wT + (size_t)p * 128;
#pragma unroll
            for (int k8 = 0; k8 < 16; ++k8) {
                short8 hv = *(const short8*)(xp + k8 * 8);
                short8 wv = *(const short8*)(wp + k8 * 8);
#pragma unroll
                for (int j = 0; j < 8; ++j)
                    a2 += b2f((ushort_t)hv[j]) * b2f((ushort_t)wv[j]);
            }
            if (f32g) ((float*)out)[(size_t)grow * 24 + p] = a2;
            else      ((ushort_t*)out)[(size_t)grow * 24 + p] = f2b(a2);
        }
    }
}

// ======== chunked double-buffered pipeline (T3-min 2-phase + T4 counted vmcnt + T14 A-prefetch) ========
// Chunk = 64-K half of a 128-K stage = 16 KB of B-fragments in lds_w[buf].
// A-fragments are prefetched ONE CHUNK AHEAD into a rotating afA/afB register pair, so the
// random-gather latency hides under the previous chunk's MFMA.
// Per-wave vmcnt ledger at steady state (oldest->newest):
//   [af_cur(4), stage_cur(4), af_next(4), stage_next(4)] -> vmcnt(8) drains {af_cur, stage_cur}
// Last P-chunk issues no af_next -> vmcnt(4). X-chunks (LDS A-source) keep the round-3 vmcnt(4).
// sched_barrier(0) after the pre-MFMA barrier / before the trailing barrier pins the lds_w
// ds_reads inside the protected window (raw s_barrier is IntrNoMem at IR level).

#define STAGE(srcp, bufi) do {                                                   \
    const ushort_t* s__ = (srcp);                                                \
    _Pragma("unroll")                                                            \
    for (int it__ = 0; it__ < 4; ++it__) {                                       \
        int g__ = it__ * 256 + tid;                                              \
        gload_lds16(s__ + (size_t)g__ * 8, &lds_w[bufi][(size_t)g__ * 8]);       \
    } } while (0)

#define LOADA(dst, apv, hf) do {                                                 \
    _Pragma("unroll") for (int t_ = 0; t_ < 2; ++t_)                             \
    _Pragma("unroll") for (int k_ = 0; k_ < 2; ++k_)                             \
        dst[t_][k_] = *(const short8*)(apv[t_] + ((hf) * 2 + k_) * 32);          \
    } while (0)

#define PCH(AFU, AFN, apv, hfn, bufi, nsrc, nbuf, VM, DO_A, DO_STAGE) do {       \
    if (DO_A) LOADA(AFN, apv, hfn);                                              \
    __builtin_amdgcn_sched_barrier(0);                                           \
    if (DO_STAGE) STAGE(nsrc, nbuf);                                             \
    asm volatile("s_waitcnt vmcnt(" #VM ")" ::: "memory");                       \
    __builtin_amdgcn_s_barrier();                                                \
    __builtin_amdgcn_sched_barrier(0);                                           \
    _Pragma("unroll") for (int k_ = 0; k_ < 2; ++k_)                             \
    _Pragma("unroll") for (int n_ = 0; n_ < 8; ++n_) {                           \
        short8 bf_ = *(const short8*)(&lds_w[bufi][(size_t)((k_ * 8 + n_) * 64 + lane) * 8]); \
        acc[0][n_] = __builtin_amdgcn_mfma_f32_16x16x32_bf16(AFU[0][k_], bf_, acc[0][n_], 0, 0, 0); \
        acc[1][n_] = __builtin_amdgcn_mfma_f32_16x16x32_bf16(AFU[1][k_], bf_, acc[1][n_], 0, 0, 0); \
    }                                                                            \
    __builtin_amdgcn_sched_barrier(0);                                           \
    __builtin_amdgcn_s_barrier();                                                \
} while (0)

#define XCHUNK(hf, bufi, DO_STAGE, nsrc, nbuf, VM) do {                          \
    if (DO_STAGE) STAGE(nsrc, nbuf);                                             \
    asm volatile("s_waitcnt vmcnt(" #VM ")" ::: "memory");                       \
    __builtin_amdgcn_s_barrier();                                                \
    __builtin_amdgcn_sched_barrier(0);                                           \
    _Pragma("unroll") for (int k_ = 0; k_ < 2; ++k_) {                           \
        short8 af_[2];                                                           \
        _Pragma("unroll") for (int t_ = 0; t_ < 2; ++t_)                         \
            af_[t_] = *(const short8*)(lds_x + (size_t)(lrow0 + t_ * 16 + l16) * XSTRIDE \
                                       + ((hf) * 2 + k_) * 32 + quad * 8);       \
        _Pragma("unroll") for (int n_ = 0; n_ < 8; ++n_) {                       \
            short8 bf_ = *(const short8*)(&lds_w[bufi][(size_t)((k_ * 8 + n_) * 64 + lane) * 8]); \
            acc[0][n_] = __builtin_amdgcn_mfma_f32_16x16x32_bf16(af_[0], bf_, acc[0][n_], 0, 0, 0); \
            acc[1][n_] = __builtin_amdgcn_mfma_f32_16x16x32_bf16(af_[1], bf_, acc[1][n_], 0, 0, 0); \
        }                                                                        \
    }                                                                            \
    __builtin_amdgcn_sched_barrier(0);                                           \
    __builtin_amdgcn_s_barrier();                                                \
} while (0)

#define EPI_PROJ() do {                                                          \
    _Pragma("unroll") for (int t_ = 0; t_ < 2; ++t_)                             \
    _Pragma("unroll") for (int r_ = 0; r_ < 4; ++r_) {                           \
        int lr_ = lrow0 + t_ * 16 + quad * 4 + r_;                               \
        _Pragma("unroll") for (int n_ = 0; n_ < 8; ++n_)                         \
            lds_x[lr_ * XSTRIDE + n_ * 16 + l16] = f2b(acc[t_][n_][r_] + pbv[n_]); \
    }                                                                            \
    _Pragma("unroll") for (int t_ = 0; t_ < 2; ++t_)                             \
    _Pragma("unroll") for (int n_ = 0; n_ < 8; ++n_) acc[t_][n_] = (f32x4){0.f, 0.f, 0.f, 0.f}; \
} while (0)

#define EPI_LN(BV, GV, BEV) do {                                                 \
    _Pragma("unroll") for (int t_ = 0; t_ < 2; ++t_)                             \
    _Pragma("unroll") for (int r_ = 0; r_ < 4; ++r_) {                           \
        int lr_ = lrow0 + t_ * 16 + quad * 4 + r_;                               \
        float x_[8];                                                             \
        _Pragma("unroll") for (int n_ = 0; n_ < 8; ++n_) x_[n_] = gelu_tanh(acc[t_][n_][r_] + BV[n_]); \
        ln8(x_, GV, BEV);                                                        \
        _Pragma("unroll") for (int n_ = 0; n_ < 8; ++n_)                         \
            lds_x[lr_ * XSTRIDE + n_ * 16 + l16] = f2b(x_[n_]);                  \
    }                                                                            \
    _Pragma("unroll") for (int t_ = 0; t_ < 2; ++t_)                             \
    _Pragma("unroll") for (int n_ = 0; n_ < 8; ++n_) acc[t_][n_] = (f32x4){0.f, 0.f, 0.f, 0.f}; \
} while (0)

// ---------------- fused edge pipeline: proj(K=384) -> MLP1 -> MLP2 + residual ----------------
__global__ __launch_bounds__(256, 2) void k_edge_fused(
    const ushort_t* __restrict__ bf_proj,
    const ushort_t* __restrict__ bf_w0,
    const ushort_t* __restrict__ bf_w1,
    ushort_t* e_glob,
    const ushort_t* __restrict__ h,
    const int* __restrict__ senders, const int* __restrict__ receivers,
    const ushort_t* __restrict__ pb,
    const ushort_t* __restrict__ b0, const ushort_t* __restrict__ g0, const ushort_t* __restrict__ be0,
    const ushort_t* __restrict__ b1, const ushort_t* __restrict__ g1, const ushort_t* __restrict__ be1)
{
    __shared__ __align__(16) ushort_t lds_w[2][64 * 128];
    __shared__ __align__(16) ushort_t lds_x[128 * XSTRIDE];
    const int tid  = threadIdx.x;
    const int wave = tid >> 6, lane = tid & 63;
    const int quad = lane >> 4, l16 = lane & 15;
    const int row0  = blockIdx.x * 128;   // 320000 % 128 == 0: all rows valid
    const int lrow0 = wave * 32;

    // hoist all epilogue constants so no stray VMEM perturbs vmcnt counting
    float pbv[8], b0v[8], g0v[8], be0v[8], b1v[8], g1v[8], be1v[8];
#pragma unroll
    for (int n = 0; n < 8; ++n) {
        int col = n * 16 + l16;
        pbv[n]  = b2f(pb[col]);
        b0v[n]  = b2f(b0[col]);  g0v[n] = b2f(g0[col]);  be0v[n] = b2f(be0[col]);
        b1v[n]  = b2f(b1[col]);  g1v[n] = b2f(g1[col]);  be1v[n] = b2f(be1[col]);
    }

    // A-source pointers for the 3 proj stages
    const ushort_t* apE[2]; const ushort_t* apS[2]; const ushort_t* apR[2];
#pragma unroll
    for (int t = 0; t < 2; ++t) {
        int grow = row0 + lrow0 + t * 16 + l16;
        apE[t] = e_glob + (size_t)grow * 128 + quad * 8;
        apS[t] = h + (size_t)clampi(senders[grow],   N_NODES) * 128 + quad * 8;
        apR[t] = h + (size_t)clampi(receivers[grow], N_NODES) * 128 + quad * 8;
    }

    // chunk pointers (16 KB = 8192 ushort each)
    const ushort_t* p0a = bf_proj;             const ushort_t* p0b = bf_proj + 8192;
    const ushort_t* p1a = bf_proj + 16384;     const ushort_t* p1b = bf_proj + 24576;
    const ushort_t* p2a = bf_proj + 32768;     const ushort_t* p2b = bf_proj + 40960;
    const ushort_t* w0a = bf_w0;               const ushort_t* w0b = bf_w0 + 8192;
    const ushort_t* w1a = bf_w1;               const ushort_t* w1b = bf_w1 + 8192;

    f32x4 acc[2][8];
#pragma unroll
    for (int t = 0; t < 2; ++t)
#pragma unroll
        for (int n = 0; n < 8; ++n) acc[t][n] = (f32x4){0.f, 0.f, 0.f, 0.f};

    short8 afA[2][2], afB[2][2];
    // prologue: first A-fragment + first weight chunk in flight
    LOADA(afA, apE, 0);
    __builtin_amdgcn_sched_barrier(0);
    STAGE(p0a, 0);
    // steady state: consume [apE0,apE1,apS0,apS1,apR0,apR1] with 1-chunk-ahead A prefetch
    PCH(afA, afB, apE, 1, 0, p0b, 1, 8, 1, 1);
    PCH(afB, afA, apS, 0, 1, p1a, 0, 8, 1, 1);
    PCH(afA, afB, apS, 1, 0, p1b, 1, 8, 1, 1);
    PCH(afB, afA, apR, 0, 1, p2a, 0, 8, 1, 1);
    PCH(afA, afB, apR, 1, 0, p2b, 1, 8, 1, 1);
    PCH(afB, afA, apR, 1, 1, w0a, 0, 4, 0, 1);   // last P-chunk: no next-A -> vmcnt(4)
    EPI_PROJ();                          // wave-private lds_x; overlaps w0a flight
    XCHUNK(0, 0, 1, w0b, 1, 4);
    XCHUNK(1, 1, 1, w1a, 0, 4);
    EPI_LN(b0v, g0v, be0v);              // MLP1 epilogue; overlaps w1a flight
    XCHUNK(0, 0, 1, w1b, 1, 4);
    XCHUNK(1, 1, 0, w1b, 0, 0);
    EPI_LN(b1v, g1v, be1v);              // final LN -> lds_x

    __syncthreads();
#pragma unroll
    for (int it = 0; it < 8; ++it) {
        int idx  = it * 256 + tid;          // 0..2047 -> 128 rows x 16 chunks
        int lrow = idx >> 4;
        int c8   = (idx & 15) << 3;
        size_t goff = (size_t)(row0 + lrow) * 128 + c8;
        short8 xv = *(const short8*)(lds_x + lrow * XSTRIDE + c8);
        short8 ev = *(const short8*)(e_glob + goff);
        short8 yv;
#pragma unroll
        for (int j = 0; j < 8; ++j)
            yv[j] = (short)f2b(b2f((ushort_t)ev[j]) + b2f((ushort_t)xv[j]));
        *(short8*)(e_glob + goff) = yv;
    }
}

// ---------------- fused node pipeline: proj(K=256) -> MLP1 -> MLP2 + residual ----------------
__global__ __launch_bounds__(256, 2) void k_node_fused(
    const ushort_t* __restrict__ bf_proj,
    const ushort_t* __restrict__ bf_w0,
    const ushort_t* __restrict__ bf_w1,
    ushort_t* h,
    const ushort_t* __restrict__ agg,
    const ushort_t* __restrict__ pb,
    const ushort_t* __restrict__ b0, const ushort_t* __restrict__ g0, const ushort_t* __restrict__ be0,
    const ushort_t* __restrict__ b1, const ushort_t* __restrict__ g1, const ushort_t* __restrict__ be1,
    int rows)
{
    __shared__ __align__(16) ushort_t lds_w[2][64 * 128];
    __shared__ __align__(16) ushort_t lds_x[128 * XSTRIDE];
    const int tid  = threadIdx.x;
    const int wave = tid >> 6, lane = tid & 63;
    const int quad = lane >> 4, l16 = lane & 15;
    const int row0  = blockIdx.x * 128;
    const int lrow0 = wave * 32;

    float pbv[8], b0v[8], g0v[8], be0v[8], b1v[8], g1v[8], be1v[8];
#pragma unroll
    for (int n = 0; n < 8; ++n) {
        int col = n * 16 + l16;
        pbv[n]  = b2f(pb[col]);
        b0v[n]  = b2f(b0[col]);  g0v[n] = b2f(g0[col]);  be0v[n] = b2f(be0[col]);
        b1v[n]  = b2f(b1[col]);  g1v[n] = b2f(g1[col]);  be1v[n] = b2f(be1[col]);
    }

    const ushort_t* apH[2]; const ushort_t* apA[2];
#pragma unroll
    for (int t = 0; t < 2; ++t) {
        int grow = row0 + lrow0 + t * 16 + l16;
        int rr = grow < rows ? grow : rows - 1;
        apH[t] = h   + (size_t)rr * 128 + quad * 8;
        apA[t] = agg + (size_t)rr * 128 + quad * 8;
    }

    const ushort_t* n0a = bf_proj;           const ushort_t* n0b = bf_proj + 8192;
    const ushort_t* n1a = bf_proj + 16384;   const ushort_t* n1b = bf_proj + 24576;
    const ushort_t* w0a = bf_w0;             const ushort_t* w0b = bf_w0 + 8192;
    const ushort_t* w1a = bf_w1;             const ushort_t* w1b = bf_w1 + 8192;

    f32x4 acc[2][8];
#pragma unroll
    for (int t = 0; t < 2; ++t)
#pragma unroll
        for (int n = 0; n < 8; ++n) acc[t][n] = (f32x4){0.f, 0.f, 0.f, 0.f};

    short8 afA[2][2], afB[2][2];
    LOADA(afA, apH, 0);
    __builtin_amdgcn_sched_barrier(0);
    STAGE(n0a, 0);
    PCH(afA, afB, apH, 1, 0, n0b, 1, 8, 1, 1);
    PCH(afB, afA, apA, 0, 1, n1a, 0, 8, 1, 1);
    PCH(afA, afB, apA, 1, 0, n1b, 1, 8, 1, 1);
    PCH(afB, afA, apA, 1, 1, w0a, 0, 4, 0, 1);   // last P-chunk: no next-A -> vmcnt(4)
    EPI_PROJ();
    XCHUNK(0, 0, 1, w0b, 1, 4);
    XCHUNK(1, 1, 1, w1a, 0, 4);
    EPI_LN(b0v, g0v, be0v);
    XCHUNK(0, 0, 1, w1b, 1, 4);
    XCHUNK(1, 1, 0, w1b, 0, 0);
    EPI_LN(b1v, g1v, be1v);

    __syncthreads();
#pragma unroll
    for (int it = 0; it < 8; ++it) {
        int idx  = it * 256 + tid;
        int lrow = idx >> 4;
        int c8   = (idx & 15) << 3;
        int grow = row0 + lrow;
        if (grow < rows) {
            size_t goff = (size_t)grow * 128 + c8;
            short8 xv = *(const short8*)(lds_x + lrow * XSTRIDE + c8);
            short8 hv = *(const short8*)(h + goff);
            short8 yv;
#pragma unroll
            for (int j = 0; j < 8; ++j)
                yv[j] = (short)f2b(b2f((ushort_t)hv[j]) + b2f((ushort_t)xv[j]));
            *(short8*)(h + goff) = yv;
        }
    }
}

// e = edges @ w_edge_emb + b   (K=2); edges/w raw inputs, b from bf16 arena
__global__ void k_eedge(const void* __restrict__ edges, const void* __restrict__ w,
                        const ushort_t* __restrict__ b, ushort_t* __restrict__ e, int E,
                        const int* __restrict__ dflag) {
    const bool f32g = *dflag != 0;
    int t = blockIdx.x * blockDim.x + threadIdx.x;
    int i = t >> 4, c8 = (t & 15) << 3;
    if (i >= E) return;
    float a0 = ldf(edges, (size_t)i * 2, f32g);
    float a1 = ldf(edges, (size_t)i * 2 + 1, f32g);
    short8 v;
#pragma unroll
    for (int j = 0; j < 8; ++j) {
        int c = c8 + j;
        v[j] = (short)f2b(a0 * ldf(w, c, f32g) + a1 * ldf(w, 128 + c, f32g) + b2f(b[c]));
    }
    *(short8*)(e + (size_t)i * 128 + c8) = v;
}

extern "C" void kernel_launch(void* const* d_in, const int* in_sizes, int n_in,
                              void* d_out, int out_size, void* d_ws, size_t ws_size,
                              hipStream_t stream) {
    const void* nodes        = d_in[0];
    const void* edges        = d_in[1];
    const int*  senders      = (const int*)d_in[2];
    const int*  receivers    = (const int*)d_in[3];
    const void* w_node_emb   = d_in[4];
    const void* b_node_emb   = d_in[5];
    const void* w_edge_emb   = d_in[6];
    const void* b_edge_emb   = d_in[7];
    const void* edge_proj_w  = d_in[8];
    const void* edge_proj_b  = d_in[9];
    const void* node_proj_w  = d_in[10];
    const void* node_proj_b  = d_in[11];
    const void* edge_mlp_w   = d_in[12];
    const void* edge_mlp_b   = d_in[13];
    const void* edge_ln_g    = d_in[14];
    const void* edge_ln_b    = d_in[15];
    const void* node_mlp_w   = d_in[16];
    const void* node_mlp_b   = d_in[17];
    const void* node_ln_g    = d_in[18];
    const void* node_ln_b    = d_in[19];
    const void* mlp_out_w    = d_in[20];
    const void* mlp_out_b    = d_in[21];
    const void* mlp_out_g    = d_in[22];
    const void* mlp_out_beta = d_in[23];
    const void* proj_w       = d_in[24];
    const void* proj_b       = d_in[25];

    char* ws = (char*)d_ws;
    ushort_t* bf_nodeemb  = (ushort_t*)ws;  ws += (size_t)288 * 128 * 2;   // frag arena start
    ushort_t* bf_edgeproj = (ushort_t*)ws;  ws += (size_t)768 * 128 * 2;
    ushort_t* bf_nodeproj = (ushort_t*)ws;  ws += (size_t)512 * 128 * 2;
    ushort_t* bf_edgemlp  = (ushort_t*)ws;  ws += (size_t)512 * 128 * 2;
    ushort_t* bf_nodemlp  = (ushort_t*)ws;  ws += (size_t)512 * 128 * 2;
    ushort_t* bf_mlpout   = (ushort_t*)ws;  ws += (size_t)128 * 128 * 2;
    ushort_t* h    = (ushort_t*)ws;         ws += (size_t)N_NODES * D * 2;
    ushort_t* e    = (ushort_t*)ws;         ws += (size_t)N_EDGES * D * 2;
    ushort_t* agg  = (ushort_t*)ws;         ws += (size_t)N_NODES * D * 2;
    int*      cnti = (int*)ws;              ws += (size_t)N_NODES * 4;
    int*      offs = (int*)ws;              ws += (size_t)N_NODES * 4;
    int*      curs = (int*)ws;              ws += (size_t)N_NODES * 4;
    int*      eid  = (int*)ws;              ws += (size_t)N_EDGES * 4;
    int*      flag = (int*)ws;              ws += 256;
    ushort_t* bvec = (ushort_t*)ws;         ws += (size_t)34 * 128 * 2;   // packed bf16 bias arena
    ushort_t* wT   = (ushort_t*)ws;         ws += (size_t)24 * 128 * 2;   // projT bf16

    hipMemsetAsync(flag, 0, 256, stream);
    k_detect<<<256, 256, 0, stream>>>((const uint32_t*)nodes, flag);

    // consolidated setup (bias packs + projT + all 6 B-fragment transforms in one launch)
    // bvec slots: 0 b_node_emb | 1 b_edge_emb | 2,3 edge_proj_b | 4,5 node_proj_b | 6..9 edge_mlp_b
    // 10..13 edge_ln_g | 14..17 edge_ln_b | 18..21 node_mlp_b | 22..25 node_ln_g
    // 26..29 node_ln_b | 30 mlp_out_b | 31 mlp_out_g | 32 mlp_out_beta
    {
        SetupArgs sa;
        const void* ps[13] = { b_node_emb, b_edge_emb, edge_proj_b, node_proj_b,
                               edge_mlp_b, edge_ln_g, edge_ln_b,
                               node_mlp_b, node_ln_g, node_ln_b,
                               mlp_out_b, mlp_out_g, mlp_out_beta };
        const int   pn[13] = { 128, 128, 256, 256, 512, 512, 512, 512, 512, 512, 128, 128, 128 };
        const int   pd[13] = { 0, 1, 2, 4, 6, 10, 14, 18, 22, 26, 30, 31, 32 };
        const void* fs[6]  = { w_node_emb, edge_proj_w, node_proj_w, edge_mlp_w, node_mlp_w, mlp_out_w };
        const int   fk[6]  = { 9, 24, 16, 16, 16, 4 };
        const int   fd[6]  = { 0, 36864, 135168, 200704, 266240, 331776 };  // ushort offsets, contiguous arena
        for (int i = 0; i < 13; ++i) { sa.psrc[i] = ps[i]; sa.pn[i] = pn[i]; sa.pdst[i] = pd[i]; }
        for (int i = 0; i < 6;  ++i) { sa.fsrc[i] = fs[i]; sa.fkb[i] = fk[i]; sa.fdst[i] = fd[i]; }
        sa.projw = proj_w;
        // total threads: 4224 (packs) + 3072 (projT) + 43520 (bfrag) = 50816 -> 199 blocks
        k_setup<<<199, 256, 0, stream>>>(sa, bvec, bf_nodeemb, wT, flag);
    }

    // CSR build (receivers constant across both layers)
    hipMemsetAsync(cnti, 0, (size_t)N_NODES * 4, stream);
    k_counti<<<(N_EDGES + 255) / 256, 256, 0, stream>>>(receivers, cnti, N_EDGES);
    k_scan<<<1, 1024, 0, stream>>>(cnti, offs, curs);
    k_fill<<<(N_EDGES + 255) / 256, 256, 0, stream>>>(receivers, curs, eid, N_EDGES);

    k_eedge<<<(N_EDGES * 16) / 256, 256, 0, stream>>>(edges, w_edge_emb, bvec + 1 * 128, e, N_EDGES, flag);
    {
        const int grid = (N_NODES + 127) / 128;
        k_gemm<3, false><<<grid, 256, 0, stream>>>(
            bf_nodeemb,
            nodes, 1, 288, 0,   128,
            nodes, 1, 288, 128, 128,
            nodes, 1, 288, 256, 32,
            N_NODES, bvec + 0 * 128, nullptr, nullptr, h, flag);
    }

    const int gridE = N_EDGES / 128;           // 2500
    const int gridN = (N_NODES + 127) / 128;   // 157

    for (int l = 0; l < 2; ++l) {
        k_edge_fused<<<gridE, 256, 0, stream>>>(
            bf_edgeproj + (size_t)l * 384 * 128,
            bf_edgemlp + (size_t)(l * 2 + 0) * 128 * 128,
            bf_edgemlp + (size_t)(l * 2 + 1) * 128 * 128,
            e, h, senders, receivers,
            bvec + (size_t)(2 + l) * 128,
            bvec + (size_t)(6  + l * 2) * 128,     bvec + (size_t)(10 + l * 2) * 128,     bvec + (size_t)(14 + l * 2) * 128,
            bvec + (size_t)(6  + l * 2 + 1) * 128, bvec + (size_t)(10 + l * 2 + 1) * 128, bvec + (size_t)(14 + l * 2 + 1) * 128);
        k_agg<<<(N_NODES + 7) / 8, 256, 0, stream>>>(e, offs, cnti, eid, agg);
        k_node_fused<<<gridN, 256, 0, stream>>>(
            bf_nodeproj + (size_t)l * 256 * 128,
            bf_nodemlp + (size_t)(l * 2 + 0) * 128 * 128,
            bf_nodemlp + (size_t)(l * 2 + 1) * 128 * 128,
            h, agg,
            bvec + (size_t)(4 + l) * 128,
            bvec + (size_t)(18 + l * 2) * 128,     bvec + (size_t)(22 + l * 2) * 128,     bvec + (size_t)(26 + l * 2) * 128,
            bvec + (size_t)(18 + l * 2 + 1) * 128, bvec + (size_t)(22 + l * 2 + 1) * 128, bvec + (size_t)(26 + l * 2 + 1) * 128,
            N_NODES);
    }

    // fused: mlp_out GEMM + gelu + LN + projection straight to d_out
    k_out<<<gridN, 256, 0, stream>>>(
        bf_mlpout, h,
        bvec + 30 * 128, bvec + 31 * 128, bvec + 32 * 128,
        wT, proj_b, d_out, N_NODES, flag);
}

// Round 11
// 648.540 us; speedup vs baseline: 1.2613x; 1.2613x over previous
//
#include <hip/hip_runtime.h>
#include <hip/hip_bf16.h>
#include <stdint.h>

typedef unsigned short ushort_t;
typedef __attribute__((ext_vector_type(8))) short short8;
typedef __attribute__((ext_vector_type(4))) short short4v;
typedef __attribute__((ext_vector_type(4))) float f32x4;
typedef __attribute__((ext_vector_type(4))) int int4v;

#define N_NODES 20000
#define N_EDGES 320000
#define D 128
#define XSTRIDE 136   // padded LDS row stride (ushorts)

#define GAS __attribute__((address_space(1)))
#define LAS __attribute__((address_space(3)))

__device__ __forceinline__ float b2f(ushort_t u) {
    union { float f; uint32_t i; } v; v.i = ((uint32_t)u) << 16; return v.f;
}
__device__ __forceinline__ ushort_t f2b(float f) {
    union { float f; uint32_t i; } v; v.f = f;
    uint32_t r = v.i + 0x7FFFu + ((v.i >> 16) & 1u);
    return (ushort_t)(r >> 16);
}
// dtype-flexible scalar load: raw input arrays may be f32 or bf16 (runtime-detected)
__device__ __forceinline__ float ldf(const void* p, size_t i, bool f32) {
    return f32 ? ((const float*)p)[i] : b2f(((const ushort_t*)p)[i]);
}
// dtype-flexible 8-element A-fragment load (8 consecutive elements, 8-aligned index)
__device__ __forceinline__ short8 lda8(const void* p, size_t i, bool f32) {
    if (f32) {
        const float* fp = (const float*)p + i;
        f32x4 v0 = *(const f32x4*)fp;
        f32x4 v1 = *(const f32x4*)(fp + 4);
        short8 a;
#pragma unroll
        for (int j = 0; j < 4; ++j) {
            a[j]     = (short)f2b(v0[j]);
            a[j + 4] = (short)f2b(v1[j]);
        }
        return a;
    }
    return *(const short8*)((const ushort_t*)p + i);
}
__device__ __forceinline__ float gelu_tanh(float x) {
    float u = 0.7978845608028654f * (x + 0.044715f * x * x * x);
    u = fminf(fmaxf(u, -15.f), 15.f);
    float e = __expf(2.f * u);
    float t = (e - 1.f) / (e + 1.f);
    return 0.5f * x * (1.f + t);
}
__device__ __forceinline__ int clampi(int v, int hi) {  // [0, hi)
    return v < 0 ? 0 : (v >= hi ? hi - 1 : v);
}
// async 16B global->LDS (linear dest, lane-ordered — matches wave-uniform-base+lane*16)
__device__ __forceinline__ void gload_lds16(const void* g, void* l) {
    __builtin_amdgcn_global_load_lds((const GAS uint32_t*)g, (LAS uint32_t*)l, 16, 0, 0);
}
// dual-dtype edge row load (2 scalars)
__device__ __forceinline__ void ldedge(const void* edges, int row, bool f32, float& a0, float& a1) {
    if (f32) {
        const float* p = (const float*)edges + (size_t)row * 2;
        a0 = p[0]; a1 = p[1];
    } else {
        const ushort_t* p = (const ushort_t*)edges + (size_t)row * 2;
        a0 = b2f(p[0]); a1 = b2f(p[1]);
    }
}
// e_init fragment: 8 consecutive cols of a0*w0 + a1*w1 + b from the wedge LDS table
__device__ __forceinline__ short8 einit8(const ushort_t* wedge, int colbase, float a0, float a1) {
    short8 w0 = *(const short8*)(wedge + colbase);
    short8 w1 = *(const short8*)(wedge + 128 + colbase);
    short8 bb = *(const short8*)(wedge + 256 + colbase);
    short8 r;
#pragma unroll
    for (int j = 0; j < 8; ++j)
        r[j] = (short)f2b(a0 * b2f((ushort_t)w0[j]) + a1 * b2f((ushort_t)w1[j]) + b2f((ushort_t)bb[j]));
    return r;
}

// row-wise LN over 128 cols spread as x[n] on 16 lanes (same quad group)
__device__ __forceinline__ void ln8(float x[8], const float gv[8], const float bv[8]) {
    float s1 = 0.f, s2 = 0.f;
#pragma unroll
    for (int n = 0; n < 8; ++n) { s1 += x[n]; s2 += x[n] * x[n]; }
#pragma unroll
    for (int m = 1; m < 16; m <<= 1) {
        s1 += __shfl_xor(s1, m, 64);
        s2 += __shfl_xor(s2, m, 64);
    }
    float mean = s1 * (1.f / 128.f);
    float var  = fmaxf(s2 * (1.f / 128.f) - mean * mean, 0.f);
    float rs   = rsqrtf(var + 1e-5f);
#pragma unroll
    for (int n = 0; n < 8; ++n) x[n] = (x[n] - mean) * rs * gv[n] + bv[n];
}

// Detect whether float inputs are f32 (flag=1) or bf16 (flag=0).
__global__ void k_detect(const uint32_t* __restrict__ raw, int* __restrict__ flag) {
    int t = blockIdx.x * blockDim.x + threadIdx.x;   // 65536 threads
    uint32_t u = raw[t];
    int e_lo = (u >> 7)  & 0xFF;
    int e_hi = (u >> 23) & 0xFF;
    if (e_lo == 0xFF || e_hi == 0xFF) atomicOr(flag, 1);
}

// ---------------- consolidated setup: bias packs + projT + all B-fragment transforms ----------------
// region 0: [0, 4608)            bias/gamma/beta/w_edge_emb packs into bvec slots
// region 1: [4608, 7680)         proj_w [128x24] -> wT [24x128]
// region 2: [7680, 7680+43520)   6 weights -> MFMA B-fragment arena (contiguous)
struct SetupArgs {
    const void* psrc[15];
    int         pn[15];
    int         pdst[15];
    const void* fsrc[6];
    int         fkb[6];
    int         fdst[6];     // dst offset into frag arena (ushort units)
    const void* projw;
};

__global__ void k_setup(SetupArgs a, ushort_t* __restrict__ bvec, ushort_t* __restrict__ frag,
                        ushort_t* __restrict__ wT, const int* __restrict__ dflag) {
    const bool f32 = *dflag != 0;
    int t = blockIdx.x * blockDim.x + threadIdx.x;
    if (t < 4608) {                      // bias packs
        int i = t, d = 0;
        while (i >= a.pn[d]) { i -= a.pn[d]; ++d; }
        bvec[(size_t)a.pdst[d] * 128 + i] = f2b(ldf(a.psrc[d], i, f32));
        return;
    }
    t -= 4608;
    if (t < 3072) {                      // projT
        int p = t >> 7, k = t & 127;
        wT[p * 128 + k] = f2b(ldf(a.projw, (size_t)k * 24 + p, f32));
        return;
    }
    t -= 3072;
    if (t >= 43520) return;              // bfrag region: sum(fkb)=85 -> 85*512 groups
    int g = t, d = 0;
    while (g >= a.fkb[d] * 512) { g -= a.fkb[d] * 512; ++d; }
    const void* src = a.fsrc[d];
    int kblk = g >> 9;
    int rem  = g & 511;
    int nt   = rem >> 6;
    int lane = rem & 63;
    int krow = kblk * 32 + ((lane >> 4) << 3);
    int col  = nt * 16 + (lane & 15);
    short8 v;
#pragma unroll
    for (int j = 0; j < 8; ++j) v[j] = (short)f2b(ldf(src, (size_t)(krow + j) * 128 + col, f32));
    *(short8*)(frag + (size_t)a.fdst[d] + (size_t)g * 8) = v;
}

// ---------------- CSR build for receiver-side aggregation ----------------
__global__ void k_counti(const int* __restrict__ recv, int* __restrict__ cnti, int E) {
    int i = blockIdx.x * blockDim.x + threadIdx.x;
    if (i < E) atomicAdd(&cnti[clampi(recv[i], N_NODES)], 1);
}

// single-block exclusive scan of cnti -> offs (and cursor copy)
__global__ void k_scan(const int* __restrict__ cnti, int* __restrict__ offs,
                       int* __restrict__ cursor) {
    __shared__ int part[1024];
    const int t = threadIdx.x;           // blockDim = 1024
    const int base = t * 20;             // 1024*20 = 20480 >= N_NODES
    int s = 0;
#pragma unroll 4
    for (int j = 0; j < 20; ++j) {
        int idx = base + j;
        if (idx < N_NODES) s += cnti[idx];
    }
    part[t] = s;
    __syncthreads();
    for (int off = 1; off < 1024; off <<= 1) {
        int v = (t >= off) ? part[t - off] : 0;
        __syncthreads();
        part[t] += v;
        __syncthreads();
    }
    int run = (t == 0) ? 0 : part[t - 1];   // exclusive prefix
    for (int j = 0; j < 20; ++j) {
        int idx = base + j;
        if (idx < N_NODES) {
            offs[idx]   = run;
            cursor[idx] = run;
            run += cnti[idx];
        }
    }
}

__global__ void k_fill(const int* __restrict__ recv, int* __restrict__ cursor,
                       int* __restrict__ eid, int E) {
    int i = blockIdx.x * blockDim.x + threadIdx.x;
    if (i < E) {
        int r = clampi(recv[i], N_NODES);
        int pos = atomicAdd(&cursor[r], 1);
        eid[pos] = i;
    }
}

// gather-mean aggregation: agg[n] = mean over incident edges of e[eid] (bf16 out)
__global__ void k_agg(const ushort_t* __restrict__ e, const int* __restrict__ offs,
                      const int* __restrict__ cnti, const int* __restrict__ eid,
                      ushort_t* __restrict__ agg) {
    const int tid = threadIdx.x;
    const int n = blockIdx.x * 8 + (tid >> 5);   // 8 nodes / 256-thread block
    const int l = tid & 31;                      // 32 lanes x 4 cols = 128 cols
    if (n >= N_NODES) return;
    const int start = offs[n], deg = cnti[n];
    float s0 = 0.f, s1 = 0.f, s2 = 0.f, s3 = 0.f;
    for (int j = 0; j < deg; ++j) {
        const ushort_t* row = e + (size_t)eid[start + j] * 128 + l * 4;
        short4v v = *(const short4v*)row;
        s0 += b2f((ushort_t)v[0]);
        s1 += b2f((ushort_t)v[1]);
        s2 += b2f((ushort_t)v[2]);
        s3 += b2f((ushort_t)v[3]);
    }
    const float inv = 1.f / (float)(deg < 1 ? 1 : deg);
    short4v o;
    o[0] = (short)f2b(s0 * inv);
    o[1] = (short)f2b(s1 * inv);
    o[2] = (short)f2b(s2 * inv);
    o[3] = (short)f2b(s3 * inv);
    *(short4v*)(agg + (size_t)n * 128 + l * 4) = o;
}

// ---------------- generic GEMM (node embedding) ----------------
template<int NC, bool LN>
__global__ __launch_bounds__(256, 2) void k_gemm(
    const ushort_t* __restrict__ bfrag,
    const void* s0, int isf0, int st0, int ko0, int kl0,
    const void* s1, int isf1, int st1, int ko1, int kl1,
    const void* s2, int isf2, int st2, int ko2, int kl2,
    int rows,
    const ushort_t* __restrict__ bias,
    const ushort_t* __restrict__ gamma,
    const ushort_t* __restrict__ betap,
    ushort_t* out,
    const int* __restrict__ dflag)
{
    __shared__ __align__(16) ushort_t lds_b[128 * 128];
    const bool f32g = *dflag != 0;
    const int tid  = threadIdx.x;
    const int wave = tid >> 6, lane = tid & 63;
    const int quad = lane >> 4, l16 = lane & 15;
    const int row0 = blockIdx.x * 128 + wave * 32;

    f32x4 acc[2][8];
#pragma unroll
    for (int t = 0; t < 2; ++t)
#pragma unroll
        for (int n = 0; n < 8; ++n) acc[t][n] = (f32x4){0.f, 0.f, 0.f, 0.f};

    const ushort_t* bptr = bfrag;
#pragma unroll
    for (int c = 0; c < NC; ++c) {
        const void* src  = (c == 0) ? s0 : ((c == 1) ? s1 : s2);
        const bool  eff  = (((c == 0) ? isf0 : ((c == 1) ? isf1 : isf2)) != 0) && f32g;
        const int stride = (c == 0) ? st0 : ((c == 1) ? st1 : st2);
        const int koff   = (c == 0) ? ko0 : ((c == 1) ? ko1 : ko2);
        const int klen   = (c == 0) ? kl0 : ((c == 1) ? kl1 : kl2);

        if (c) __syncthreads();
        {
            const int ngrp = klen * 16;
            for (int g = tid; g < ngrp; g += 256)
                gload_lds16(bptr + (size_t)g * 8, lds_b + (size_t)g * 8);
        }
        __syncthreads();   // full drain: staging resident

        size_t aoff[2];
#pragma unroll
        for (int t = 0; t < 2; ++t) {
            int r  = row0 + t * 16 + l16;
            int rr = r < rows ? r : rows - 1;
            aoff[t] = (size_t)rr * stride + koff + quad * 8;
        }
        const int ksteps = klen >> 5;
        for (int ks = 0; ks < ksteps; ++ks) {
            short8 af[2];
#pragma unroll
            for (int t = 0; t < 2; ++t)
                af[t] = lda8(src, aoff[t] + ks * 32, eff);
#pragma unroll
            for (int n = 0; n < 8; ++n) {
                short8 bf = *(const short8*)(lds_b + (size_t)((ks * 8 + n) * 64 + lane) * 8);
                acc[0][n] = __builtin_amdgcn_mfma_f32_16x16x32_bf16(af[0], bf, acc[0][n], 0, 0, 0);
                acc[1][n] = __builtin_amdgcn_mfma_f32_16x16x32_bf16(af[1], bf, acc[1][n], 0, 0, 0);
            }
        }
        bptr += (size_t)klen * 128;
    }

    float bv[8], gv[8], btv[8];
#pragma unroll
    for (int n = 0; n < 8; ++n) {
        int col = n * 16 + l16;
        bv[n] = b2f(bias[col]);
        if (LN) { gv[n] = b2f(gamma[col]); btv[n] = b2f(betap[col]); }
    }
#pragma unroll
    for (int t = 0; t < 2; ++t) {
#pragma unroll
        for (int r = 0; r < 4; ++r) {
            int row = row0 + t * 16 + quad * 4 + r;
            float x[8];
#pragma unroll
            for (int n = 0; n < 8; ++n) x[n] = acc[t][n][r] + bv[n];
            if (LN) {
#pragma unroll
                for (int n = 0; n < 8; ++n) x[n] = gelu_tanh(x[n]);
                ln8(x, gv, btv);
            }
            if (row < rows) {
#pragma unroll
                for (int n = 0; n < 8; ++n)
                    out[(size_t)row * 128 + n * 16 + l16] = f2b(x[n]);
            }
        }
    }
}

// ---------------- fused output: mlp_out GEMM + gelu + LN + projection to d_out ----------------
__global__ __launch_bounds__(256, 2) void k_out(
    const ushort_t* __restrict__ bfrag,     // bf_mlpout
    const ushort_t* __restrict__ h,
    const ushort_t* __restrict__ bias,
    const ushort_t* __restrict__ gamma,
    const ushort_t* __restrict__ betap,
    const ushort_t* __restrict__ wT,        // [24][128] bf16
    const void* __restrict__ pb,            // proj_b raw
    void* __restrict__ out, int rows,
    const int* __restrict__ dflag)
{
    __shared__ __align__(16) ushort_t lds_b[128 * 128];
    __shared__ __align__(16) ushort_t lds_x[128 * XSTRIDE];
    const bool f32g = *dflag != 0;
    const int tid  = threadIdx.x;
    const int wave = tid >> 6, lane = tid & 63;
    const int quad = lane >> 4, l16 = lane & 15;
    const int row0  = blockIdx.x * 128;
    const int lrow0 = wave * 32;

    for (int g = tid; g < 2048; g += 256)
        gload_lds16(bfrag + (size_t)g * 8, lds_b + (size_t)g * 8);
    __syncthreads();

    f32x4 acc[2][8];
#pragma unroll
    for (int t = 0; t < 2; ++t)
#pragma unroll
        for (int n = 0; n < 8; ++n) acc[t][n] = (f32x4){0.f, 0.f, 0.f, 0.f};

    const ushort_t* ap[2];
#pragma unroll
    for (int t = 0; t < 2; ++t) {
        int grow = row0 + lrow0 + t * 16 + l16;
        int rr = grow < rows ? grow : rows - 1;
        ap[t] = h + (size_t)rr * 128 + quad * 8;
    }
    for (int ks = 0; ks < 4; ++ks) {
        short8 af[2];
#pragma unroll
        for (int t = 0; t < 2; ++t) af[t] = *(const short8*)(ap[t] + ks * 32);
#pragma unroll
        for (int n = 0; n < 8; ++n) {
            short8 bf = *(const short8*)(lds_b + (size_t)((ks * 8 + n) * 64 + lane) * 8);
            acc[0][n] = __builtin_amdgcn_mfma_f32_16x16x32_bf16(af[0], bf, acc[0][n], 0, 0, 0);
            acc[1][n] = __builtin_amdgcn_mfma_f32_16x16x32_bf16(af[1], bf, acc[1][n], 0, 0, 0);
        }
    }

    {
        float bv[8], gv[8], btv[8];
#pragma unroll
        for (int n = 0; n < 8; ++n) {
            int col = n * 16 + l16;
            bv[n] = b2f(bias[col]); gv[n] = b2f(gamma[col]); btv[n] = b2f(betap[col]);
        }
#pragma unroll
        for (int t = 0; t < 2; ++t)
#pragma unroll
            for (int r = 0; r < 4; ++r) {
                int lrow = lrow0 + t * 16 + quad * 4 + r;
                float x[8];
#pragma unroll
                for (int n = 0; n < 8; ++n) x[n] = gelu_tanh(acc[t][n][r] + bv[n]);
                ln8(x, gv, btv);
#pragma unroll
                for (int n = 0; n < 8; ++n)
                    lds_x[lrow * XSTRIDE + n * 16 + l16] = f2b(x[n]);
            }
    }
    __syncthreads();

    // projection: 128 rows x 24 outputs = 3072 -> 12 per thread
#pragma unroll
    for (int it = 0; it < 12; ++it) {
        int idx  = it * 256 + tid;
        int lrow = idx / 24;
        int p    = idx - lrow * 24;
        int grow = row0 + lrow;
        if (grow < rows) {
            float a2 = ldf(pb, p, f32g);
            const ushort_t* xp = lds_x + lrow * XSTRIDE;
            const ushort_t* wp = wT + (size_t)p * 128;
#pragma unroll
            for (int k8 = 0; k8 < 16; ++k8) {
                short8 hv = *(const short8*)(xp + k8 * 8);
                short8 wv = *(const short8*)(wp + k8 * 8);
#pragma unroll
                for (int j = 0; j < 8; ++j)
                    a2 += b2f((ushort_t)hv[j]) * b2f((ushort_t)wv[j]);
            }
            if (f32g) ((float*)out)[(size_t)grow * 24 + p] = a2;
            else      ((ushort_t*)out)[(size_t)grow * 24 + p] = f2b(a2);
        }
    }
}

// ======== chunked double-buffered pipeline (T3-min 2-phase + T4 counted vmcnt + T14 A-prefetch) ========
// Chunk = 64-K half of a 128-K stage = 16 KB of B-fragments in lds_w[buf].
// A-fragments are prefetched ONE CHUNK AHEAD into a rotating afA/afB register pair.
// L1 steady-state ledger: [af_cur(4), stage_cur(4), af_next(4), stage_next(4)] -> vmcnt(8).
// L0: the two e-chunk A-fragments are COMPUTED (rank-2 einit, VALU+LDS, no VMEM), so the
// ledger shifts: E0=vmcnt(4), E1..R0=vmcnt(8), R1=vmcnt(4); X-chunks vmcnt(4,4,4,0).

#define STAGE(srcp, bufi) do {                                                   \
    const ushort_t* s__ = (srcp);                                                \
    _Pragma("unroll")                                                            \
    for (int it__ = 0; it__ < 4; ++it__) {                                       \
        int g__ = it__ * 256 + tid;                                              \
        gload_lds16(s__ + (size_t)g__ * 8, &lds_w[bufi][(size_t)g__ * 8]);       \
    } } while (0)

#define LOADA(dst, apv, hf) do {                                                 \
    _Pragma("unroll") for (int t_ = 0; t_ < 2; ++t_)                             \
    _Pragma("unroll") for (int k_ = 0; k_ < 2; ++k_)                             \
        dst[t_][k_] = *(const short8*)(apv[t_] + ((hf) * 2 + k_) * 32);          \
    } while (0)

#define PCH(AFU, AFN, apv, hfn, bufi, nsrc, nbuf, VM, DO_A, DO_STAGE) do {       \
    if (DO_A) LOADA(AFN, apv, hfn);                                              \
    __builtin_amdgcn_sched_barrier(0);                                           \
    if (DO_STAGE) STAGE(nsrc, nbuf);                                             \
    asm volatile("s_waitcnt vmcnt(" #VM ")" ::: "memory");                       \
    __builtin_amdgcn_s_barrier();                                                \
    __builtin_amdgcn_sched_barrier(0);                                           \
    _Pragma("unroll") for (int k_ = 0; k_ < 2; ++k_)                             \
    _Pragma("unroll") for (int n_ = 0; n_ < 8; ++n_) {                           \
        short8 bf_ = *(const short8*)(&lds_w[bufi][(size_t)((k_ * 8 + n_) * 64 + lane) * 8]); \
        acc[0][n_] = __builtin_amdgcn_mfma_f32_16x16x32_bf16(AFU[0][k_], bf_, acc[0][n_], 0, 0, 0); \
        acc[1][n_] = __builtin_amdgcn_mfma_f32_16x16x32_bf16(AFU[1][k_], bf_, acc[1][n_], 0, 0, 0); \
    }                                                                            \
    __builtin_amdgcn_sched_barrier(0);                                           \
    __builtin_amdgcn_s_barrier();                                                \
} while (0)

#define XCHUNK(hf, bufi, DO_STAGE, nsrc, nbuf, VM) do {                          \
    if (DO_STAGE) STAGE(nsrc, nbuf);                                             \
    asm volatile("s_waitcnt vmcnt(" #VM ")" ::: "memory");                       \
    __builtin_amdgcn_s_barrier();                                                \
    __builtin_amdgcn_sched_barrier(0);                                           \
    _Pragma("unroll") for (int k_ = 0; k_ < 2; ++k_) {                           \
        short8 af_[2];                                                           \
        _Pragma("unroll") for (int t_ = 0; t_ < 2; ++t_)                         \
            af_[t_] = *(const short8*)(lds_x + (size_t)(lrow0 + t_ * 16 + l16) * XSTRIDE \
                                       + ((hf) * 2 + k_) * 32 + quad * 8);       \
        _Pragma("unroll") for (int n_ = 0; n_ < 8; ++n_) {                       \
            short8 bf_ = *(const short8*)(&lds_w[bufi][(size_t)((k_ * 8 + n_) * 64 + lane) * 8]); \
            acc[0][n_] = __builtin_amdgcn_mfma_f32_16x16x32_bf16(af_[0], bf_, acc[0][n_], 0, 0, 0); \
            acc[1][n_] = __builtin_amdgcn_mfma_f32_16x16x32_bf16(af_[1], bf_, acc[1][n_], 0, 0, 0); \
        }                                                                        \
    }                                                                            \
    __builtin_amdgcn_sched_barrier(0);                                           \
    __builtin_amdgcn_s_barrier();                                                \
} while (0)

#define EPI_PROJ() do {                                                          \
    _Pragma("unroll") for (int t_ = 0; t_ < 2; ++t_)                             \
    _Pragma("unroll") for (int r_ = 0; r_ < 4; ++r_) {                           \
        int lr_ = lrow0 + t_ * 16 + quad * 4 + r_;                               \
        _Pragma("unroll") for (int n_ = 0; n_ < 8; ++n_)                         \
            lds_x[lr_ * XSTRIDE + n_ * 16 + l16] = f2b(acc[t_][n_][r_] + pbv[n_]); \
    }                                                                            \
    _Pragma("unroll") for (int t_ = 0; t_ < 2; ++t_)                             \
    _Pragma("unroll") for (int n_ = 0; n_ < 8; ++n_) acc[t_][n_] = (f32x4){0.f, 0.f, 0.f, 0.f}; \
} while (0)

#define EPI_LN(BV, GV, BEV) do {                                                 \
    _Pragma("unroll") for (int t_ = 0; t_ < 2; ++t_)                             \
    _Pragma("unroll") for (int r_ = 0; r_ < 4; ++r_) {                           \
        int lr_ = lrow0 + t_ * 16 + quad * 4 + r_;                               \
        float x_[8];                                                             \
        _Pragma("unroll") for (int n_ = 0; n_ < 8; ++n_) x_[n_] = gelu_tanh(acc[t_][n_][r_] + BV[n_]); \
        ln8(x_, GV, BEV);                                                        \
        _Pragma("unroll") for (int n_ = 0; n_ < 8; ++n_)                         \
            lds_x[lr_ * XSTRIDE + n_ * 16 + l16] = f2b(x_[n_]);                  \
    }                                                                            \
    _Pragma("unroll") for (int t_ = 0; t_ < 2; ++t_)                             \
    _Pragma("unroll") for (int n_ = 0; n_ < 8; ++n_) acc[t_][n_] = (f32x4){0.f, 0.f, 0.f, 0.f}; \
} while (0)

// ---------------- fused edge pipeline: [L0: inline e_init] proj(K=384) -> MLP1 -> MLP2 + residual ----------------
template<int L0>
__global__ __launch_bounds__(256, 2) void k_edge_fused(
    const ushort_t* __restrict__ bf_proj,
    const ushort_t* __restrict__ bf_w0,
    const ushort_t* __restrict__ bf_w1,
    ushort_t* e_glob,
    const ushort_t* __restrict__ h,
    const int* __restrict__ senders, const int* __restrict__ receivers,
    const void* __restrict__ edges_raw,        // raw edge features [E][2] (dual-dtype), L0 only
    const ushort_t* __restrict__ wedge_arena,  // bvec slots 33..35: w0[128] w1[128] be[128] bf16
    const ushort_t* __restrict__ pb,
    const ushort_t* __restrict__ b0, const ushort_t* __restrict__ g0, const ushort_t* __restrict__ be0,
    const ushort_t* __restrict__ b1, const ushort_t* __restrict__ g1, const ushort_t* __restrict__ be1,
    const int* __restrict__ dflag)
{
    __shared__ __align__(16) ushort_t lds_w[2][64 * 128];
    __shared__ __align__(16) ushort_t lds_x[128 * XSTRIDE];
    __shared__ __align__(16) ushort_t wedge[512];   // 1 KB: w0|w1|be (+overread pad)
    const int tid  = threadIdx.x;
    const int wave = tid >> 6, lane = tid & 63;
    const int quad = lane >> 4, l16 = lane & 15;
    const int row0  = blockIdx.x * 128;   // 320000 % 128 == 0: all rows valid
    const int lrow0 = wave * 32;
    const bool f32g = L0 ? (*dflag != 0) : false;

    // hoist all epilogue constants so no stray VMEM perturbs vmcnt counting
    float pbv[8], b0v[8], g0v[8], be0v[8], b1v[8], g1v[8], be1v[8];
#pragma unroll
    for (int n = 0; n < 8; ++n) {
        int col = n * 16 + l16;
        pbv[n]  = b2f(pb[col]);
        b0v[n]  = b2f(b0[col]);  g0v[n] = b2f(g0[col]);  be0v[n] = b2f(be0[col]);
        b1v[n]  = b2f(b1[col]);  g1v[n] = b2f(g1[col]);  be1v[n] = b2f(be1[col]);
    }

    // A-source pointers (E-stage pointers only needed for L1)
    const ushort_t* apE[2]; const ushort_t* apS[2]; const ushort_t* apR[2];
#pragma unroll
    for (int t = 0; t < 2; ++t) {
        int grow = row0 + lrow0 + t * 16 + l16;
        apE[t] = e_glob + (size_t)grow * 128 + quad * 8;
        apS[t] = h + (size_t)clampi(senders[grow],   N_NODES) * 128 + quad * 8;
        apR[t] = h + (size_t)clampi(receivers[grow], N_NODES) * 128 + quad * 8;
    }

    // chunk pointers (16 KB = 8192 ushort each)
    const ushort_t* p0a = bf_proj;             const ushort_t* p0b = bf_proj + 8192;
    const ushort_t* p1a = bf_proj + 16384;     const ushort_t* p1b = bf_proj + 24576;
    const ushort_t* p2a = bf_proj + 32768;     const ushort_t* p2b = bf_proj + 40960;
    const ushort_t* w0a = bf_w0;               const ushort_t* w0b = bf_w0 + 8192;
    const ushort_t* w1a = bf_w1;               const ushort_t* w1b = bf_w1 + 8192;

    f32x4 acc[2][8];
#pragma unroll
    for (int t = 0; t < 2; ++t)
#pragma unroll
        for (int n = 0; n < 8; ++n) acc[t][n] = (f32x4){0.f, 0.f, 0.f, 0.f};

    short8 afA[2][2], afB[2][2];

    if (L0) {
        // stage wedge table (wave 0: 64 lanes x 16B = 1 KB, overreads into spare slot)
        if (wave == 0)
            gload_lds16(wedge_arena + (size_t)lane * 8, wedge + (size_t)lane * 8);
        // per-lane edge feature loads (2 rows)
        float a0f[2], a1f[2];
#pragma unroll
        for (int t = 0; t < 2; ++t) {
            int grow = row0 + lrow0 + t * 16 + l16;
            ldedge(edges_raw, grow, f32g, a0f[t], a1f[t]);
        }
        asm volatile("s_waitcnt vmcnt(0)" ::: "memory");
        __builtin_amdgcn_s_barrier();
        // compute both e-chunk A-fragments in registers (no VMEM)
        short8 afE0[2][2], afE1[2][2];
#pragma unroll
        for (int t = 0; t < 2; ++t)
#pragma unroll
            for (int k = 0; k < 2; ++k) {
                afE0[t][k] = einit8(wedge, (0 * 2 + k) * 32 + quad * 8, a0f[t], a1f[t]);
                afE1[t][k] = einit8(wedge, (1 * 2 + k) * 32 + quad * 8, a0f[t], a1f[t]);
            }
        STAGE(p0a, 0);
        // ledger: E0 [S0,S1]->vmcnt4 | E1 [S1,A0,S2]->vmcnt8 | S0..R0 [A,S,A,S]->vmcnt8 | R1 [A,S5,S6]->vmcnt4
        PCH(afE0, afA, apS, 0, 0, p0b, 1, 4, 0, 1);
        PCH(afE1, afA, apS, 0, 1, p1a, 0, 8, 1, 1);
        PCH(afA,  afB, apS, 1, 0, p1b, 1, 8, 1, 1);
        PCH(afB,  afA, apR, 0, 1, p2a, 0, 8, 1, 1);
        PCH(afA,  afB, apR, 1, 0, p2b, 1, 8, 1, 1);
        PCH(afB,  afA, apR, 1, 1, w0a, 0, 4, 0, 1);
    } else {
        LOADA(afA, apE, 0);
        __builtin_amdgcn_sched_barrier(0);
        STAGE(p0a, 0);
        PCH(afA, afB, apE, 1, 0, p0b, 1, 8, 1, 1);
        PCH(afB, afA, apS, 0, 1, p1a, 0, 8, 1, 1);
        PCH(afA, afB, apS, 1, 0, p1b, 1, 8, 1, 1);
        PCH(afB, afA, apR, 0, 1, p2a, 0, 8, 1, 1);
        PCH(afA, afB, apR, 1, 0, p2b, 1, 8, 1, 1);
        PCH(afB, afA, apR, 1, 1, w0a, 0, 4, 0, 1);
    }
    EPI_PROJ();                          // wave-private lds_x; overlaps w0a flight
    XCHUNK(0, 0, 1, w0b, 1, 4);
    XCHUNK(1, 1, 1, w1a, 0, 4);
    EPI_LN(b0v, g0v, be0v);              // MLP1 epilogue; overlaps w1a flight
    XCHUNK(0, 0, 1, w1b, 1, 4);
    XCHUNK(1, 1, 0, w1b, 0, 0);
    EPI_LN(b1v, g1v, be1v);              // final LN -> lds_x

    __syncthreads();
#pragma unroll
    for (int it = 0; it < 8; ++it) {
        int idx  = it * 256 + tid;          // 0..2047 -> 128 rows x 16 chunks
        int lrow = idx >> 4;
        int c8   = (idx & 15) << 3;
        size_t goff = (size_t)(row0 + lrow) * 128 + c8;
        short8 xv = *(const short8*)(lds_x + lrow * XSTRIDE + c8);
        short8 yv;
        if (L0) {
            // residual base = e_init recomputed in f32 (never materialized)
            float ea0, ea1;
            ldedge(edges_raw, row0 + lrow, f32g, ea0, ea1);
            short8 w0 = *(const short8*)(wedge + c8);
            short8 w1 = *(const short8*)(wedge + 128 + c8);
            short8 bb = *(const short8*)(wedge + 256 + c8);
#pragma unroll
            for (int j = 0; j < 8; ++j) {
                float base = ea0 * b2f((ushort_t)w0[j]) + ea1 * b2f((ushort_t)w1[j]) + b2f((ushort_t)bb[j]);
                yv[j] = (short)f2b(base + b2f((ushort_t)xv[j]));
            }
        } else {
            short8 ev = *(const short8*)(e_glob + goff);
#pragma unroll
            for (int j = 0; j < 8; ++j)
                yv[j] = (short)f2b(b2f((ushort_t)ev[j]) + b2f((ushort_t)xv[j]));
        }
        *(short8*)(e_glob + goff) = yv;
    }
}

// ---------------- fused node pipeline: proj(K=256) -> MLP1 -> MLP2 + residual ----------------
__global__ __launch_bounds__(256, 2) void k_node_fused(
    const ushort_t* __restrict__ bf_proj,
    const ushort_t* __restrict__ bf_w0,
    const ushort_t* __restrict__ bf_w1,
    ushort_t* h,
    const ushort_t* __restrict__ agg,
    const ushort_t* __restrict__ pb,
    const ushort_t* __restrict__ b0, const ushort_t* __restrict__ g0, const ushort_t* __restrict__ be0,
    const ushort_t* __restrict__ b1, const ushort_t* __restrict__ g1, const ushort_t* __restrict__ be1,
    int rows)
{
    __shared__ __align__(16) ushort_t lds_w[2][64 * 128];
    __shared__ __align__(16) ushort_t lds_x[128 * XSTRIDE];
    const int tid  = threadIdx.x;
    const int wave = tid >> 6, lane = tid & 63;
    const int quad = lane >> 4, l16 = lane & 15;
    const int row0  = blockIdx.x * 128;
    const int lrow0 = wave * 32;

    float pbv[8], b0v[8], g0v[8], be0v[8], b1v[8], g1v[8], be1v[8];
#pragma unroll
    for (int n = 0; n < 8; ++n) {
        int col = n * 16 + l16;
        pbv[n]  = b2f(pb[col]);
        b0v[n]  = b2f(b0[col]);  g0v[n] = b2f(g0[col]);  be0v[n] = b2f(be0[col]);
        b1v[n]  = b2f(b1[col]);  g1v[n] = b2f(g1[col]);  be1v[n] = b2f(be1[col]);
    }

    const ushort_t* apH[2]; const ushort_t* apA[2];
#pragma unroll
    for (int t = 0; t < 2; ++t) {
        int grow = row0 + lrow0 + t * 16 + l16;
        int rr = grow < rows ? grow : rows - 1;
        apH[t] = h   + (size_t)rr * 128 + quad * 8;
        apA[t] = agg + (size_t)rr * 128 + quad * 8;
    }

    const ushort_t* n0a = bf_proj;           const ushort_t* n0b = bf_proj + 8192;
    const ushort_t* n1a = bf_proj + 16384;   const ushort_t* n1b = bf_proj + 24576;
    const ushort_t* w0a = bf_w0;             const ushort_t* w0b = bf_w0 + 8192;
    const ushort_t* w1a = bf_w1;             const ushort_t* w1b = bf_w1 + 8192;

    f32x4 acc[2][8];
#pragma unroll
    for (int t = 0; t < 2; ++t)
#pragma unroll
        for (int n = 0; n < 8; ++n) acc[t][n] = (f32x4){0.f, 0.f, 0.f, 0.f};

    short8 afA[2][2], afB[2][2];
    LOADA(afA, apH, 0);
    __builtin_amdgcn_sched_barrier(0);
    STAGE(n0a, 0);
    PCH(afA, afB, apH, 1, 0, n0b, 1, 8, 1, 1);
    PCH(afB, afA, apA, 0, 1, n1a, 0, 8, 1, 1);
    PCH(afA, afB, apA, 1, 0, n1b, 1, 8, 1, 1);
    PCH(afB, afA, apA, 1, 1, w0a, 0, 4, 0, 1);   // last P-chunk: no next-A -> vmcnt(4)
    EPI_PROJ();
    XCHUNK(0, 0, 1, w0b, 1, 4);
    XCHUNK(1, 1, 1, w1a, 0, 4);
    EPI_LN(b0v, g0v, be0v);
    XCHUNK(0, 0, 1, w1b, 1, 4);
    XCHUNK(1, 1, 0, w1b, 0, 0);
    EPI_LN(b1v, g1v, be1v);

    __syncthreads();
#pragma unroll
    for (int it = 0; it < 8; ++it) {
        int idx  = it * 256 + tid;
        int lrow = idx >> 4;
        int c8   = (idx & 15) << 3;
        int grow = row0 + lrow;
        if (grow < rows) {
            size_t goff = (size_t)grow * 128 + c8;
            short8 xv = *(const short8*)(lds_x + lrow * XSTRIDE + c8);
            short8 hv = *(const short8*)(h + goff);
            short8 yv;
#pragma unroll
            for (int j = 0; j < 8; ++j)
                yv[j] = (short)f2b(b2f((ushort_t)hv[j]) + b2f((ushort_t)xv[j]));
            *(short8*)(h + goff) = yv;
        }
    }
}

extern "C" void kernel_launch(void* const* d_in, const int* in_sizes, int n_in,
                              void* d_out, int out_size, void* d_ws, size_t ws_size,
                              hipStream_t stream) {
    const void* nodes        = d_in[0];
    const void* edges        = d_in[1];
    const int*  senders      = (const int*)d_in[2];
    const int*  receivers    = (const int*)d_in[3];
    const void* w_node_emb   = d_in[4];
    const void* b_node_emb   = d_in[5];
    const void* w_edge_emb   = d_in[6];
    const void* b_edge_emb   = d_in[7];
    const void* edge_proj_w  = d_in[8];
    const void* edge_proj_b  = d_in[9];
    const void* node_proj_w  = d_in[10];
    const void* node_proj_b  = d_in[11];
    const void* edge_mlp_w   = d_in[12];
    const void* edge_mlp_b   = d_in[13];
    const void* edge_ln_g    = d_in[14];
    const void* edge_ln_b    = d_in[15];
    const void* node_mlp_w   = d_in[16];
    const void* node_mlp_b   = d_in[17];
    const void* node_ln_g    = d_in[18];
    const void* node_ln_b    = d_in[19];
    const void* mlp_out_w    = d_in[20];
    const void* mlp_out_b    = d_in[21];
    const void* mlp_out_g    = d_in[22];
    const void* mlp_out_beta = d_in[23];
    const void* proj_w       = d_in[24];
    const void* proj_b       = d_in[25];

    char* ws = (char*)d_ws;
    ushort_t* bf_nodeemb  = (ushort_t*)ws;  ws += (size_t)288 * 128 * 2;   // frag arena start
    ushort_t* bf_edgeproj = (ushort_t*)ws;  ws += (size_t)768 * 128 * 2;
    ushort_t* bf_nodeproj = (ushort_t*)ws;  ws += (size_t)512 * 128 * 2;
    ushort_t* bf_edgemlp  = (ushort_t*)ws;  ws += (size_t)512 * 128 * 2;
    ushort_t* bf_nodemlp  = (ushort_t*)ws;  ws += (size_t)512 * 128 * 2;
    ushort_t* bf_mlpout   = (ushort_t*)ws;  ws += (size_t)128 * 128 * 2;
    ushort_t* h    = (ushort_t*)ws;         ws += (size_t)N_NODES * D * 2;
    ushort_t* e    = (ushort_t*)ws;         ws += (size_t)N_EDGES * D * 2;
    ushort_t* agg  = (ushort_t*)ws;         ws += (size_t)N_NODES * D * 2;
    int*      cnti = (int*)ws;              ws += (size_t)N_NODES * 4;
    int*      offs = (int*)ws;              ws += (size_t)N_NODES * 4;
    int*      curs = (int*)ws;              ws += (size_t)N_NODES * 4;
    int*      eid  = (int*)ws;              ws += (size_t)N_EDGES * 4;
    int*      flag = (int*)ws;              ws += 256;
    ushort_t* bvec = (ushort_t*)ws;         ws += (size_t)37 * 128 * 2;   // bf16 bias arena (+DMA overread pad)
    ushort_t* wT   = (ushort_t*)ws;         ws += (size_t)24 * 128 * 2;   // projT bf16

    hipMemsetAsync(flag, 0, 256, stream);
    k_detect<<<256, 256, 0, stream>>>((const uint32_t*)nodes, flag);

    // consolidated setup (bias packs + projT + all 6 B-fragment transforms in one launch)
    // bvec slots: 0 b_node_emb | 1 b_edge_emb | 2,3 edge_proj_b | 4,5 node_proj_b | 6..9 edge_mlp_b
    // 10..13 edge_ln_g | 14..17 edge_ln_b | 18..21 node_mlp_b | 22..25 node_ln_g
    // 26..29 node_ln_b | 30 mlp_out_b | 31 mlp_out_g | 32 mlp_out_beta
    // 33,34 w_edge_emb | 35 b_edge_emb (wedge table, contiguous for LDS-DMA) | 36 pad
    {
        SetupArgs sa;
        const void* ps[15] = { b_node_emb, b_edge_emb, edge_proj_b, node_proj_b,
                               edge_mlp_b, edge_ln_g, edge_ln_b,
                               node_mlp_b, node_ln_g, node_ln_b,
                               mlp_out_b, mlp_out_g, mlp_out_beta,
                               w_edge_emb, b_edge_emb };
        const int   pn[15] = { 128, 128, 256, 256, 512, 512, 512, 512, 512, 512, 128, 128, 128, 256, 128 };
        const int   pd[15] = { 0, 1, 2, 4, 6, 10, 14, 18, 22, 26, 30, 31, 32, 33, 35 };
        const void* fs[6]  = { w_node_emb, edge_proj_w, node_proj_w, edge_mlp_w, node_mlp_w, mlp_out_w };
        const int   fk[6]  = { 9, 24, 16, 16, 16, 4 };
        const int   fd[6]  = { 0, 36864, 135168, 200704, 266240, 331776 };  // ushort offsets, contiguous arena
        for (int i = 0; i < 15; ++i) { sa.psrc[i] = ps[i]; sa.pn[i] = pn[i]; sa.pdst[i] = pd[i]; }
        for (int i = 0; i < 6;  ++i) { sa.fsrc[i] = fs[i]; sa.fkb[i] = fk[i]; sa.fdst[i] = fd[i]; }
        sa.projw = proj_w;
        // total threads: 4608 (packs) + 3072 (projT) + 43520 (bfrag) = 51200 -> 200 blocks
        k_setup<<<200, 256, 0, stream>>>(sa, bvec, bf_nodeemb, wT, flag);
    }

    // CSR build (receivers constant across both layers)
    hipMemsetAsync(cnti, 0, (size_t)N_NODES * 4, stream);
    k_counti<<<(N_EDGES + 255) / 256, 256, 0, stream>>>(receivers, cnti, N_EDGES);
    k_scan<<<1, 1024, 0, stream>>>(cnti, offs, curs);
    k_fill<<<(N_EDGES + 255) / 256, 256, 0, stream>>>(receivers, curs, eid, N_EDGES);

    {
        const int grid = (N_NODES + 127) / 128;
        k_gemm<3, false><<<grid, 256, 0, stream>>>(
            bf_nodeemb,
            nodes, 1, 288, 0,   128,
            nodes, 1, 288, 128, 128,
            nodes, 1, 288, 256, 32,
            N_NODES, bvec + 0 * 128, nullptr, nullptr, h, flag);
    }

    const int gridE = N_EDGES / 128;           // 2500
    const int gridN = (N_NODES + 127) / 128;   // 157

    for (int l = 0; l < 2; ++l) {
        if (l == 0) {
            k_edge_fused<1><<<gridE, 256, 0, stream>>>(
                bf_edgeproj,
                bf_edgemlp + (size_t)0 * 128 * 128,
                bf_edgemlp + (size_t)1 * 128 * 128,
                e, h, senders, receivers,
                edges, bvec + 33 * 128,
                bvec + 2 * 128,
                bvec + 6 * 128,  bvec + 10 * 128, bvec + 14 * 128,
                bvec + 7 * 128,  bvec + 11 * 128, bvec + 15 * 128,
                flag);
        } else {
            k_edge_fused<0><<<gridE, 256, 0, stream>>>(
                bf_edgeproj + (size_t)384 * 128,
                bf_edgemlp + (size_t)2 * 128 * 128,
                bf_edgemlp + (size_t)3 * 128 * 128,
                e, h, senders, receivers,
                edges, bvec + 33 * 128,
                bvec + 3 * 128,
                bvec + 8 * 128,  bvec + 12 * 128, bvec + 16 * 128,
                bvec + 9 * 128,  bvec + 13 * 128, bvec + 17 * 128,
                flag);
        }
        k_agg<<<(N_NODES + 7) / 8, 256, 0, stream>>>(e, offs, cnti, eid, agg);
        k_node_fused<<<gridN, 256, 0, stream>>>(
            bf_nodeproj + (size_t)l * 256 * 128,
            bf_nodemlp + (size_t)(l * 2 + 0) * 128 * 128,
            bf_nodemlp + (size_t)(l * 2 + 1) * 128 * 128,
            h, agg,
            bvec + (size_t)(4 + l) * 128,
            bvec + (size_t)(18 + l * 2) * 128,     bvec + (size_t)(22 + l * 2) * 128,     bvec + (size_t)(26 + l * 2) * 128,
            bvec + (size_t)(18 + l * 2 + 1) * 128, bvec + (size_t)(22 + l * 2 + 1) * 128, bvec + (size_t)(26 + l * 2 + 1) * 128,
            N_NODES);
    }

    // fused: mlp_out GEMM + gelu + LN + projection straight to d_out
    k_out<<<gridN, 256, 0, stream>>>(
        bf_mlpout, h,
        bvec + 30 * 128, bvec + 31 * 128, bvec + 32 * 128,
        wT, proj_b, d_out, N_NODES, flag);
}

// Round 12
// 602.107 us; speedup vs baseline: 1.3586x; 1.0771x over previous
//
#include <hip/hip_runtime.h>
#include <hip/hip_bf16.h>
#include <stdint.h>

typedef unsigned short ushort_t;
typedef __attribute__((ext_vector_type(8))) short short8;
typedef __attribute__((ext_vector_type(4))) short short4v;
typedef __attribute__((ext_vector_type(4))) float f32x4;
typedef __attribute__((ext_vector_type(4))) int int4v;

#define N_NODES 20000
#define N_EDGES 320000
#define D 128
#define XSTRIDE 136   // padded LDS row stride (ushorts)

#define GAS __attribute__((address_space(1)))
#define LAS __attribute__((address_space(3)))

__device__ __forceinline__ float b2f(ushort_t u) {
    union { float f; uint32_t i; } v; v.i = ((uint32_t)u) << 16; return v.f;
}
// native RNE f32->bf16 (bit-identical to the old integer-trick RNE); compiler pairs
// adjacent casts into v_cvt_pk_bf16_f32 (~0.5 VALU op/elem vs ~4.5 for the bit trick)
__device__ __forceinline__ ushort_t f2b(float f) {
    __bf16 h = (__bf16)f;
    return __builtin_bit_cast(ushort_t, h);
}
// dtype-flexible scalar load: raw input arrays may be f32 or bf16 (runtime-detected)
__device__ __forceinline__ float ldf(const void* p, size_t i, bool f32) {
    return f32 ? ((const float*)p)[i] : b2f(((const ushort_t*)p)[i]);
}
// dtype-flexible 8-element A-fragment load (8 consecutive elements, 8-aligned index)
__device__ __forceinline__ short8 lda8(const void* p, size_t i, bool f32) {
    if (f32) {
        const float* fp = (const float*)p + i;
        f32x4 v0 = *(const f32x4*)fp;
        f32x4 v1 = *(const f32x4*)(fp + 4);
        short8 a;
#pragma unroll
        for (int j = 0; j < 4; ++j) {
            a[j]     = (short)f2b(v0[j]);
            a[j + 4] = (short)f2b(v1[j]);
        }
        return a;
    }
    return *(const short8*)((const ushort_t*)p + i);
}
// tanh-gelu with fast reciprocal (v_rcp_f32, ~1ulp) instead of full-precision division
__device__ __forceinline__ float gelu_tanh(float x) {
    float u = 0.7978845608028654f * (x + 0.044715f * x * x * x);
    u = fminf(fmaxf(u, -15.f), 15.f);
    float e = __expf(2.f * u);
    float t = (e - 1.f) * __builtin_amdgcn_rcpf(e + 1.f);
    return 0.5f * x * (1.f + t);
}
__device__ __forceinline__ int clampi(int v, int hi) {  // [0, hi)
    return v < 0 ? 0 : (v >= hi ? hi - 1 : v);
}
// async 16B global->LDS (linear dest, lane-ordered — matches wave-uniform-base+lane*16)
__device__ __forceinline__ void gload_lds16(const void* g, void* l) {
    __builtin_amdgcn_global_load_lds((const GAS uint32_t*)g, (LAS uint32_t*)l, 16, 0, 0);
}
// dual-dtype edge row load (2 scalars)
__device__ __forceinline__ void ldedge(const void* edges, int row, bool f32, float& a0, float& a1) {
    if (f32) {
        const float* p = (const float*)edges + (size_t)row * 2;
        a0 = p[0]; a1 = p[1];
    } else {
        const ushort_t* p = (const ushort_t*)edges + (size_t)row * 2;
        a0 = b2f(p[0]); a1 = b2f(p[1]);
    }
}
// e_init fragment: 8 consecutive cols of a0*w0 + a1*w1 + b from the wedge LDS table
__device__ __forceinline__ short8 einit8(const ushort_t* wedge, int colbase, float a0, float a1) {
    short8 w0 = *(const short8*)(wedge + colbase);
    short8 w1 = *(const short8*)(wedge + 128 + colbase);
    short8 bb = *(const short8*)(wedge + 256 + colbase);
    short8 r;
#pragma unroll
    for (int j = 0; j < 8; ++j)
        r[j] = (short)f2b(a0 * b2f((ushort_t)w0[j]) + a1 * b2f((ushort_t)w1[j]) + b2f((ushort_t)bb[j]));
    return r;
}

// row-wise LN over 128 cols spread as x[n] on 16 lanes (same quad group)
__device__ __forceinline__ void ln8(float x[8], const float gv[8], const float bv[8]) {
    float s1 = 0.f, s2 = 0.f;
#pragma unroll
    for (int n = 0; n < 8; ++n) { s1 += x[n]; s2 += x[n] * x[n]; }
#pragma unroll
    for (int m = 1; m < 16; m <<= 1) {
        s1 += __shfl_xor(s1, m, 64);
        s2 += __shfl_xor(s2, m, 64);
    }
    float mean = s1 * (1.f / 128.f);
    float var  = fmaxf(s2 * (1.f / 128.f) - mean * mean, 0.f);
    float rs   = __builtin_amdgcn_rsqf(var + 1e-5f);
#pragma unroll
    for (int n = 0; n < 8; ++n) x[n] = (x[n] - mean) * rs * gv[n] + bv[n];
}

// Detect whether float inputs are f32 (flag=1) or bf16 (flag=0).
__global__ void k_detect(const uint32_t* __restrict__ raw, int* __restrict__ flag) {
    int t = blockIdx.x * blockDim.x + threadIdx.x;   // 65536 threads
    uint32_t u = raw[t];
    int e_lo = (u >> 7)  & 0xFF;
    int e_hi = (u >> 23) & 0xFF;
    if (e_lo == 0xFF || e_hi == 0xFF) atomicOr(flag, 1);
}

// ---------------- consolidated setup: bias packs + projT + all B-fragment transforms ----------------
// region 0: [0, 4608)            bias/gamma/beta/w_edge_emb packs into bvec slots
// region 1: [4608, 7680)         proj_w [128x24] -> wT [24x128]
// region 2: [7680, 7680+43520)   6 weights -> MFMA B-fragment arena (contiguous)
struct SetupArgs {
    const void* psrc[15];
    int         pn[15];
    int         pdst[15];
    const void* fsrc[6];
    int         fkb[6];
    int         fdst[6];     // dst offset into frag arena (ushort units)
    const void* projw;
};

__global__ void k_setup(SetupArgs a, ushort_t* __restrict__ bvec, ushort_t* __restrict__ frag,
                        ushort_t* __restrict__ wT, const int* __restrict__ dflag) {
    const bool f32 = *dflag != 0;
    int t = blockIdx.x * blockDim.x + threadIdx.x;
    if (t < 4608) {                      // bias packs
        int i = t, d = 0;
        while (i >= a.pn[d]) { i -= a.pn[d]; ++d; }
        bvec[(size_t)a.pdst[d] * 128 + i] = f2b(ldf(a.psrc[d], i, f32));
        return;
    }
    t -= 4608;
    if (t < 3072) {                      // projT
        int p = t >> 7, k = t & 127;
        wT[p * 128 + k] = f2b(ldf(a.projw, (size_t)k * 24 + p, f32));
        return;
    }
    t -= 3072;
    if (t >= 43520) return;              // bfrag region: sum(fkb)=85 -> 85*512 groups
    int g = t, d = 0;
    while (g >= a.fkb[d] * 512) { g -= a.fkb[d] * 512; ++d; }
    const void* src = a.fsrc[d];
    int kblk = g >> 9;
    int rem  = g & 511;
    int nt   = rem >> 6;
    int lane = rem & 63;
    int krow = kblk * 32 + ((lane >> 4) << 3);
    int col  = nt * 16 + (lane & 15);
    short8 v;
#pragma unroll
    for (int j = 0; j < 8; ++j) v[j] = (short)f2b(ldf(src, (size_t)(krow + j) * 128 + col, f32));
    *(short8*)(frag + (size_t)a.fdst[d] + (size_t)g * 8) = v;
}

// ---------------- CSR build for receiver-side aggregation ----------------
__global__ void k_counti(const int* __restrict__ recv, int* __restrict__ cnti, int E) {
    int i = blockIdx.x * blockDim.x + threadIdx.x;
    if (i < E) atomicAdd(&cnti[clampi(recv[i], N_NODES)], 1);
}

// single-block exclusive scan of cnti -> offs (and cursor copy)
__global__ void k_scan(const int* __restrict__ cnti, int* __restrict__ offs,
                       int* __restrict__ cursor) {
    __shared__ int part[1024];
    const int t = threadIdx.x;           // blockDim = 1024
    const int base = t * 20;             // 1024*20 = 20480 >= N_NODES
    int s = 0;
#pragma unroll 4
    for (int j = 0; j < 20; ++j) {
        int idx = base + j;
        if (idx < N_NODES) s += cnti[idx];
    }
    part[t] = s;
    __syncthreads();
    for (int off = 1; off < 1024; off <<= 1) {
        int v = (t >= off) ? part[t - off] : 0;
        __syncthreads();
        part[t] += v;
        __syncthreads();
    }
    int run = (t == 0) ? 0 : part[t - 1];   // exclusive prefix
    for (int j = 0; j < 20; ++j) {
        int idx = base + j;
        if (idx < N_NODES) {
            offs[idx]   = run;
            cursor[idx] = run;
            run += cnti[idx];
        }
    }
}

__global__ void k_fill(const int* __restrict__ recv, int* __restrict__ cursor,
                       int* __restrict__ eid, int E) {
    int i = blockIdx.x * blockDim.x + threadIdx.x;
    if (i < E) {
        int r = clampi(recv[i], N_NODES);
        int pos = atomicAdd(&cursor[r], 1);
        eid[pos] = i;
    }
}

// gather-mean aggregation: agg[n] = mean over incident edges of e[eid] (bf16 out)
__global__ void k_agg(const ushort_t* __restrict__ e, const int* __restrict__ offs,
                      const int* __restrict__ cnti, const int* __restrict__ eid,
                      ushort_t* __restrict__ agg) {
    const int tid = threadIdx.x;
    const int n = blockIdx.x * 8 + (tid >> 5);   // 8 nodes / 256-thread block
    const int l = tid & 31;                      // 32 lanes x 4 cols = 128 cols
    if (n >= N_NODES) return;
    const int start = offs[n], deg = cnti[n];
    float s0 = 0.f, s1 = 0.f, s2 = 0.f, s3 = 0.f;
    for (int j = 0; j < deg; ++j) {
        const ushort_t* row = e + (size_t)eid[start + j] * 128 + l * 4;
        short4v v = *(const short4v*)row;
        s0 += b2f((ushort_t)v[0]);
        s1 += b2f((ushort_t)v[1]);
        s2 += b2f((ushort_t)v[2]);
        s3 += b2f((ushort_t)v[3]);
    }
    const float inv = 1.f / (float)(deg < 1 ? 1 : deg);
    short4v o;
    o[0] = (short)f2b(s0 * inv);
    o[1] = (short)f2b(s1 * inv);
    o[2] = (short)f2b(s2 * inv);
    o[3] = (short)f2b(s3 * inv);
    *(short4v*)(agg + (size_t)n * 128 + l * 4) = o;
}

// ---------------- generic GEMM (node embedding) ----------------
template<int NC, bool LN>
__global__ __launch_bounds__(256, 2) void k_gemm(
    const ushort_t* __restrict__ bfrag,
    const void* s0, int isf0, int st0, int ko0, int kl0,
    const void* s1, int isf1, int st1, int ko1, int kl1,
    const void* s2, int isf2, int st2, int ko2, int kl2,
    int rows,
    const ushort_t* __restrict__ bias,
    const ushort_t* __restrict__ gamma,
    const ushort_t* __restrict__ betap,
    ushort_t* out,
    const int* __restrict__ dflag)
{
    __shared__ __align__(16) ushort_t lds_b[128 * 128];
    const bool f32g = *dflag != 0;
    const int tid  = threadIdx.x;
    const int wave = tid >> 6, lane = tid & 63;
    const int quad = lane >> 4, l16 = lane & 15;
    const int row0 = blockIdx.x * 128 + wave * 32;

    f32x4 acc[2][8];
#pragma unroll
    for (int t = 0; t < 2; ++t)
#pragma unroll
        for (int n = 0; n < 8; ++n) acc[t][n] = (f32x4){0.f, 0.f, 0.f, 0.f};

    const ushort_t* bptr = bfrag;
#pragma unroll
    for (int c = 0; c < NC; ++c) {
        const void* src  = (c == 0) ? s0 : ((c == 1) ? s1 : s2);
        const bool  eff  = (((c == 0) ? isf0 : ((c == 1) ? isf1 : isf2)) != 0) && f32g;
        const int stride = (c == 0) ? st0 : ((c == 1) ? st1 : st2);
        const int koff   = (c == 0) ? ko0 : ((c == 1) ? ko1 : ko2);
        const int klen   = (c == 0) ? kl0 : ((c == 1) ? kl1 : kl2);

        if (c) __syncthreads();
        {
            const int ngrp = klen * 16;
            for (int g = tid; g < ngrp; g += 256)
                gload_lds16(bptr + (size_t)g * 8, lds_b + (size_t)g * 8);
        }
        __syncthreads();   // full drain: staging resident

        size_t aoff[2];
#pragma unroll
        for (int t = 0; t < 2; ++t) {
            int r  = row0 + t * 16 + l16;
            int rr = r < rows ? r : rows - 1;
            aoff[t] = (size_t)rr * stride + koff + quad * 8;
        }
        const int ksteps = klen >> 5;
        for (int ks = 0; ks < ksteps; ++ks) {
            short8 af[2];
#pragma unroll
            for (int t = 0; t < 2; ++t)
                af[t] = lda8(src, aoff[t] + ks * 32, eff);
#pragma unroll
            for (int n = 0; n < 8; ++n) {
                short8 bf = *(const short8*)(lds_b + (size_t)((ks * 8 + n) * 64 + lane) * 8);
                acc[0][n] = __builtin_amdgcn_mfma_f32_16x16x32_bf16(af[0], bf, acc[0][n], 0, 0, 0);
                acc[1][n] = __builtin_amdgcn_mfma_f32_16x16x32_bf16(af[1], bf, acc[1][n], 0, 0, 0);
            }
        }
        bptr += (size_t)klen * 128;
    }

    float bv[8], gv[8], btv[8];
#pragma unroll
    for (int n = 0; n < 8; ++n) {
        int col = n * 16 + l16;
        bv[n] = b2f(bias[col]);
        if (LN) { gv[n] = b2f(gamma[col]); btv[n] = b2f(betap[col]); }
    }
#pragma unroll
    for (int t = 0; t < 2; ++t) {
#pragma unroll
        for (int r = 0; r < 4; ++r) {
            int row = row0 + t * 16 + quad * 4 + r;
            float x[8];
#pragma unroll
            for (int n = 0; n < 8; ++n) x[n] = acc[t][n][r] + bv[n];
            if (LN) {
#pragma unroll
                for (int n = 0; n < 8; ++n) x[n] = gelu_tanh(x[n]);
                ln8(x, gv, btv);
            }
            if (row < rows) {
#pragma unroll
                for (int n = 0; n < 8; ++n)
                    out[(size_t)row * 128 + n * 16 + l16] = f2b(x[n]);
            }
        }
    }
}

// ---------------- fused output: mlp_out GEMM + gelu + LN + projection to d_out ----------------
__global__ __launch_bounds__(256, 2) void k_out(
    const ushort_t* __restrict__ bfrag,     // bf_mlpout
    const ushort_t* __restrict__ h,
    const ushort_t* __restrict__ bias,
    const ushort_t* __restrict__ gamma,
    const ushort_t* __restrict__ betap,
    const ushort_t* __restrict__ wT,        // [24][128] bf16
    const void* __restrict__ pb,            // proj_b raw
    void* __restrict__ out, int rows,
    const int* __restrict__ dflag)
{
    __shared__ __align__(16) ushort_t lds_b[128 * 128];
    __shared__ __align__(16) ushort_t lds_x[128 * XSTRIDE];
    const bool f32g = *dflag != 0;
    const int tid  = threadIdx.x;
    const int wave = tid >> 6, lane = tid & 63;
    const int quad = lane >> 4, l16 = lane & 15;
    const int row0  = blockIdx.x * 128;
    const int lrow0 = wave * 32;

    for (int g = tid; g < 2048; g += 256)
        gload_lds16(bfrag + (size_t)g * 8, lds_b + (size_t)g * 8);
    __syncthreads();

    f32x4 acc[2][8];
#pragma unroll
    for (int t = 0; t < 2; ++t)
#pragma unroll
        for (int n = 0; n < 8; ++n) acc[t][n] = (f32x4){0.f, 0.f, 0.f, 0.f};

    const ushort_t* ap[2];
#pragma unroll
    for (int t = 0; t < 2; ++t) {
        int grow = row0 + lrow0 + t * 16 + l16;
        int rr = grow < rows ? grow : rows - 1;
        ap[t] = h + (size_t)rr * 128 + quad * 8;
    }
    for (int ks = 0; ks < 4; ++ks) {
        short8 af[2];
#pragma unroll
        for (int t = 0; t < 2; ++t) af[t] = *(const short8*)(ap[t] + ks * 32);
#pragma unroll
        for (int n = 0; n < 8; ++n) {
            short8 bf = *(const short8*)(lds_b + (size_t)((ks * 8 + n) * 64 + lane) * 8);
            acc[0][n] = __builtin_amdgcn_mfma_f32_16x16x32_bf16(af[0], bf, acc[0][n], 0, 0, 0);
            acc[1][n] = __builtin_amdgcn_mfma_f32_16x16x32_bf16(af[1], bf, acc[1][n], 0, 0, 0);
        }
    }

    {
        float bv[8], gv[8], btv[8];
#pragma unroll
        for (int n = 0; n < 8; ++n) {
            int col = n * 16 + l16;
            bv[n] = b2f(bias[col]); gv[n] = b2f(gamma[col]); btv[n] = b2f(betap[col]);
        }
#pragma unroll
        for (int t = 0; t < 2; ++t)
#pragma unroll
            for (int r = 0; r < 4; ++r) {
                int lrow = lrow0 + t * 16 + quad * 4 + r;
                float x[8];
#pragma unroll
                for (int n = 0; n < 8; ++n) x[n] = gelu_tanh(acc[t][n][r] + bv[n]);
                ln8(x, gv, btv);
#pragma unroll
                for (int n = 0; n < 8; ++n)
                    lds_x[lrow * XSTRIDE + n * 16 + l16] = f2b(x[n]);
            }
    }
    __syncthreads();

    // projection: 128 rows x 24 outputs = 3072 -> 12 per thread
#pragma unroll
    for (int it = 0; it < 12; ++it) {
        int idx  = it * 256 + tid;
        int lrow = idx / 24;
        int p    = idx - lrow * 24;
        int grow = row0 + lrow;
        if (grow < rows) {
            float a2 = ldf(pb, p, f32g);
            const ushort_t* xp = lds_x + lrow * XSTRIDE;
            const ushort_t* wp = wT + (size_t)p * 128;
#pragma unroll
            for (int k8 = 0; k8 < 16; ++k8) {
                short8 hv = *(const short8*)(xp + k8 * 8);
                short8 wv = *(const short8*)(wp + k8 * 8);
#pragma unroll
                for (int j = 0; j < 8; ++j)
                    a2 += b2f((ushort_t)hv[j]) * b2f((ushort_t)wv[j]);
            }
            if (f32g) ((float*)out)[(size_t)grow * 24 + p] = a2;
            else      ((ushort_t*)out)[(size_t)grow * 24 + p] = f2b(a2);
        }
    }
}

// ======== chunked double-buffered pipeline (T3-min 2-phase + T4 counted vmcnt + T14 A-prefetch) ========
// Chunk = 64-K half of a 128-K stage = 16 KB of B-fragments in lds_w[buf].
// A-fragments are prefetched ONE CHUNK AHEAD into a rotating afA/afB register pair.
// L1 steady-state ledger: [af_cur(4), stage_cur(4), af_next(4), stage_next(4)] -> vmcnt(8).
// L0: the two e-chunk A-fragments are COMPUTED (rank-2 einit, VALU+LDS, no VMEM), so the
// ledger shifts: E0=vmcnt(4), E1..R0=vmcnt(8), R1=vmcnt(4); X-chunks vmcnt(4,4,4,0).

#define STAGE(srcp, bufi) do {                                                   \
    const ushort_t* s__ = (srcp);                                                \
    _Pragma("unroll")                                                            \
    for (int it__ = 0; it__ < 4; ++it__) {                                       \
        int g__ = it__ * 256 + tid;                                              \
        gload_lds16(s__ + (size_t)g__ * 8, &lds_w[bufi][(size_t)g__ * 8]);       \
    } } while (0)

#define LOADA(dst, apv, hf) do {                                                 \
    _Pragma("unroll") for (int t_ = 0; t_ < 2; ++t_)                             \
    _Pragma("unroll") for (int k_ = 0; k_ < 2; ++k_)                             \
        dst[t_][k_] = *(const short8*)(apv[t_] + ((hf) * 2 + k_) * 32);          \
    } while (0)

#define PCH(AFU, AFN, apv, hfn, bufi, nsrc, nbuf, VM, DO_A, DO_STAGE) do {       \
    if (DO_A) LOADA(AFN, apv, hfn);                                              \
    __builtin_amdgcn_sched_barrier(0);                                           \
    if (DO_STAGE) STAGE(nsrc, nbuf);                                             \
    asm volatile("s_waitcnt vmcnt(" #VM ")" ::: "memory");                       \
    __builtin_amdgcn_s_barrier();                                                \
    __builtin_amdgcn_sched_barrier(0);                                           \
    _Pragma("unroll") for (int k_ = 0; k_ < 2; ++k_)                             \
    _Pragma("unroll") for (int n_ = 0; n_ < 8; ++n_) {                           \
        short8 bf_ = *(const short8*)(&lds_w[bufi][(size_t)((k_ * 8 + n_) * 64 + lane) * 8]); \
        acc[0][n_] = __builtin_amdgcn_mfma_f32_16x16x32_bf16(AFU[0][k_], bf_, acc[0][n_], 0, 0, 0); \
        acc[1][n_] = __builtin_amdgcn_mfma_f32_16x16x32_bf16(AFU[1][k_], bf_, acc[1][n_], 0, 0, 0); \
    }                                                                            \
    __builtin_amdgcn_sched_barrier(0);                                           \
    __builtin_amdgcn_s_barrier();                                                \
} while (0)

#define XCHUNK(hf, bufi, DO_STAGE, nsrc, nbuf, VM) do {                          \
    if (DO_STAGE) STAGE(nsrc, nbuf);                                             \
    asm volatile("s_waitcnt vmcnt(" #VM ")" ::: "memory");                       \
    __builtin_amdgcn_s_barrier();                                                \
    __builtin_amdgcn_sched_barrier(0);                                           \
    _Pragma("unroll") for (int k_ = 0; k_ < 2; ++k_) {                           \
        short8 af_[2];                                                           \
        _Pragma("unroll") for (int t_ = 0; t_ < 2; ++t_)                         \
            af_[t_] = *(const short8*)(lds_x + (size_t)(lrow0 + t_ * 16 + l16) * XSTRIDE \
                                       + ((hf) * 2 + k_) * 32 + quad * 8);       \
        _Pragma("unroll") for (int n_ = 0; n_ < 8; ++n_) {                       \
            short8 bf_ = *(const short8*)(&lds_w[bufi][(size_t)((k_ * 8 + n_) * 64 + lane) * 8]); \
            acc[0][n_] = __builtin_amdgcn_mfma_f32_16x16x32_bf16(af_[0], bf_, acc[0][n_], 0, 0, 0); \
            acc[1][n_] = __builtin_amdgcn_mfma_f32_16x16x32_bf16(af_[1], bf_, acc[1][n_], 0, 0, 0); \
        }                                                                        \
    }                                                                            \
    __builtin_amdgcn_sched_barrier(0);                                           \
    __builtin_amdgcn_s_barrier();                                                \
} while (0)

#define EPI_PROJ() do {                                                          \
    _Pragma("unroll") for (int t_ = 0; t_ < 2; ++t_)                             \
    _Pragma("unroll") for (int r_ = 0; r_ < 4; ++r_) {                           \
        int lr_ = lrow0 + t_ * 16 + quad * 4 + r_;                               \
        _Pragma("unroll") for (int n_ = 0; n_ < 8; ++n_)                         \
            lds_x[lr_ * XSTRIDE + n_ * 16 + l16] = f2b(acc[t_][n_][r_] + pbv[n_]); \
    }                                                                            \
    _Pragma("unroll") for (int t_ = 0; t_ < 2; ++t_)                             \
    _Pragma("unroll") for (int n_ = 0; n_ < 8; ++n_) acc[t_][n_] = (f32x4){0.f, 0.f, 0.f, 0.f}; \
} while (0)

#define EPI_LN(BV, GV, BEV) do {                                                 \
    _Pragma("unroll") for (int t_ = 0; t_ < 2; ++t_)                             \
    _Pragma("unroll") for (int r_ = 0; r_ < 4; ++r_) {                           \
        int lr_ = lrow0 + t_ * 16 + quad * 4 + r_;                               \
        float x_[8];                                                             \
        _Pragma("unroll") for (int n_ = 0; n_ < 8; ++n_) x_[n_] = gelu_tanh(acc[t_][n_][r_] + BV[n_]); \
        ln8(x_, GV, BEV);                                                        \
        _Pragma("unroll") for (int n_ = 0; n_ < 8; ++n_)                         \
            lds_x[lr_ * XSTRIDE + n_ * 16 + l16] = f2b(x_[n_]);                  \
    }                                                                            \
    _Pragma("unroll") for (int t_ = 0; t_ < 2; ++t_)                             \
    _Pragma("unroll") for (int n_ = 0; n_ < 8; ++n_) acc[t_][n_] = (f32x4){0.f, 0.f, 0.f, 0.f}; \
} while (0)

// ---------------- fused edge pipeline: [L0: inline e_init] proj(K=384) -> MLP1 -> MLP2 + residual ----------------
template<int L0>
__global__ __launch_bounds__(256, 2) void k_edge_fused(
    const ushort_t* __restrict__ bf_proj,
    const ushort_t* __restrict__ bf_w0,
    const ushort_t* __restrict__ bf_w1,
    ushort_t* e_glob,
    const ushort_t* __restrict__ h,
    const int* __restrict__ senders, const int* __restrict__ receivers,
    const void* __restrict__ edges_raw,        // raw edge features [E][2] (dual-dtype), L0 only
    const ushort_t* __restrict__ wedge_arena,  // bvec slots 33..35: w0[128] w1[128] be[128] bf16
    const ushort_t* __restrict__ pb,
    const ushort_t* __restrict__ b0, const ushort_t* __restrict__ g0, const ushort_t* __restrict__ be0,
    const ushort_t* __restrict__ b1, const ushort_t* __restrict__ g1, const ushort_t* __restrict__ be1,
    const int* __restrict__ dflag)
{
    __shared__ __align__(16) ushort_t lds_w[2][64 * 128];
    __shared__ __align__(16) ushort_t lds_x[128 * XSTRIDE];
    __shared__ __align__(16) ushort_t wedge[512];   // 1 KB: w0|w1|be (+overread pad)
    const int tid  = threadIdx.x;
    const int wave = tid >> 6, lane = tid & 63;
    const int quad = lane >> 4, l16 = lane & 15;
    const int row0  = blockIdx.x * 128;   // 320000 % 128 == 0: all rows valid
    const int lrow0 = wave * 32;
    const bool f32g = L0 ? (*dflag != 0) : false;

    // hoist all epilogue constants so no stray VMEM perturbs vmcnt counting
    float pbv[8], b0v[8], g0v[8], be0v[8], b1v[8], g1v[8], be1v[8];
#pragma unroll
    for (int n = 0; n < 8; ++n) {
        int col = n * 16 + l16;
        pbv[n]  = b2f(pb[col]);
        b0v[n]  = b2f(b0[col]);  g0v[n] = b2f(g0[col]);  be0v[n] = b2f(be0[col]);
        b1v[n]  = b2f(b1[col]);  g1v[n] = b2f(g1[col]);  be1v[n] = b2f(be1[col]);
    }

    // A-source pointers (E-stage pointers only needed for L1)
    const ushort_t* apE[2]; const ushort_t* apS[2]; const ushort_t* apR[2];
#pragma unroll
    for (int t = 0; t < 2; ++t) {
        int grow = row0 + lrow0 + t * 16 + l16;
        apE[t] = e_glob + (size_t)grow * 128 + quad * 8;
        apS[t] = h + (size_t)clampi(senders[grow],   N_NODES) * 128 + quad * 8;
        apR[t] = h + (size_t)clampi(receivers[grow], N_NODES) * 128 + quad * 8;
    }

    // chunk pointers (16 KB = 8192 ushort each)
    const ushort_t* p0a = bf_proj;             const ushort_t* p0b = bf_proj + 8192;
    const ushort_t* p1a = bf_proj + 16384;     const ushort_t* p1b = bf_proj + 24576;
    const ushort_t* p2a = bf_proj + 32768;     const ushort_t* p2b = bf_proj + 40960;
    const ushort_t* w0a = bf_w0;               const ushort_t* w0b = bf_w0 + 8192;
    const ushort_t* w1a = bf_w1;               const ushort_t* w1b = bf_w1 + 8192;

    f32x4 acc[2][8];
#pragma unroll
    for (int t = 0; t < 2; ++t)
#pragma unroll
        for (int n = 0; n < 8; ++n) acc[t][n] = (f32x4){0.f, 0.f, 0.f, 0.f};

    short8 afA[2][2], afB[2][2];

    if (L0) {
        // stage wedge table (wave 0: 64 lanes x 16B = 1 KB, overreads into spare slot)
        if (wave == 0)
            gload_lds16(wedge_arena + (size_t)lane * 8, wedge + (size_t)lane * 8);
        // per-lane edge feature loads (2 rows)
        float a0f[2], a1f[2];
#pragma unroll
        for (int t = 0; t < 2; ++t) {
            int grow = row0 + lrow0 + t * 16 + l16;
            ldedge(edges_raw, grow, f32g, a0f[t], a1f[t]);
        }
        asm volatile("s_waitcnt vmcnt(0)" ::: "memory");
        __builtin_amdgcn_s_barrier();
        // compute both e-chunk A-fragments in registers (no VMEM)
        short8 afE0[2][2], afE1[2][2];
#pragma unroll
        for (int t = 0; t < 2; ++t)
#pragma unroll
            for (int k = 0; k < 2; ++k) {
                afE0[t][k] = einit8(wedge, (0 * 2 + k) * 32 + quad * 8, a0f[t], a1f[t]);
                afE1[t][k] = einit8(wedge, (1 * 2 + k) * 32 + quad * 8, a0f[t], a1f[t]);
            }
        STAGE(p0a, 0);
        // ledger: E0 [S0,S1]->vmcnt4 | E1 [S1,A0,S2]->vmcnt8 | S0..R0 [A,S,A,S]->vmcnt8 | R1 [A,S5,S6]->vmcnt4
        PCH(afE0, afA, apS, 0, 0, p0b, 1, 4, 0, 1);
        PCH(afE1, afA, apS, 0, 1, p1a, 0, 8, 1, 1);
        PCH(afA,  afB, apS, 1, 0, p1b, 1, 8, 1, 1);
        PCH(afB,  afA, apR, 0, 1, p2a, 0, 8, 1, 1);
        PCH(afA,  afB, apR, 1, 0, p2b, 1, 8, 1, 1);
        PCH(afB,  afA, apR, 1, 1, w0a, 0, 4, 0, 1);
    } else {
        LOADA(afA, apE, 0);
        __builtin_amdgcn_sched_barrier(0);
        STAGE(p0a, 0);
        PCH(afA, afB, apE, 1, 0, p0b, 1, 8, 1, 1);
        PCH(afB, afA, apS, 0, 1, p1a, 0, 8, 1, 1);
        PCH(afA, afB, apS, 1, 0, p1b, 1, 8, 1, 1);
        PCH(afB, afA, apR, 0, 1, p2a, 0, 8, 1, 1);
        PCH(afA, afB, apR, 1, 0, p2b, 1, 8, 1, 1);
        PCH(afB, afA, apR, 1, 1, w0a, 0, 4, 0, 1);
    }
    EPI_PROJ();                          // wave-private lds_x; overlaps w0a flight
    XCHUNK(0, 0, 1, w0b, 1, 4);
    XCHUNK(1, 1, 1, w1a, 0, 4);
    EPI_LN(b0v, g0v, be0v);              // MLP1 epilogue; overlaps w1a flight
    XCHUNK(0, 0, 1, w1b, 1, 4);
    XCHUNK(1, 1, 0, w1b, 0, 0);
    EPI_LN(b1v, g1v, be1v);              // final LN -> lds_x

    __syncthreads();
#pragma unroll
    for (int it = 0; it < 8; ++it) {
        int idx  = it * 256 + tid;          // 0..2047 -> 128 rows x 16 chunks
        int lrow = idx >> 4;
        int c8   = (idx & 15) << 3;
        size_t goff = (size_t)(row0 + lrow) * 128 + c8;
        short8 xv = *(const short8*)(lds_x + lrow * XSTRIDE + c8);
        short8 yv;
        if (L0) {
            // residual base = e_init recomputed in f32 (never materialized)
            float ea0, ea1;
            ldedge(edges_raw, row0 + lrow, f32g, ea0, ea1);
            short8 w0 = *(const short8*)(wedge + c8);
            short8 w1 = *(const short8*)(wedge + 128 + c8);
            short8 bb = *(const short8*)(wedge + 256 + c8);
#pragma unroll
            for (int j = 0; j < 8; ++j) {
                float base = ea0 * b2f((ushort_t)w0[j]) + ea1 * b2f((ushort_t)w1[j]) + b2f((ushort_t)bb[j]);
                yv[j] = (short)f2b(base + b2f((ushort_t)xv[j]));
            }
        } else {
            short8 ev = *(const short8*)(e_glob + goff);
#pragma unroll
            for (int j = 0; j < 8; ++j)
                yv[j] = (short)f2b(b2f((ushort_t)ev[j]) + b2f((ushort_t)xv[j]));
        }
        *(short8*)(e_glob + goff) = yv;
    }
}

// ---------------- fused node pipeline: proj(K=256) -> MLP1 -> MLP2 + residual ----------------
__global__ __launch_bounds__(256, 2) void k_node_fused(
    const ushort_t* __restrict__ bf_proj,
    const ushort_t* __restrict__ bf_w0,
    const ushort_t* __restrict__ bf_w1,
    ushort_t* h,
    const ushort_t* __restrict__ agg,
    const ushort_t* __restrict__ pb,
    const ushort_t* __restrict__ b0, const ushort_t* __restrict__ g0, const ushort_t* __restrict__ be0,
    const ushort_t* __restrict__ b1, const ushort_t* __restrict__ g1, const ushort_t* __restrict__ be1,
    int rows)
{
    __shared__ __align__(16) ushort_t lds_w[2][64 * 128];
    __shared__ __align__(16) ushort_t lds_x[128 * XSTRIDE];
    const int tid  = threadIdx.x;
    const int wave = tid >> 6, lane = tid & 63;
    const int quad = lane >> 4, l16 = lane & 15;
    const int row0  = blockIdx.x * 128;
    const int lrow0 = wave * 32;

    float pbv[8], b0v[8], g0v[8], be0v[8], b1v[8], g1v[8], be1v[8];
#pragma unroll
    for (int n = 0; n < 8; ++n) {
        int col = n * 16 + l16;
        pbv[n]  = b2f(pb[col]);
        b0v[n]  = b2f(b0[col]);  g0v[n] = b2f(g0[col]);  be0v[n] = b2f(be0[col]);
        b1v[n]  = b2f(b1[col]);  g1v[n] = b2f(g1[col]);  be1v[n] = b2f(be1[col]);
    }

    const ushort_t* apH[2]; const ushort_t* apA[2];
#pragma unroll
    for (int t = 0; t < 2; ++t) {
        int grow = row0 + lrow0 + t * 16 + l16;
        int rr = grow < rows ? grow : rows - 1;
        apH[t] = h   + (size_t)rr * 128 + quad * 8;
        apA[t] = agg + (size_t)rr * 128 + quad * 8;
    }

    const ushort_t* n0a = bf_proj;           const ushort_t* n0b = bf_proj + 8192;
    const ushort_t* n1a = bf_proj + 16384;   const ushort_t* n1b = bf_proj + 24576;
    const ushort_t* w0a = bf_w0;             const ushort_t* w0b = bf_w0 + 8192;
    const ushort_t* w1a = bf_w1;             const ushort_t* w1b = bf_w1 + 8192;

    f32x4 acc[2][8];
#pragma unroll
    for (int t = 0; t < 2; ++t)
#pragma unroll
        for (int n = 0; n < 8; ++n) acc[t][n] = (f32x4){0.f, 0.f, 0.f, 0.f};

    short8 afA[2][2], afB[2][2];
    LOADA(afA, apH, 0);
    __builtin_amdgcn_sched_barrier(0);
    STAGE(n0a, 0);
    PCH(afA, afB, apH, 1, 0, n0b, 1, 8, 1, 1);
    PCH(afB, afA, apA, 0, 1, n1a, 0, 8, 1, 1);
    PCH(afA, afB, apA, 1, 0, n1b, 1, 8, 1, 1);
    PCH(afB, afA, apA, 1, 1, w0a, 0, 4, 0, 1);   // last P-chunk: no next-A -> vmcnt(4)
    EPI_PROJ();
    XCHUNK(0, 0, 1, w0b, 1, 4);
    XCHUNK(1, 1, 1, w1a, 0, 4);
    EPI_LN(b0v, g0v, be0v);
    XCHUNK(0, 0, 1, w1b, 1, 4);
    XCHUNK(1, 1, 0, w1b, 0, 0);
    EPI_LN(b1v, g1v, be1v);

    __syncthreads();
#pragma unroll
    for (int it = 0; it < 8; ++it) {
        int idx  = it * 256 + tid;
        int lrow = idx >> 4;
        int c8   = (idx & 15) << 3;
        int grow = row0 + lrow;
        if (grow < rows) {
            size_t goff = (size_t)grow * 128 + c8;
            short8 xv = *(const short8*)(lds_x + lrow * XSTRIDE + c8);
            short8 hv = *(const short8*)(h + goff);
            short8 yv;
#pragma unroll
            for (int j = 0; j < 8; ++j)
                yv[j] = (short)f2b(b2f((ushort_t)hv[j]) + b2f((ushort_t)xv[j]));
            *(short8*)(h + goff) = yv;
        }
    }
}

extern "C" void kernel_launch(void* const* d_in, const int* in_sizes, int n_in,
                              void* d_out, int out_size, void* d_ws, size_t ws_size,
                              hipStream_t stream) {
    const void* nodes        = d_in[0];
    const void* edges        = d_in[1];
    const int*  senders      = (const int*)d_in[2];
    const int*  receivers    = (const int*)d_in[3];
    const void* w_node_emb   = d_in[4];
    const void* b_node_emb   = d_in[5];
    const void* w_edge_emb   = d_in[6];
    const void* b_edge_emb   = d_in[7];
    const void* edge_proj_w  = d_in[8];
    const void* edge_proj_b  = d_in[9];
    const void* node_proj_w  = d_in[10];
    const void* node_proj_b  = d_in[11];
    const void* edge_mlp_w   = d_in[12];
    const void* edge_mlp_b   = d_in[13];
    const void* edge_ln_g    = d_in[14];
    const void* edge_ln_b    = d_in[15];
    const void* node_mlp_w   = d_in[16];
    const void* node_mlp_b   = d_in[17];
    const void* node_ln_g    = d_in[18];
    const void* node_ln_b    = d_in[19];
    const void* mlp_out_w    = d_in[20];
    const void* mlp_out_b    = d_in[21];
    const void* mlp_out_g    = d_in[22];
    const void* mlp_out_beta = d_in[23];
    const void* proj_w       = d_in[24];
    const void* proj_b       = d_in[25];

    char* ws = (char*)d_ws;
    ushort_t* bf_nodeemb  = (ushort_t*)ws;  ws += (size_t)288 * 128 * 2;   // frag arena start
    ushort_t* bf_edgeproj = (ushort_t*)ws;  ws += (size_t)768 * 128 * 2;
    ushort_t* bf_nodeproj = (ushort_t*)ws;  ws += (size_t)512 * 128 * 2;
    ushort_t* bf_edgemlp  = (ushort_t*)ws;  ws += (size_t)512 * 128 * 2;
    ushort_t* bf_nodemlp  = (ushort_t*)ws;  ws += (size_t)512 * 128 * 2;
    ushort_t* bf_mlpout   = (ushort_t*)ws;  ws += (size_t)128 * 128 * 2;
    ushort_t* h    = (ushort_t*)ws;         ws += (size_t)N_NODES * D * 2;
    ushort_t* e    = (ushort_t*)ws;         ws += (size_t)N_EDGES * D * 2;
    ushort_t* agg  = (ushort_t*)ws;         ws += (size_t)N_NODES * D * 2;
    int*      cnti = (int*)ws;              ws += (size_t)N_NODES * 4;
    int*      offs = (int*)ws;              ws += (size_t)N_NODES * 4;
    int*      curs = (int*)ws;              ws += (size_t)N_NODES * 4;
    int*      eid  = (int*)ws;              ws += (size_t)N_EDGES * 4;
    int*      flag = (int*)ws;              ws += 256;
    ushort_t* bvec = (ushort_t*)ws;         ws += (size_t)37 * 128 * 2;   // bf16 bias arena (+DMA overread pad)
    ushort_t* wT   = (ushort_t*)ws;         ws += (size_t)24 * 128 * 2;   // projT bf16

    hipMemsetAsync(flag, 0, 256, stream);
    k_detect<<<256, 256, 0, stream>>>((const uint32_t*)nodes, flag);

    // consolidated setup (bias packs + projT + all 6 B-fragment transforms in one launch)
    // bvec slots: 0 b_node_emb | 1 b_edge_emb | 2,3 edge_proj_b | 4,5 node_proj_b | 6..9 edge_mlp_b
    // 10..13 edge_ln_g | 14..17 edge_ln_b | 18..21 node_mlp_b | 22..25 node_ln_g
    // 26..29 node_ln_b | 30 mlp_out_b | 31 mlp_out_g | 32 mlp_out_beta
    // 33,34 w_edge_emb | 35 b_edge_emb (wedge table, contiguous for LDS-DMA) | 36 pad
    {
        SetupArgs sa;
        const void* ps[15] = { b_node_emb, b_edge_emb, edge_proj_b, node_proj_b,
                               edge_mlp_b, edge_ln_g, edge_ln_b,
                               node_mlp_b, node_ln_g, node_ln_b,
                               mlp_out_b, mlp_out_g, mlp_out_beta,
                               w_edge_emb, b_edge_emb };
        const int   pn[15] = { 128, 128, 256, 256, 512, 512, 512, 512, 512, 512, 128, 128, 128, 256, 128 };
        const int   pd[15] = { 0, 1, 2, 4, 6, 10, 14, 18, 22, 26, 30, 31, 32, 33, 35 };
        const void* fs[6]  = { w_node_emb, edge_proj_w, node_proj_w, edge_mlp_w, node_mlp_w, mlp_out_w };
        const int   fk[6]  = { 9, 24, 16, 16, 16, 4 };
        const int   fd[6]  = { 0, 36864, 135168, 200704, 266240, 331776 };  // ushort offsets, contiguous arena
        for (int i = 0; i < 15; ++i) { sa.psrc[i] = ps[i]; sa.pn[i] = pn[i]; sa.pdst[i] = pd[i]; }
        for (int i = 0; i < 6;  ++i) { sa.fsrc[i] = fs[i]; sa.fkb[i] = fk[i]; sa.fdst[i] = fd[i]; }
        sa.projw = proj_w;
        // total threads: 4608 (packs) + 3072 (projT) + 43520 (bfrag) = 51200 -> 200 blocks
        k_setup<<<200, 256, 0, stream>>>(sa, bvec, bf_nodeemb, wT, flag);
    }

    // CSR build (receivers constant across both layers)
    hipMemsetAsync(cnti, 0, (size_t)N_NODES * 4, stream);
    k_counti<<<(N_EDGES + 255) / 256, 256, 0, stream>>>(receivers, cnti, N_EDGES);
    k_scan<<<1, 1024, 0, stream>>>(cnti, offs, curs);
    k_fill<<<(N_EDGES + 255) / 256, 256, 0, stream>>>(receivers, curs, eid, N_EDGES);

    {
        const int grid = (N_NODES + 127) / 128;
        k_gemm<3, false><<<grid, 256, 0, stream>>>(
            bf_nodeemb,
            nodes, 1, 288, 0,   128,
            nodes, 1, 288, 128, 128,
            nodes, 1, 288, 256, 32,
            N_NODES, bvec + 0 * 128, nullptr, nullptr, h, flag);
    }

    const int gridE = N_EDGES / 128;           // 2500
    const int gridN = (N_NODES + 127) / 128;   // 157

    for (int l = 0; l < 2; ++l) {
        if (l == 0) {
            k_edge_fused<1><<<gridE, 256, 0, stream>>>(
                bf_edgeproj,
                bf_edgemlp + (size_t)0 * 128 * 128,
                bf_edgemlp + (size_t)1 * 128 * 128,
                e, h, senders, receivers,
                edges, bvec + 33 * 128,
                bvec + 2 * 128,
                bvec + 6 * 128,  bvec + 10 * 128, bvec + 14 * 128,
                bvec + 7 * 128,  bvec + 11 * 128, bvec + 15 * 128,
                flag);
        } else {
            k_edge_fused<0><<<gridE, 256, 0, stream>>>(
                bf_edgeproj + (size_t)384 * 128,
                bf_edgemlp + (size_t)2 * 128 * 128,
                bf_edgemlp + (size_t)3 * 128 * 128,
                e, h, senders, receivers,
                edges, bvec + 33 * 128,
                bvec + 3 * 128,
                bvec + 8 * 128,  bvec + 12 * 128, bvec + 16 * 128,
                bvec + 9 * 128,  bvec + 13 * 128, bvec + 17 * 128,
                flag);
        }
        k_agg<<<(N_NODES + 7) / 8, 256, 0, stream>>>(e, offs, cnti, eid, agg);
        k_node_fused<<<gridN, 256, 0, stream>>>(
            bf_nodeproj + (size_t)l * 256 * 128,
            bf_nodemlp + (size_t)(l * 2 + 0) * 128 * 128,
            bf_nodemlp + (size_t)(l * 2 + 1) * 128 * 128,
            h, agg,
            bvec + (size_t)(4 + l) * 128,
            bvec + (size_t)(18 + l * 2) * 128,     bvec + (size_t)(22 + l * 2) * 128,     bvec + (size_t)(26 + l * 2) * 128,
            bvec + (size_t)(18 + l * 2 + 1) * 128, bvec + (size_t)(22 + l * 2 + 1) * 128, bvec + (size_t)(26 + l * 2 + 1) * 128,
            N_NODES);
    }

    // fused: mlp_out GEMM + gelu + LN + projection straight to d_out
    k_out<<<gridN, 256, 0, stream>>>(
        bf_mlpout, h,
        bvec + 30 * 128, bvec + 31 * 128, bvec + 32 * 128,
        wT, proj_b, d_out, N_NODES, flag);
}

// Round 13
// 573.779 us; speedup vs baseline: 1.4257x; 1.0494x over previous
//
#include <hip/hip_runtime.h>
#include <hip/hip_bf16.h>
#include <stdint.h>

typedef unsigned short ushort_t;
typedef __attribute__((ext_vector_type(8))) short short8;
typedef __attribute__((ext_vector_type(4))) short short4v;
typedef __attribute__((ext_vector_type(4))) float f32x4;
typedef __attribute__((ext_vector_type(4))) int int4v;

#define N_NODES 20000
#define N_EDGES 320000
#define D 128
#define XSTRIDE 136   // padded LDS row stride (ushorts)

#define GAS __attribute__((address_space(1)))
#define LAS __attribute__((address_space(3)))

__device__ __forceinline__ float b2f(ushort_t u) {
    union { float f; uint32_t i; } v; v.i = ((uint32_t)u) << 16; return v.f;
}
// native RNE f32->bf16 (bit-identical to integer-trick RNE); compiler pairs adjacent
// casts into v_cvt_pk_bf16_f32
__device__ __forceinline__ ushort_t f2b(float f) {
    __bf16 h = (__bf16)f;
    return __builtin_bit_cast(ushort_t, h);
}
// dtype-flexible scalar load: raw input arrays may be f32 or bf16 (runtime-detected)
__device__ __forceinline__ float ldf(const void* p, size_t i, bool f32) {
    return f32 ? ((const float*)p)[i] : b2f(((const ushort_t*)p)[i]);
}
// dtype-flexible 8-element A-fragment load (8 consecutive elements, 8-aligned index)
__device__ __forceinline__ short8 lda8(const void* p, size_t i, bool f32) {
    if (f32) {
        const float* fp = (const float*)p + i;
        f32x4 v0 = *(const f32x4*)fp;
        f32x4 v1 = *(const f32x4*)(fp + 4);
        short8 a;
#pragma unroll
        for (int j = 0; j < 4; ++j) {
            a[j]     = (short)f2b(v0[j]);
            a[j + 4] = (short)f2b(v1[j]);
        }
        return a;
    }
    return *(const short8*)((const ushort_t*)p + i);
}
// tanh-gelu with fast reciprocal (v_rcp_f32, ~1ulp) instead of full-precision division
__device__ __forceinline__ float gelu_tanh(float x) {
    float u = 0.7978845608028654f * (x + 0.044715f * x * x * x);
    u = fminf(fmaxf(u, -15.f), 15.f);
    float e = __expf(2.f * u);
    float t = (e - 1.f) * __builtin_amdgcn_rcpf(e + 1.f);
    return 0.5f * x * (1.f + t);
}
__device__ __forceinline__ int clampi(int v, int hi) {  // [0, hi)
    return v < 0 ? 0 : (v >= hi ? hi - 1 : v);
}
// async 16B global->LDS (linear dest, lane-ordered — matches wave-uniform-base+lane*16)
__device__ __forceinline__ void gload_lds16(const void* g, void* l) {
    __builtin_amdgcn_global_load_lds((const GAS uint32_t*)g, (LAS uint32_t*)l, 16, 0, 0);
}
// dual-dtype edge row load (2 scalars)
__device__ __forceinline__ void ldedge(const void* edges, int row, bool f32, float& a0, float& a1) {
    if (f32) {
        const float* p = (const float*)edges + (size_t)row * 2;
        a0 = p[0]; a1 = p[1];
    } else {
        const ushort_t* p = (const ushort_t*)edges + (size_t)row * 2;
        a0 = b2f(p[0]); a1 = b2f(p[1]);
    }
}
// e_init fragment: 8 consecutive cols of a0*w0 + a1*w1 + b from the wedge LDS table
__device__ __forceinline__ short8 einit8(const ushort_t* wedge, int colbase, float a0, float a1) {
    short8 w0 = *(const short8*)(wedge + colbase);
    short8 w1 = *(const short8*)(wedge + 128 + colbase);
    short8 bb = *(const short8*)(wedge + 256 + colbase);
    short8 r;
#pragma unroll
    for (int j = 0; j < 8; ++j)
        r[j] = (short)f2b(a0 * b2f((ushort_t)w0[j]) + a1 * b2f((ushort_t)w1[j]) + b2f((ushort_t)bb[j]));
    return r;
}

// row-wise LN over 128 cols spread as x[n] on 16 lanes (same quad group)
__device__ __forceinline__ void ln8(float x[8], const float gv[8], const float bv[8]) {
    float s1 = 0.f, s2 = 0.f;
#pragma unroll
    for (int n = 0; n < 8; ++n) { s1 += x[n]; s2 += x[n] * x[n]; }
#pragma unroll
    for (int m = 1; m < 16; m <<= 1) {
        s1 += __shfl_xor(s1, m, 64);
        s2 += __shfl_xor(s2, m, 64);
    }
    float mean = s1 * (1.f / 128.f);
    float var  = fmaxf(s2 * (1.f / 128.f) - mean * mean, 0.f);
    float rs   = __builtin_amdgcn_rsqf(var + 1e-5f);
#pragma unroll
    for (int n = 0; n < 8; ++n) x[n] = (x[n] - mean) * rs * gv[n] + bv[n];
}

// Detect whether float inputs are f32 (flag=1) or bf16 (flag=0).
__global__ void k_detect(const uint32_t* __restrict__ raw, int* __restrict__ flag) {
    int t = blockIdx.x * blockDim.x + threadIdx.x;   // 65536 threads
    uint32_t u = raw[t];
    int e_lo = (u >> 7)  & 0xFF;
    int e_hi = (u >> 23) & 0xFF;
    if (e_lo == 0xFF || e_hi == 0xFF) atomicOr(flag, 1);
}

// ---------------- consolidated setup: bias packs + projT + all B-fragment transforms ----------------
struct SetupArgs {
    const void* psrc[15];
    int         pn[15];
    int         pdst[15];
    const void* fsrc[6];
    int         fkb[6];
    int         fdst[6];     // dst offset into frag arena (ushort units)
    const void* projw;
};

__global__ void k_setup(SetupArgs a, ushort_t* __restrict__ bvec, ushort_t* __restrict__ frag,
                        ushort_t* __restrict__ wT, const int* __restrict__ dflag) {
    const bool f32 = *dflag != 0;
    int t = blockIdx.x * blockDim.x + threadIdx.x;
    if (t < 4608) {                      // bias packs
        int i = t, d = 0;
        while (i >= a.pn[d]) { i -= a.pn[d]; ++d; }
        bvec[(size_t)a.pdst[d] * 128 + i] = f2b(ldf(a.psrc[d], i, f32));
        return;
    }
    t -= 4608;
    if (t < 3072) {                      // projT
        int p = t >> 7, k = t & 127;
        wT[p * 128 + k] = f2b(ldf(a.projw, (size_t)k * 24 + p, f32));
        return;
    }
    t -= 3072;
    if (t >= 43520) return;              // bfrag region: sum(fkb)=85 -> 85*512 groups
    int g = t, d = 0;
    while (g >= a.fkb[d] * 512) { g -= a.fkb[d] * 512; ++d; }
    const void* src = a.fsrc[d];
    int kblk = g >> 9;
    int rem  = g & 511;
    int nt   = rem >> 6;
    int lane = rem & 63;
    int krow = kblk * 32 + ((lane >> 4) << 3);
    int col  = nt * 16 + (lane & 15);
    short8 v;
#pragma unroll
    for (int j = 0; j < 8; ++j) v[j] = (short)f2b(ldf(src, (size_t)(krow + j) * 128 + col, f32));
    *(short8*)(frag + (size_t)a.fdst[d] + (size_t)g * 8) = v;
}

// ---------------- CSR build for receiver-side aggregation ----------------
__global__ void k_counti(const int* __restrict__ recv, int* __restrict__ cnti, int E) {
    int i = blockIdx.x * blockDim.x + threadIdx.x;
    if (i < E) atomicAdd(&cnti[clampi(recv[i], N_NODES)], 1);
}

// single-block exclusive scan of cnti -> offs (and cursor copy)
__global__ void k_scan(const int* __restrict__ cnti, int* __restrict__ offs,
                       int* __restrict__ cursor) {
    __shared__ int part[1024];
    const int t = threadIdx.x;           // blockDim = 1024
    const int base = t * 20;             // 1024*20 = 20480 >= N_NODES
    int s = 0;
#pragma unroll 4
    for (int j = 0; j < 20; ++j) {
        int idx = base + j;
        if (idx < N_NODES) s += cnti[idx];
    }
    part[t] = s;
    __syncthreads();
    for (int off = 1; off < 1024; off <<= 1) {
        int v = (t >= off) ? part[t - off] : 0;
        __syncthreads();
        part[t] += v;
        __syncthreads();
    }
    int run = (t == 0) ? 0 : part[t - 1];   // exclusive prefix
    for (int j = 0; j < 20; ++j) {
        int idx = base + j;
        if (idx < N_NODES) {
            offs[idx]   = run;
            cursor[idx] = run;
            run += cnti[idx];
        }
    }
}

__global__ void k_fill(const int* __restrict__ recv, int* __restrict__ cursor,
                       int* __restrict__ eid, int E) {
    int i = blockIdx.x * blockDim.x + threadIdx.x;
    if (i < E) {
        int r = clampi(recv[i], N_NODES);
        int pos = atomicAdd(&cursor[r], 1);
        eid[pos] = i;
    }
}

// gather-mean aggregation: agg[n] = mean over incident edges of e[eid] (bf16 out)
__global__ void k_agg(const ushort_t* __restrict__ e, const int* __restrict__ offs,
                      const int* __restrict__ cnti, const int* __restrict__ eid,
                      ushort_t* __restrict__ agg) {
    const int tid = threadIdx.x;
    const int n = blockIdx.x * 8 + (tid >> 5);   // 8 nodes / 256-thread block
    const int l = tid & 31;                      // 32 lanes x 4 cols = 128 cols
    if (n >= N_NODES) return;
    const int start = offs[n], deg = cnti[n];
    float s0 = 0.f, s1 = 0.f, s2 = 0.f, s3 = 0.f;
    for (int j = 0; j < deg; ++j) {
        const ushort_t* row = e + (size_t)eid[start + j] * 128 + l * 4;
        short4v v = *(const short4v*)row;
        s0 += b2f((ushort_t)v[0]);
        s1 += b2f((ushort_t)v[1]);
        s2 += b2f((ushort_t)v[2]);
        s3 += b2f((ushort_t)v[3]);
    }
    const float inv = 1.f / (float)(deg < 1 ? 1 : deg);
    short4v o;
    o[0] = (short)f2b(s0 * inv);
    o[1] = (short)f2b(s1 * inv);
    o[2] = (short)f2b(s2 * inv);
    o[3] = (short)f2b(s3 * inv);
    *(short4v*)(agg + (size_t)n * 128 + l * 4) = o;
}

// ---------------- generic GEMM (node embedding) ----------------
template<int NC, bool LN>
__global__ __launch_bounds__(256, 2) void k_gemm(
    const ushort_t* __restrict__ bfrag,
    const void* s0, int isf0, int st0, int ko0, int kl0,
    const void* s1, int isf1, int st1, int ko1, int kl1,
    const void* s2, int isf2, int st2, int ko2, int kl2,
    int rows,
    const ushort_t* __restrict__ bias,
    const ushort_t* __restrict__ gamma,
    const ushort_t* __restrict__ betap,
    ushort_t* out,
    const int* __restrict__ dflag)
{
    __shared__ __align__(16) ushort_t lds_b[128 * 128];
    const bool f32g = *dflag != 0;
    const int tid  = threadIdx.x;
    const int wave = tid >> 6, lane = tid & 63;
    const int quad = lane >> 4, l16 = lane & 15;
    const int row0 = blockIdx.x * 128 + wave * 32;

    f32x4 acc[2][8];
#pragma unroll
    for (int t = 0; t < 2; ++t)
#pragma unroll
        for (int n = 0; n < 8; ++n) acc[t][n] = (f32x4){0.f, 0.f, 0.f, 0.f};

    const ushort_t* bptr = bfrag;
#pragma unroll
    for (int c = 0; c < NC; ++c) {
        const void* src  = (c == 0) ? s0 : ((c == 1) ? s1 : s2);
        const bool  eff  = (((c == 0) ? isf0 : ((c == 1) ? isf1 : isf2)) != 0) && f32g;
        const int stride = (c == 0) ? st0 : ((c == 1) ? st1 : st2);
        const int koff   = (c == 0) ? ko0 : ((c == 1) ? ko1 : ko2);
        const int klen   = (c == 0) ? kl0 : ((c == 1) ? kl1 : kl2);

        if (c) __syncthreads();
        {
            const int ngrp = klen * 16;
            for (int g = tid; g < ngrp; g += 256)
                gload_lds16(bptr + (size_t)g * 8, lds_b + (size_t)g * 8);
        }
        __syncthreads();   // full drain: staging resident

        size_t aoff[2];
#pragma unroll
        for (int t = 0; t < 2; ++t) {
            int r  = row0 + t * 16 + l16;
            int rr = r < rows ? r : rows - 1;
            aoff[t] = (size_t)rr * stride + koff + quad * 8;
        }
        const int ksteps = klen >> 5;
        for (int ks = 0; ks < ksteps; ++ks) {
            short8 af[2];
#pragma unroll
            for (int t = 0; t < 2; ++t)
                af[t] = lda8(src, aoff[t] + ks * 32, eff);
#pragma unroll
            for (int n = 0; n < 8; ++n) {
                short8 bf = *(const short8*)(lds_b + (size_t)((ks * 8 + n) * 64 + lane) * 8);
                acc[0][n] = __builtin_amdgcn_mfma_f32_16x16x32_bf16(af[0], bf, acc[0][n], 0, 0, 0);
                acc[1][n] = __builtin_amdgcn_mfma_f32_16x16x32_bf16(af[1], bf, acc[1][n], 0, 0, 0);
            }
        }
        bptr += (size_t)klen * 128;
    }

    float bv[8], gv[8], btv[8];
#pragma unroll
    for (int n = 0; n < 8; ++n) {
        int col = n * 16 + l16;
        bv[n] = b2f(bias[col]);
        if (LN) { gv[n] = b2f(gamma[col]); btv[n] = b2f(betap[col]); }
    }
#pragma unroll
    for (int t = 0; t < 2; ++t) {
#pragma unroll
        for (int r = 0; r < 4; ++r) {
            int row = row0 + t * 16 + quad * 4 + r;
            float x[8];
#pragma unroll
            for (int n = 0; n < 8; ++n) x[n] = acc[t][n][r] + bv[n];
            if (LN) {
#pragma unroll
                for (int n = 0; n < 8; ++n) x[n] = gelu_tanh(x[n]);
                ln8(x, gv, btv);
            }
            if (row < rows) {
#pragma unroll
                for (int n = 0; n < 8; ++n)
                    out[(size_t)row * 128 + n * 16 + l16] = f2b(x[n]);
            }
        }
    }
}

// ---------------- fused output: mlp_out GEMM + gelu + LN + projection to d_out ----------------
__global__ __launch_bounds__(256, 2) void k_out(
    const ushort_t* __restrict__ bfrag,     // bf_mlpout
    const ushort_t* __restrict__ h,
    const ushort_t* __restrict__ bias,
    const ushort_t* __restrict__ gamma,
    const ushort_t* __restrict__ betap,
    const ushort_t* __restrict__ wT,        // [24][128] bf16
    const void* __restrict__ pb,            // proj_b raw
    void* __restrict__ out, int rows,
    const int* __restrict__ dflag)
{
    __shared__ __align__(16) ushort_t lds_b[128 * 128];
    __shared__ __align__(16) ushort_t lds_x[128 * XSTRIDE];
    const bool f32g = *dflag != 0;
    const int tid  = threadIdx.x;
    const int wave = tid >> 6, lane = tid & 63;
    const int quad = lane >> 4, l16 = lane & 15;
    const int row0  = blockIdx.x * 128;
    const int lrow0 = wave * 32;

    for (int g = tid; g < 2048; g += 256)
        gload_lds16(bfrag + (size_t)g * 8, lds_b + (size_t)g * 8);
    __syncthreads();

    f32x4 acc[2][8];
#pragma unroll
    for (int t = 0; t < 2; ++t)
#pragma unroll
        for (int n = 0; n < 8; ++n) acc[t][n] = (f32x4){0.f, 0.f, 0.f, 0.f};

    const ushort_t* ap[2];
#pragma unroll
    for (int t = 0; t < 2; ++t) {
        int grow = row0 + lrow0 + t * 16 + l16;
        int rr = grow < rows ? grow : rows - 1;
        ap[t] = h + (size_t)rr * 128 + quad * 8;
    }
    for (int ks = 0; ks < 4; ++ks) {
        short8 af[2];
#pragma unroll
        for (int t = 0; t < 2; ++t) af[t] = *(const short8*)(ap[t] + ks * 32);
#pragma unroll
        for (int n = 0; n < 8; ++n) {
            short8 bf = *(const short8*)(lds_b + (size_t)((ks * 8 + n) * 64 + lane) * 8);
            acc[0][n] = __builtin_amdgcn_mfma_f32_16x16x32_bf16(af[0], bf, acc[0][n], 0, 0, 0);
            acc[1][n] = __builtin_amdgcn_mfma_f32_16x16x32_bf16(af[1], bf, acc[1][n], 0, 0, 0);
        }
    }

    {
        float bv[8], gv[8], btv[8];
#pragma unroll
        for (int n = 0; n < 8; ++n) {
            int col = n * 16 + l16;
            bv[n] = b2f(bias[col]); gv[n] = b2f(gamma[col]); btv[n] = b2f(betap[col]);
        }
#pragma unroll
        for (int t = 0; t < 2; ++t)
#pragma unroll
            for (int r = 0; r < 4; ++r) {
                int lrow = lrow0 + t * 16 + quad * 4 + r;
                float x[8];
#pragma unroll
                for (int n = 0; n < 8; ++n) x[n] = gelu_tanh(acc[t][n][r] + bv[n]);
                ln8(x, gv, btv);
#pragma unroll
                for (int n = 0; n < 8; ++n)
                    lds_x[lrow * XSTRIDE + n * 16 + l16] = f2b(x[n]);
            }
    }
    __syncthreads();

    // projection: 128 rows x 24 outputs = 3072 -> 12 per thread
#pragma unroll
    for (int it = 0; it < 12; ++it) {
        int idx  = it * 256 + tid;
        int lrow = idx / 24;
        int p    = idx - lrow * 24;
        int grow = row0 + lrow;
        if (grow < rows) {
            float a2 = ldf(pb, p, f32g);
            const ushort_t* xp = lds_x + lrow * XSTRIDE;
            const ushort_t* wp = wT + (size_t)p * 128;
#pragma unroll
            for (int k8 = 0; k8 < 16; ++k8) {
                short8 hv = *(const short8*)(xp + k8 * 8);
                short8 wv = *(const short8*)(wp + k8 * 8);
#pragma unroll
                for (int j = 0; j < 8; ++j)
                    a2 += b2f((ushort_t)hv[j]) * b2f((ushort_t)wv[j]);
            }
            if (f32g) ((float*)out)[(size_t)grow * 24 + p] = a2;
            else      ((ushort_t*)out)[(size_t)grow * 24 + p] = f2b(a2);
        }
    }
}

// ======== BK=32 chunked double-buffered pipeline (3 blocks/CU) ========
// Chunk = 32-K slice = 8 KB of B-fragments in lds_w[buf] (2 buffers = 16 KB total ->
// LDS 51 KB -> 3 blocks/CU vs 2 at BK=64). A-fragments prefetched one chunk ahead.
// STAGE = 2 loads/thread, LOADA = 2 loads. Steady-state per-wave vmcnt ledger:
//   [af_cur(2), stage_cur(2), af_next(2), stage_next(2)] -> vmcnt(4)
// boundary chunks (no next-A): vmcnt(2); last X chunk: vmcnt(0). Buffer parity
// alternates per chunk. lds_x is wave-private (32-row slab per wave).

#define STAGE(srcp, bufi) do {                                                   \
    const ushort_t* s__ = (srcp);                                                \
    _Pragma("unroll")                                                            \
    for (int it__ = 0; it__ < 2; ++it__) {                                       \
        int g__ = it__ * 256 + tid;                                              \
        gload_lds16(s__ + (size_t)g__ * 8, &lds_w[bufi][(size_t)g__ * 8]);       \
    } } while (0)

#define LOADA(dst, apv, kn) do {                                                 \
    _Pragma("unroll") for (int t_ = 0; t_ < 2; ++t_)                             \
        dst[t_] = *(const short8*)(apv[t_] + (kn) * 32);                         \
    } while (0)

#define PCH(AFU, AFN, apv, kn, bufi, nsrc, nbuf, VM, DO_A, DO_STAGE) do {        \
    if (DO_A) LOADA(AFN, apv, kn);                                               \
    __builtin_amdgcn_sched_barrier(0);                                           \
    if (DO_STAGE) STAGE(nsrc, nbuf);                                             \
    asm volatile("s_waitcnt vmcnt(" #VM ")" ::: "memory");                       \
    __builtin_amdgcn_s_barrier();                                                \
    __builtin_amdgcn_sched_barrier(0);                                           \
    _Pragma("unroll") for (int n_ = 0; n_ < 8; ++n_) {                           \
        short8 bf_ = *(const short8*)(&lds_w[bufi][(size_t)(n_ * 64 + lane) * 8]); \
        acc[0][n_] = __builtin_amdgcn_mfma_f32_16x16x32_bf16(AFU[0], bf_, acc[0][n_], 0, 0, 0); \
        acc[1][n_] = __builtin_amdgcn_mfma_f32_16x16x32_bf16(AFU[1], bf_, acc[1][n_], 0, 0, 0); \
    }                                                                            \
    __builtin_amdgcn_sched_barrier(0);                                           \
    __builtin_amdgcn_s_barrier();                                                \
} while (0)

#define XCHUNK(kx, bufi, DO_STAGE, nsrc, nbuf, VM) do {                          \
    if (DO_STAGE) STAGE(nsrc, nbuf);                                             \
    asm volatile("s_waitcnt vmcnt(" #VM ")" ::: "memory");                       \
    __builtin_amdgcn_s_barrier();                                                \
    __builtin_amdgcn_sched_barrier(0);                                           \
    {                                                                            \
        short8 af_[2];                                                           \
        _Pragma("unroll") for (int t_ = 0; t_ < 2; ++t_)                         \
            af_[t_] = *(const short8*)(lds_x + (size_t)(lrow0 + t_ * 16 + l16) * XSTRIDE \
                                       + (kx) * 32 + quad * 8);                  \
        _Pragma("unroll") for (int n_ = 0; n_ < 8; ++n_) {                       \
            short8 bf_ = *(const short8*)(&lds_w[bufi][(size_t)(n_ * 64 + lane) * 8]); \
            acc[0][n_] = __builtin_amdgcn_mfma_f32_16x16x32_bf16(af_[0], bf_, acc[0][n_], 0, 0, 0); \
            acc[1][n_] = __builtin_amdgcn_mfma_f32_16x16x32_bf16(af_[1], bf_, acc[1][n_], 0, 0, 0); \
        }                                                                        \
    }                                                                            \
    __builtin_amdgcn_sched_barrier(0);                                           \
    __builtin_amdgcn_s_barrier();                                                \
} while (0)

#define EPI_PROJ() do {                                                          \
    _Pragma("unroll") for (int t_ = 0; t_ < 2; ++t_)                             \
    _Pragma("unroll") for (int r_ = 0; r_ < 4; ++r_) {                           \
        int lr_ = lrow0 + t_ * 16 + quad * 4 + r_;                               \
        _Pragma("unroll") for (int n_ = 0; n_ < 8; ++n_)                         \
            lds_x[lr_ * XSTRIDE + n_ * 16 + l16] = f2b(acc[t_][n_][r_] + pbv[n_]); \
    }                                                                            \
    _Pragma("unroll") for (int t_ = 0; t_ < 2; ++t_)                             \
    _Pragma("unroll") for (int n_ = 0; n_ < 8; ++n_) acc[t_][n_] = (f32x4){0.f, 0.f, 0.f, 0.f}; \
} while (0)

#define EPI_LN(BV, GV, BEV) do {                                                 \
    _Pragma("unroll") for (int t_ = 0; t_ < 2; ++t_)                             \
    _Pragma("unroll") for (int r_ = 0; r_ < 4; ++r_) {                           \
        int lr_ = lrow0 + t_ * 16 + quad * 4 + r_;                               \
        float x_[8];                                                             \
        _Pragma("unroll") for (int n_ = 0; n_ < 8; ++n_) x_[n_] = gelu_tanh(acc[t_][n_][r_] + BV[n_]); \
        ln8(x_, GV, BEV);                                                        \
        _Pragma("unroll") for (int n_ = 0; n_ < 8; ++n_)                         \
            lds_x[lr_ * XSTRIDE + n_ * 16 + l16] = f2b(x_[n_]);                  \
    }                                                                            \
    _Pragma("unroll") for (int t_ = 0; t_ < 2; ++t_)                             \
    _Pragma("unroll") for (int n_ = 0; n_ < 8; ++n_) acc[t_][n_] = (f32x4){0.f, 0.f, 0.f, 0.f}; \
} while (0)

// ---------------- fused edge pipeline: [L0: inline e_init] proj(K=384) -> MLP1 -> MLP2 + residual ----------------
template<int L0>
__global__ __launch_bounds__(256, 3) void k_edge_fused(
    const ushort_t* __restrict__ bf_proj,
    const ushort_t* __restrict__ bf_w0,
    const ushort_t* __restrict__ bf_w1,
    ushort_t* e_glob,
    const ushort_t* __restrict__ h,
    const int* __restrict__ senders, const int* __restrict__ receivers,
    const void* __restrict__ edges_raw,        // raw edge features [E][2] (dual-dtype), L0 only
    const ushort_t* __restrict__ wedge_arena,  // bvec slots 33..35: w0[128] w1[128] be[128] bf16
    const ushort_t* __restrict__ pb,
    const ushort_t* __restrict__ b0, const ushort_t* __restrict__ g0, const ushort_t* __restrict__ be0,
    const ushort_t* __restrict__ b1, const ushort_t* __restrict__ g1, const ushort_t* __restrict__ be1,
    const int* __restrict__ dflag)
{
    __shared__ __align__(16) ushort_t lds_w[2][32 * 128];   // 2 x 8 KB
    __shared__ __align__(16) ushort_t lds_x[128 * XSTRIDE];
    __shared__ __align__(16) ushort_t wedge[512];   // 1 KB: w0|w1|be (+overread pad)
    const int tid  = threadIdx.x;
    const int wave = tid >> 6, lane = tid & 63;
    const int quad = lane >> 4, l16 = lane & 15;
    const int row0  = blockIdx.x * 128;   // 320000 % 128 == 0: all rows valid
    const int lrow0 = wave * 32;
    const bool f32g = L0 ? (*dflag != 0) : false;

    // hoist all epilogue constants so no stray VMEM perturbs vmcnt counting
    float pbv[8], b0v[8], g0v[8], be0v[8], b1v[8], g1v[8], be1v[8];
#pragma unroll
    for (int n = 0; n < 8; ++n) {
        int col = n * 16 + l16;
        pbv[n]  = b2f(pb[col]);
        b0v[n]  = b2f(b0[col]);  g0v[n] = b2f(g0[col]);  be0v[n] = b2f(be0[col]);
        b1v[n]  = b2f(b1[col]);  g1v[n] = b2f(g1[col]);  be1v[n] = b2f(be1[col]);
    }

    // A-source pointers (E-stage pointers only needed for L1)
    const ushort_t* apE[2]; const ushort_t* apS[2]; const ushort_t* apR[2];
#pragma unroll
    for (int t = 0; t < 2; ++t) {
        int grow = row0 + lrow0 + t * 16 + l16;
        apE[t] = e_glob + (size_t)grow * 128 + quad * 8;
        apS[t] = h + (size_t)clampi(senders[grow],   N_NODES) * 128 + quad * 8;
        apR[t] = h + (size_t)clampi(receivers[grow], N_NODES) * 128 + quad * 8;
    }

    // 32-K chunk pointers (8 KB = 4096 ushorts each)
    const ushort_t* pe0 = bf_proj;                const ushort_t* pe1 = bf_proj + 4096;
    const ushort_t* pe2 = bf_proj + 8192;         const ushort_t* pe3 = bf_proj + 12288;
    const ushort_t* ps0 = bf_proj + 16384;        const ushort_t* ps1 = bf_proj + 20480;
    const ushort_t* ps2 = bf_proj + 24576;        const ushort_t* ps3 = bf_proj + 28672;
    const ushort_t* pr0 = bf_proj + 32768;        const ushort_t* pr1 = bf_proj + 36864;
    const ushort_t* pr2 = bf_proj + 40960;        const ushort_t* pr3 = bf_proj + 45056;
    const ushort_t* w0c0 = bf_w0;                 const ushort_t* w0c1 = bf_w0 + 4096;
    const ushort_t* w0c2 = bf_w0 + 8192;          const ushort_t* w0c3 = bf_w0 + 12288;
    const ushort_t* w1c0 = bf_w1;                 const ushort_t* w1c1 = bf_w1 + 4096;
    const ushort_t* w1c2 = bf_w1 + 8192;          const ushort_t* w1c3 = bf_w1 + 12288;

    f32x4 acc[2][8];
#pragma unroll
    for (int t = 0; t < 2; ++t)
#pragma unroll
        for (int n = 0; n < 8; ++n) acc[t][n] = (f32x4){0.f, 0.f, 0.f, 0.f};

    short8 afA[2], afB[2];

    if (L0) {
        // stage wedge table (wave 0: 64 lanes x 16B = 1 KB, overreads into spare slot)
        if (wave == 0)
            gload_lds16(wedge_arena + (size_t)lane * 8, wedge + (size_t)lane * 8);
        // per-lane edge feature loads (2 rows)
        float a0f[2], a1f[2];
#pragma unroll
        for (int t = 0; t < 2; ++t) {
            int grow = row0 + lrow0 + t * 16 + l16;
            ldedge(edges_raw, grow, f32g, a0f[t], a1f[t]);
        }
        asm volatile("s_waitcnt vmcnt(0)" ::: "memory");
        __builtin_amdgcn_s_barrier();
        // compute all four e-chunk A-fragments in registers (no VMEM)
        short8 afE0[2], afE1[2], afE2[2], afE3[2];
#pragma unroll
        for (int t = 0; t < 2; ++t) {
            afE0[t] = einit8(wedge, 0 * 32 + quad * 8, a0f[t], a1f[t]);
            afE1[t] = einit8(wedge, 1 * 32 + quad * 8, a0f[t], a1f[t]);
            afE2[t] = einit8(wedge, 2 * 32 + quad * 8, a0f[t], a1f[t]);
            afE3[t] = einit8(wedge, 3 * 32 + quad * 8, a0f[t], a1f[t]);
        }
        STAGE(pe0, 0);
        // ledger: E0..E2 [S,S]->vmcnt2 | E3 [S,A,S]->vmcnt4 | S0..R2 steady->vmcnt4 | R3 ->vmcnt2
        PCH(afE0, afA, apS, 0, 0, pe1, 1, 2, 0, 1);
        PCH(afE1, afA, apS, 0, 1, pe2, 0, 2, 0, 1);
        PCH(afE2, afA, apS, 0, 0, pe3, 1, 2, 0, 1);
        PCH(afE3, afA, apS, 0, 1, ps0, 0, 4, 1, 1);
        PCH(afA,  afB, apS, 1, 0, ps1, 1, 4, 1, 1);
        PCH(afB,  afA, apS, 2, 1, ps2, 0, 4, 1, 1);
        PCH(afA,  afB, apS, 3, 0, ps3, 1, 4, 1, 1);
        PCH(afB,  afA, apR, 0, 1, pr0, 0, 4, 1, 1);
        PCH(afA,  afB, apR, 1, 0, pr1, 1, 4, 1, 1);
        PCH(afB,  afA, apR, 2, 1, pr2, 0, 4, 1, 1);
        PCH(afA,  afB, apR, 3, 0, pr3, 1, 4, 1, 1);
        PCH(afB,  afA, apR, 3, 1, w0c0, 0, 2, 0, 1);
    } else {
        LOADA(afA, apE, 0);
        __builtin_amdgcn_sched_barrier(0);
        STAGE(pe0, 0);
        PCH(afA, afB, apE, 1, 0, pe1, 1, 4, 1, 1);
        PCH(afB, afA, apE, 2, 1, pe2, 0, 4, 1, 1);
        PCH(afA, afB, apE, 3, 0, pe3, 1, 4, 1, 1);
        PCH(afB, afA, apS, 0, 1, ps0, 0, 4, 1, 1);
        PCH(afA, afB, apS, 1, 0, ps1, 1, 4, 1, 1);
        PCH(afB, afA, apS, 2, 1, ps2, 0, 4, 1, 1);
        PCH(afA, afB, apS, 3, 0, ps3, 1, 4, 1, 1);
        PCH(afB, afA, apR, 0, 1, pr0, 0, 4, 1, 1);
        PCH(afA, afB, apR, 1, 0, pr1, 1, 4, 1, 1);
        PCH(afB, afA, apR, 2, 1, pr2, 0, 4, 1, 1);
        PCH(afA, afB, apR, 3, 0, pr3, 1, 4, 1, 1);
        PCH(afB, afA, apR, 3, 1, w0c0, 0, 2, 0, 1);
    }
    EPI_PROJ();                          // wave-private lds_x; overlaps w0c0 flight
    XCHUNK(0, 0, 1, w0c1, 1, 2);
    XCHUNK(1, 1, 1, w0c2, 0, 2);
    XCHUNK(2, 0, 1, w0c3, 1, 2);
    XCHUNK(3, 1, 1, w1c0, 0, 2);
    EPI_LN(b0v, g0v, be0v);              // MLP1 epilogue; overlaps w1c0 flight
    XCHUNK(0, 0, 1, w1c1, 1, 2);
    XCHUNK(1, 1, 1, w1c2, 0, 2);
    XCHUNK(2, 0, 1, w1c3, 1, 2);
    XCHUNK(3, 1, 0, w1c3, 0, 0);
    EPI_LN(b1v, g1v, be1v);              // final LN -> lds_x

    __syncthreads();
#pragma unroll
    for (int it = 0; it < 8; ++it) {
        int idx  = it * 256 + tid;          // 0..2047 -> 128 rows x 16 chunks
        int lrow = idx >> 4;
        int c8   = (idx & 15) << 3;
        size_t goff = (size_t)(row0 + lrow) * 128 + c8;
        short8 xv = *(const short8*)(lds_x + lrow * XSTRIDE + c8);
        short8 yv;
        if (L0) {
            // residual base = e_init recomputed in f32 (never materialized)
            float ea0, ea1;
            ldedge(edges_raw, row0 + lrow, f32g, ea0, ea1);
            short8 w0 = *(const short8*)(wedge + c8);
            short8 w1 = *(const short8*)(wedge + 128 + c8);
            short8 bb = *(const short8*)(wedge + 256 + c8);
#pragma unroll
            for (int j = 0; j < 8; ++j) {
                float base = ea0 * b2f((ushort_t)w0[j]) + ea1 * b2f((ushort_t)w1[j]) + b2f((ushort_t)bb[j]);
                yv[j] = (short)f2b(base + b2f((ushort_t)xv[j]));
            }
        } else {
            short8 ev = *(const short8*)(e_glob + goff);
#pragma unroll
            for (int j = 0; j < 8; ++j)
                yv[j] = (short)f2b(b2f((ushort_t)ev[j]) + b2f((ushort_t)xv[j]));
        }
        *(short8*)(e_glob + goff) = yv;
    }
}

// ---------------- fused node pipeline: proj(K=256) -> MLP1 -> MLP2 + residual ----------------
__global__ __launch_bounds__(256, 3) void k_node_fused(
    const ushort_t* __restrict__ bf_proj,
    const ushort_t* __restrict__ bf_w0,
    const ushort_t* __restrict__ bf_w1,
    ushort_t* h,
    const ushort_t* __restrict__ agg,
    const ushort_t* __restrict__ pb,
    const ushort_t* __restrict__ b0, const ushort_t* __restrict__ g0, const ushort_t* __restrict__ be0,
    const ushort_t* __restrict__ b1, const ushort_t* __restrict__ g1, const ushort_t* __restrict__ be1,
    int rows)
{
    __shared__ __align__(16) ushort_t lds_w[2][32 * 128];   // 2 x 8 KB
    __shared__ __align__(16) ushort_t lds_x[128 * XSTRIDE];
    const int tid  = threadIdx.x;
    const int wave = tid >> 6, lane = tid & 63;
    const int quad = lane >> 4, l16 = lane & 15;
    const int row0  = blockIdx.x * 128;
    const int lrow0 = wave * 32;

    float pbv[8], b0v[8], g0v[8], be0v[8], b1v[8], g1v[8], be1v[8];
#pragma unroll
    for (int n = 0; n < 8; ++n) {
        int col = n * 16 + l16;
        pbv[n]  = b2f(pb[col]);
        b0v[n]  = b2f(b0[col]);  g0v[n] = b2f(g0[col]);  be0v[n] = b2f(be0[col]);
        b1v[n]  = b2f(b1[col]);  g1v[n] = b2f(g1[col]);  be1v[n] = b2f(be1[col]);
    }

    const ushort_t* apH[2]; const ushort_t* apA[2];
#pragma unroll
    for (int t = 0; t < 2; ++t) {
        int grow = row0 + lrow0 + t * 16 + l16;
        int rr = grow < rows ? grow : rows - 1;
        apH[t] = h   + (size_t)rr * 128 + quad * 8;
        apA[t] = agg + (size_t)rr * 128 + quad * 8;
    }

    const ushort_t* ph0 = bf_proj;            const ushort_t* ph1 = bf_proj + 4096;
    const ushort_t* ph2 = bf_proj + 8192;     const ushort_t* ph3 = bf_proj + 12288;
    const ushort_t* pa0 = bf_proj + 16384;    const ushort_t* pa1 = bf_proj + 20480;
    const ushort_t* pa2 = bf_proj + 24576;    const ushort_t* pa3 = bf_proj + 28672;
    const ushort_t* w0c0 = bf_w0;             const ushort_t* w0c1 = bf_w0 + 4096;
    const ushort_t* w0c2 = bf_w0 + 8192;      const ushort_t* w0c3 = bf_w0 + 12288;
    const ushort_t* w1c0 = bf_w1;             const ushort_t* w1c1 = bf_w1 + 4096;
    const ushort_t* w1c2 = bf_w1 + 8192;      const ushort_t* w1c3 = bf_w1 + 12288;

    f32x4 acc[2][8];
#pragma unroll
    for (int t = 0; t < 2; ++t)
#pragma unroll
        for (int n = 0; n < 8; ++n) acc[t][n] = (f32x4){0.f, 0.f, 0.f, 0.f};

    short8 afA[2], afB[2];
    LOADA(afA, apH, 0);
    __builtin_amdgcn_sched_barrier(0);
    STAGE(ph0, 0);
    PCH(afA, afB, apH, 1, 0, ph1, 1, 4, 1, 1);
    PCH(afB, afA, apH, 2, 1, ph2, 0, 4, 1, 1);
    PCH(afA, afB, apH, 3, 0, ph3, 1, 4, 1, 1);
    PCH(afB, afA, apA, 0, 1, pa0, 0, 4, 1, 1);
    PCH(afA, afB, apA, 1, 0, pa1, 1, 4, 1, 1);
    PCH(afB, afA, apA, 2, 1, pa2, 0, 4, 1, 1);
    PCH(afA, afB, apA, 3, 0, pa3, 1, 4, 1, 1);
    PCH(afB, afA, apA, 3, 1, w0c0, 0, 2, 0, 1);   // last P-chunk: no next-A -> vmcnt(2)
    EPI_PROJ();
    XCHUNK(0, 0, 1, w0c1, 1, 2);
    XCHUNK(1, 1, 1, w0c2, 0, 2);
    XCHUNK(2, 0, 1, w0c3, 1, 2);
    XCHUNK(3, 1, 1, w1c0, 0, 2);
    EPI_LN(b0v, g0v, be0v);
    XCHUNK(0, 0, 1, w1c1, 1, 2);
    XCHUNK(1, 1, 1, w1c2, 0, 2);
    XCHUNK(2, 0, 1, w1c3, 1, 2);
    XCHUNK(3, 1, 0, w1c3, 0, 0);
    EPI_LN(b1v, g1v, be1v);

    __syncthreads();
#pragma unroll
    for (int it = 0; it < 8; ++it) {
        int idx  = it * 256 + tid;
        int lrow = idx >> 4;
        int c8   = (idx & 15) << 3;
        int grow = row0 + lrow;
        if (grow < rows) {
            size_t goff = (size_t)grow * 128 + c8;
            short8 xv = *(const short8*)(lds_x + lrow * XSTRIDE + c8);
            short8 hv = *(const short8*)(h + goff);
            short8 yv;
#pragma unroll
            for (int j = 0; j < 8; ++j)
                yv[j] = (short)f2b(b2f((ushort_t)hv[j]) + b2f((ushort_t)xv[j]));
            *(short8*)(h + goff) = yv;
        }
    }
}

extern "C" void kernel_launch(void* const* d_in, const int* in_sizes, int n_in,
                              void* d_out, int out_size, void* d_ws, size_t ws_size,
                              hipStream_t stream) {
    const void* nodes        = d_in[0];
    const void* edges        = d_in[1];
    const int*  senders      = (const int*)d_in[2];
    const int*  receivers    = (const int*)d_in[3];
    const void* w_node_emb   = d_in[4];
    const void* b_node_emb   = d_in[5];
    const void* w_edge_emb   = d_in[6];
    const void* b_edge_emb   = d_in[7];
    const void* edge_proj_w  = d_in[8];
    const void* edge_proj_b  = d_in[9];
    const void* node_proj_w  = d_in[10];
    const void* node_proj_b  = d_in[11];
    const void* edge_mlp_w   = d_in[12];
    const void* edge_mlp_b   = d_in[13];
    const void* edge_ln_g    = d_in[14];
    const void* edge_ln_b    = d_in[15];
    const void* node_mlp_w   = d_in[16];
    const void* node_mlp_b   = d_in[17];
    const void* node_ln_g    = d_in[18];
    const void* node_ln_b    = d_in[19];
    const void* mlp_out_w    = d_in[20];
    const void* mlp_out_b    = d_in[21];
    const void* mlp_out_g    = d_in[22];
    const void* mlp_out_beta = d_in[23];
    const void* proj_w       = d_in[24];
    const void* proj_b       = d_in[25];

    char* ws = (char*)d_ws;
    ushort_t* bf_nodeemb  = (ushort_t*)ws;  ws += (size_t)288 * 128 * 2;   // frag arena start
    ushort_t* bf_edgeproj = (ushort_t*)ws;  ws += (size_t)768 * 128 * 2;
    ushort_t* bf_nodeproj = (ushort_t*)ws;  ws += (size_t)512 * 128 * 2;
    ushort_t* bf_edgemlp  = (ushort_t*)ws;  ws += (size_t)512 * 128 * 2;
    ushort_t* bf_nodemlp  = (ushort_t*)ws;  ws += (size_t)512 * 128 * 2;
    ushort_t* bf_mlpout   = (ushort_t*)ws;  ws += (size_t)128 * 128 * 2;
    ushort_t* h    = (ushort_t*)ws;         ws += (size_t)N_NODES * D * 2;
    ushort_t* e    = (ushort_t*)ws;         ws += (size_t)N_EDGES * D * 2;
    ushort_t* agg  = (ushort_t*)ws;         ws += (size_t)N_NODES * D * 2;
    int*      cnti = (int*)ws;              ws += (size_t)N_NODES * 4;
    int*      offs = (int*)ws;              ws += (size_t)N_NODES * 4;
    int*      curs = (int*)ws;              ws += (size_t)N_NODES * 4;
    int*      eid  = (int*)ws;              ws += (size_t)N_EDGES * 4;
    int*      flag = (int*)ws;              ws += 256;
    ushort_t* bvec = (ushort_t*)ws;         ws += (size_t)37 * 128 * 2;   // bf16 bias arena (+DMA overread pad)
    ushort_t* wT   = (ushort_t*)ws;         ws += (size_t)24 * 128 * 2;   // projT bf16

    hipMemsetAsync(flag, 0, 256, stream);
    k_detect<<<256, 256, 0, stream>>>((const uint32_t*)nodes, flag);

    // consolidated setup (bias packs + projT + all 6 B-fragment transforms in one launch)
    // bvec slots: 0 b_node_emb | 1 b_edge_emb | 2,3 edge_proj_b | 4,5 node_proj_b | 6..9 edge_mlp_b
    // 10..13 edge_ln_g | 14..17 edge_ln_b | 18..21 node_mlp_b | 22..25 node_ln_g
    // 26..29 node_ln_b | 30 mlp_out_b | 31 mlp_out_g | 32 mlp_out_beta
    // 33,34 w_edge_emb | 35 b_edge_emb (wedge table, contiguous for LDS-DMA) | 36 pad
    {
        SetupArgs sa;
        const void* ps[15] = { b_node_emb, b_edge_emb, edge_proj_b, node_proj_b,
                               edge_mlp_b, edge_ln_g, edge_ln_b,
                               node_mlp_b, node_ln_g, node_ln_b,
                               mlp_out_b, mlp_out_g, mlp_out_beta,
                               w_edge_emb, b_edge_emb };
        const int   pn[15] = { 128, 128, 256, 256, 512, 512, 512, 512, 512, 512, 128, 128, 128, 256, 128 };
        const int   pd[15] = { 0, 1, 2, 4, 6, 10, 14, 18, 22, 26, 30, 31, 32, 33, 35 };
        const void* fs[6]  = { w_node_emb, edge_proj_w, node_proj_w, edge_mlp_w, node_mlp_w, mlp_out_w };
        const int   fk[6]  = { 9, 24, 16, 16, 16, 4 };
        const int   fd[6]  = { 0, 36864, 135168, 200704, 266240, 331776 };  // ushort offsets, contiguous arena
        for (int i = 0; i < 15; ++i) { sa.psrc[i] = ps[i]; sa.pn[i] = pn[i]; sa.pdst[i] = pd[i]; }
        for (int i = 0; i < 6;  ++i) { sa.fsrc[i] = fs[i]; sa.fkb[i] = fk[i]; sa.fdst[i] = fd[i]; }
        sa.projw = proj_w;
        // total threads: 4608 (packs) + 3072 (projT) + 43520 (bfrag) = 51200 -> 200 blocks
        k_setup<<<200, 256, 0, stream>>>(sa, bvec, bf_nodeemb, wT, flag);
    }

    // CSR build (receivers constant across both layers)
    hipMemsetAsync(cnti, 0, (size_t)N_NODES * 4, stream);
    k_counti<<<(N_EDGES + 255) / 256, 256, 0, stream>>>(receivers, cnti, N_EDGES);
    k_scan<<<1, 1024, 0, stream>>>(cnti, offs, curs);
    k_fill<<<(N_EDGES + 255) / 256, 256, 0, stream>>>(receivers, curs, eid, N_EDGES);

    {
        const int grid = (N_NODES + 127) / 128;
        k_gemm<3, false><<<grid, 256, 0, stream>>>(
            bf_nodeemb,
            nodes, 1, 288, 0,   128,
            nodes, 1, 288, 128, 128,
            nodes, 1, 288, 256, 32,
            N_NODES, bvec + 0 * 128, nullptr, nullptr, h, flag);
    }

    const int gridE = N_EDGES / 128;           // 2500
    const int gridN = (N_NODES + 127) / 128;   // 157

    for (int l = 0; l < 2; ++l) {
        if (l == 0) {
            k_edge_fused<1><<<gridE, 256, 0, stream>>>(
                bf_edgeproj,
                bf_edgemlp + (size_t)0 * 128 * 128,
                bf_edgemlp + (size_t)1 * 128 * 128,
                e, h, senders, receivers,
                edges, bvec + 33 * 128,
                bvec + 2 * 128,
                bvec + 6 * 128,  bvec + 10 * 128, bvec + 14 * 128,
                bvec + 7 * 128,  bvec + 11 * 128, bvec + 15 * 128,
                flag);
        } else {
            k_edge_fused<0><<<gridE, 256, 0, stream>>>(
                bf_edgeproj + (size_t)384 * 128,
                bf_edgemlp + (size_t)2 * 128 * 128,
                bf_edgemlp + (size_t)3 * 128 * 128,
                e, h, senders, receivers,
                edges, bvec + 33 * 128,
                bvec + 3 * 128,
                bvec + 8 * 128,  bvec + 12 * 128, bvec + 16 * 128,
                bvec + 9 * 128,  bvec + 13 * 128, bvec + 17 * 128,
                flag);
        }
        k_agg<<<(N_NODES + 7) / 8, 256, 0, stream>>>(e, offs, cnti, eid, agg);
        k_node_fused<<<gridN, 256, 0, stream>>>(
            bf_nodeproj + (size_t)l * 256 * 128,
            bf_nodemlp + (size_t)(l * 2 + 0) * 128 * 128,
            bf_nodemlp + (size_t)(l * 2 + 1) * 128 * 128,
            h, agg,
            bvec + (size_t)(4 + l) * 128,
            bvec + (size_t)(18 + l * 2) * 128,     bvec + (size_t)(22 + l * 2) * 128,     bvec + (size_t)(26 + l * 2) * 128,
            bvec + (size_t)(18 + l * 2 + 1) * 128, bvec + (size_t)(22 + l * 2 + 1) * 128, bvec + (size_t)(26 + l * 2 + 1) * 128,
            N_NODES);
    }

    // fused: mlp_out GEMM + gelu + LN + projection straight to d_out
    k_out<<<gridN, 256, 0, stream>>>(
        bf_mlpout, h,
        bvec + 30 * 128, bvec + 31 * 128, bvec + 32 * 128,
        wT, proj_b, d_out, N_NODES, flag);
}

// Round 14
// 555.482 us; speedup vs baseline: 1.4726x; 1.0329x over previous
//
#include <hip/hip_runtime.h>
#include <hip/hip_bf16.h>
#include <stdint.h>

typedef unsigned short ushort_t;
typedef __attribute__((ext_vector_type(8))) short short8;
typedef __attribute__((ext_vector_type(4))) short short4v;
typedef __attribute__((ext_vector_type(4))) float f32x4;
typedef __attribute__((ext_vector_type(4))) int int4v;

#define N_NODES 20000
#define N_EDGES 320000
#define D 128
#define XSTRIDE 136   // padded LDS row stride (ushorts)

#define GAS __attribute__((address_space(1)))
#define LAS __attribute__((address_space(3)))

__device__ __forceinline__ float b2f(ushort_t u) {
    union { float f; uint32_t i; } v; v.i = ((uint32_t)u) << 16; return v.f;
}
// native RNE f32->bf16 (bit-identical to integer-trick RNE); compiler pairs adjacent
// casts into v_cvt_pk_bf16_f32
__device__ __forceinline__ ushort_t f2b(float f) {
    __bf16 h = (__bf16)f;
    return __builtin_bit_cast(ushort_t, h);
}
// dtype-flexible scalar load: raw input arrays may be f32 or bf16 (runtime-detected)
__device__ __forceinline__ float ldf(const void* p, size_t i, bool f32) {
    return f32 ? ((const float*)p)[i] : b2f(((const ushort_t*)p)[i]);
}
// dtype-flexible 8-element A-fragment load (8 consecutive elements, 8-aligned index)
__device__ __forceinline__ short8 lda8(const void* p, size_t i, bool f32) {
    if (f32) {
        const float* fp = (const float*)p + i;
        f32x4 v0 = *(const f32x4*)fp;
        f32x4 v1 = *(const f32x4*)(fp + 4);
        short8 a;
#pragma unroll
        for (int j = 0; j < 4; ++j) {
            a[j]     = (short)f2b(v0[j]);
            a[j + 4] = (short)f2b(v1[j]);
        }
        return a;
    }
    return *(const short8*)((const ushort_t*)p + i);
}
// tanh-gelu with fast reciprocal (v_rcp_f32, ~1ulp) instead of full-precision division
__device__ __forceinline__ float gelu_tanh(float x) {
    float u = 0.7978845608028654f * (x + 0.044715f * x * x * x);
    u = fminf(fmaxf(u, -15.f), 15.f);
    float e = __expf(2.f * u);
    float t = (e - 1.f) * __builtin_amdgcn_rcpf(e + 1.f);
    return 0.5f * x * (1.f + t);
}
__device__ __forceinline__ int clampi(int v, int hi) {  // [0, hi)
    return v < 0 ? 0 : (v >= hi ? hi - 1 : v);
}
// async 16B global->LDS (linear dest, lane-ordered — matches wave-uniform-base+lane*16)
__device__ __forceinline__ void gload_lds16(const void* g, void* l) {
    __builtin_amdgcn_global_load_lds((const GAS uint32_t*)g, (LAS uint32_t*)l, 16, 0, 0);
}
// dual-dtype edge row load (2 scalars)
__device__ __forceinline__ void ldedge(const void* edges, int row, bool f32, float& a0, float& a1) {
    if (f32) {
        const float* p = (const float*)edges + (size_t)row * 2;
        a0 = p[0]; a1 = p[1];
    } else {
        const ushort_t* p = (const ushort_t*)edges + (size_t)row * 2;
        a0 = b2f(p[0]); a1 = b2f(p[1]);
    }
}
// e_init fragment: 8 consecutive cols of a0*w0 + a1*w1 + b from the wedge LDS table
__device__ __forceinline__ short8 einit8(const ushort_t* wedge, int colbase, float a0, float a1) {
    short8 w0 = *(const short8*)(wedge + colbase);
    short8 w1 = *(const short8*)(wedge + 128 + colbase);
    short8 bb = *(const short8*)(wedge + 256 + colbase);
    short8 r;
#pragma unroll
    for (int j = 0; j < 8; ++j)
        r[j] = (short)f2b(a0 * b2f((ushort_t)w0[j]) + a1 * b2f((ushort_t)w1[j]) + b2f((ushort_t)bb[j]));
    return r;
}

// row-wise LN over 128 cols spread as x[n] on 16 lanes (same quad group)
__device__ __forceinline__ void ln8(float x[8], const float gv[8], const float bv[8]) {
    float s1 = 0.f, s2 = 0.f;
#pragma unroll
    for (int n = 0; n < 8; ++n) { s1 += x[n]; s2 += x[n] * x[n]; }
#pragma unroll
    for (int m = 1; m < 16; m <<= 1) {
        s1 += __shfl_xor(s1, m, 64);
        s2 += __shfl_xor(s2, m, 64);
    }
    float mean = s1 * (1.f / 128.f);
    float var  = fmaxf(s2 * (1.f / 128.f) - mean * mean, 0.f);
    float rs   = __builtin_amdgcn_rsqf(var + 1e-5f);
#pragma unroll
    for (int n = 0; n < 8; ++n) x[n] = (x[n] - mean) * rs * gv[n] + bv[n];
}

// Detect whether float inputs are f32 (flag=1) or bf16 (flag=0).
__global__ void k_detect(const uint32_t* __restrict__ raw, int* __restrict__ flag) {
    int t = blockIdx.x * blockDim.x + threadIdx.x;   // 65536 threads
    uint32_t u = raw[t];
    int e_lo = (u >> 7)  & 0xFF;
    int e_hi = (u >> 23) & 0xFF;
    if (e_lo == 0xFF || e_hi == 0xFF) atomicOr(flag, 1);
}

// ---------------- consolidated setup: bias packs + projT + all B-fragment transforms ----------------
struct SetupArgs {
    const void* psrc[15];
    int         pn[15];
    int         pdst[15];
    const void* fsrc[6];
    int         fkb[6];
    int         fdst[6];     // dst offset into frag arena (ushort units)
    const void* projw;
};

__global__ void k_setup(SetupArgs a, ushort_t* __restrict__ bvec, ushort_t* __restrict__ frag,
                        ushort_t* __restrict__ wT, const int* __restrict__ dflag) {
    const bool f32 = *dflag != 0;
    int t = blockIdx.x * blockDim.x + threadIdx.x;
    if (t < 4608) {                      // bias packs
        int i = t, d = 0;
        while (i >= a.pn[d]) { i -= a.pn[d]; ++d; }
        bvec[(size_t)a.pdst[d] * 128 + i] = f2b(ldf(a.psrc[d], i, f32));
        return;
    }
    t -= 4608;
    if (t < 3072) {                      // projT
        int p = t >> 7, k = t & 127;
        wT[p * 128 + k] = f2b(ldf(a.projw, (size_t)k * 24 + p, f32));
        return;
    }
    t -= 3072;
    if (t >= 43520) return;              // bfrag region: sum(fkb)=85 -> 85*512 groups
    int g = t, d = 0;
    while (g >= a.fkb[d] * 512) { g -= a.fkb[d] * 512; ++d; }
    const void* src = a.fsrc[d];
    int kblk = g >> 9;
    int rem  = g & 511;
    int nt   = rem >> 6;
    int lane = rem & 63;
    int krow = kblk * 32 + ((lane >> 4) << 3);
    int col  = nt * 16 + (lane & 15);
    short8 v;
#pragma unroll
    for (int j = 0; j < 8; ++j) v[j] = (short)f2b(ldf(src, (size_t)(krow + j) * 128 + col, f32));
    *(short8*)(frag + (size_t)a.fdst[d] + (size_t)g * 8) = v;
}

// ---------------- CSR build for receiver-side aggregation ----------------
__global__ void k_counti(const int* __restrict__ recv, int* __restrict__ cnti, int E) {
    int i = blockIdx.x * blockDim.x + threadIdx.x;
    if (i < E) atomicAdd(&cnti[clampi(recv[i], N_NODES)], 1);
}

// single-block exclusive scan of cnti -> offs (and cursor copy)
__global__ void k_scan(const int* __restrict__ cnti, int* __restrict__ offs,
                       int* __restrict__ cursor) {
    __shared__ int part[1024];
    const int t = threadIdx.x;           // blockDim = 1024
    const int base = t * 20;             // 1024*20 = 20480 >= N_NODES
    int s = 0;
#pragma unroll 4
    for (int j = 0; j < 20; ++j) {
        int idx = base + j;
        if (idx < N_NODES) s += cnti[idx];
    }
    part[t] = s;
    __syncthreads();
    for (int off = 1; off < 1024; off <<= 1) {
        int v = (t >= off) ? part[t - off] : 0;
        __syncthreads();
        part[t] += v;
        __syncthreads();
    }
    int run = (t == 0) ? 0 : part[t - 1];   // exclusive prefix
    for (int j = 0; j < 20; ++j) {
        int idx = base + j;
        if (idx < N_NODES) {
            offs[idx]   = run;
            cursor[idx] = run;
            run += cnti[idx];
        }
    }
}

__global__ void k_fill(const int* __restrict__ recv, int* __restrict__ cursor,
                       int* __restrict__ eid, int E) {
    int i = blockIdx.x * blockDim.x + threadIdx.x;
    if (i < E) {
        int r = clampi(recv[i], N_NODES);
        int pos = atomicAdd(&cursor[r], 1);
        eid[pos] = i;
    }
}

// gather-mean aggregation: agg[n] = mean over incident edges of e[eid] (bf16 out)
// 4-way unrolled: 4 independent eid loads + 4 independent row gathers in flight (ILP vs
// the previous 1-deep serial chain; this kernel is latency-bound, not BW-bound)
__global__ void k_agg(const ushort_t* __restrict__ e, const int* __restrict__ offs,
                      const int* __restrict__ cnti, const int* __restrict__ eid,
                      ushort_t* __restrict__ agg) {
    const int tid = threadIdx.x;
    const int n = blockIdx.x * 8 + (tid >> 5);   // 8 nodes / 256-thread block
    const int l = tid & 31;                      // 32 lanes x 4 cols = 128 cols
    if (n >= N_NODES) return;
    const int start = offs[n], deg = cnti[n];
    float s0 = 0.f, s1 = 0.f, s2 = 0.f, s3 = 0.f;
    int j = 0;
    for (; j + 4 <= deg; j += 4) {
        int i0 = eid[start + j];
        int i1 = eid[start + j + 1];
        int i2 = eid[start + j + 2];
        int i3 = eid[start + j + 3];
        short4v v0 = *(const short4v*)(e + (size_t)i0 * 128 + l * 4);
        short4v v1 = *(const short4v*)(e + (size_t)i1 * 128 + l * 4);
        short4v v2 = *(const short4v*)(e + (size_t)i2 * 128 + l * 4);
        short4v v3 = *(const short4v*)(e + (size_t)i3 * 128 + l * 4);
        s0 += b2f((ushort_t)v0[0]) + b2f((ushort_t)v1[0]) + b2f((ushort_t)v2[0]) + b2f((ushort_t)v3[0]);
        s1 += b2f((ushort_t)v0[1]) + b2f((ushort_t)v1[1]) + b2f((ushort_t)v2[1]) + b2f((ushort_t)v3[1]);
        s2 += b2f((ushort_t)v0[2]) + b2f((ushort_t)v1[2]) + b2f((ushort_t)v2[2]) + b2f((ushort_t)v3[2]);
        s3 += b2f((ushort_t)v0[3]) + b2f((ushort_t)v1[3]) + b2f((ushort_t)v2[3]) + b2f((ushort_t)v3[3]);
    }
    for (; j < deg; ++j) {
        const ushort_t* row = e + (size_t)eid[start + j] * 128 + l * 4;
        short4v v = *(const short4v*)row;
        s0 += b2f((ushort_t)v[0]);
        s1 += b2f((ushort_t)v[1]);
        s2 += b2f((ushort_t)v[2]);
        s3 += b2f((ushort_t)v[3]);
    }
    const float inv = 1.f / (float)(deg < 1 ? 1 : deg);
    short4v o;
    o[0] = (short)f2b(s0 * inv);
    o[1] = (short)f2b(s1 * inv);
    o[2] = (short)f2b(s2 * inv);
    o[3] = (short)f2b(s3 * inv);
    *(short4v*)(agg + (size_t)n * 128 + l * 4) = o;
}

// ---------------- generic GEMM (node embedding) ----------------
template<int NC, bool LN>
__global__ __launch_bounds__(256, 2) void k_gemm(
    const ushort_t* __restrict__ bfrag,
    const void* s0, int isf0, int st0, int ko0, int kl0,
    const void* s1, int isf1, int st1, int ko1, int kl1,
    const void* s2, int isf2, int st2, int ko2, int kl2,
    int rows,
    const ushort_t* __restrict__ bias,
    const ushort_t* __restrict__ gamma,
    const ushort_t* __restrict__ betap,
    ushort_t* out,
    const int* __restrict__ dflag)
{
    __shared__ __align__(16) ushort_t lds_b[128 * 128];
    const bool f32g = *dflag != 0;
    const int tid  = threadIdx.x;
    const int wave = tid >> 6, lane = tid & 63;
    const int quad = lane >> 4, l16 = lane & 15;
    const int row0 = blockIdx.x * 128 + wave * 32;

    f32x4 acc[2][8];
#pragma unroll
    for (int t = 0; t < 2; ++t)
#pragma unroll
        for (int n = 0; n < 8; ++n) acc[t][n] = (f32x4){0.f, 0.f, 0.f, 0.f};

    const ushort_t* bptr = bfrag;
#pragma unroll
    for (int c = 0; c < NC; ++c) {
        const void* src  = (c == 0) ? s0 : ((c == 1) ? s1 : s2);
        const bool  eff  = (((c == 0) ? isf0 : ((c == 1) ? isf1 : isf2)) != 0) && f32g;
        const int stride = (c == 0) ? st0 : ((c == 1) ? st1 : st2);
        const int koff   = (c == 0) ? ko0 : ((c == 1) ? ko1 : ko2);
        const int klen   = (c == 0) ? kl0 : ((c == 1) ? kl1 : kl2);

        if (c) __syncthreads();
        {
            const int ngrp = klen * 16;
            for (int g = tid; g < ngrp; g += 256)
                gload_lds16(bptr + (size_t)g * 8, lds_b + (size_t)g * 8);
        }
        __syncthreads();   // full drain: staging resident

        size_t aoff[2];
#pragma unroll
        for (int t = 0; t < 2; ++t) {
            int r  = row0 + t * 16 + l16;
            int rr = r < rows ? r : rows - 1;
            aoff[t] = (size_t)rr * stride + koff + quad * 8;
        }
        const int ksteps = klen >> 5;
        for (int ks = 0; ks < ksteps; ++ks) {
            short8 af[2];
#pragma unroll
            for (int t = 0; t < 2; ++t)
                af[t] = lda8(src, aoff[t] + ks * 32, eff);
#pragma unroll
            for (int n = 0; n < 8; ++n) {
                short8 bf = *(const short8*)(lds_b + (size_t)((ks * 8 + n) * 64 + lane) * 8);
                acc[0][n] = __builtin_amdgcn_mfma_f32_16x16x32_bf16(af[0], bf, acc[0][n], 0, 0, 0);
                acc[1][n] = __builtin_amdgcn_mfma_f32_16x16x32_bf16(af[1], bf, acc[1][n], 0, 0, 0);
            }
        }
        bptr += (size_t)klen * 128;
    }

    float bv[8], gv[8], btv[8];
#pragma unroll
    for (int n = 0; n < 8; ++n) {
        int col = n * 16 + l16;
        bv[n] = b2f(bias[col]);
        if (LN) { gv[n] = b2f(gamma[col]); btv[n] = b2f(betap[col]); }
    }
#pragma unroll
    for (int t = 0; t < 2; ++t) {
#pragma unroll
        for (int r = 0; r < 4; ++r) {
            int row = row0 + t * 16 + quad * 4 + r;
            float x[8];
#pragma unroll
            for (int n = 0; n < 8; ++n) x[n] = acc[t][n][r] + bv[n];
            if (LN) {
#pragma unroll
                for (int n = 0; n < 8; ++n) x[n] = gelu_tanh(x[n]);
                ln8(x, gv, btv);
            }
            if (row < rows) {
#pragma unroll
                for (int n = 0; n < 8; ++n)
                    out[(size_t)row * 128 + n * 16 + l16] = f2b(x[n]);
            }
        }
    }
}

// ---------------- fused output: mlp_out GEMM + gelu + LN + projection to d_out ----------------
__global__ __launch_bounds__(256, 2) void k_out(
    const ushort_t* __restrict__ bfrag,     // bf_mlpout
    const ushort_t* __restrict__ h,
    const ushort_t* __restrict__ bias,
    const ushort_t* __restrict__ gamma,
    const ushort_t* __restrict__ betap,
    const ushort_t* __restrict__ wT,        // [24][128] bf16
    const void* __restrict__ pb,            // proj_b raw
    void* __restrict__ out, int rows,
    const int* __restrict__ dflag)
{
    __shared__ __align__(16) ushort_t lds_b[128 * 128];
    __shared__ __align__(16) ushort_t lds_x[128 * XSTRIDE];
    const bool f32g = *dflag != 0;
    const int tid  = threadIdx.x;
    const int wave = tid >> 6, lane = tid & 63;
    const int quad = lane >> 4, l16 = lane & 15;
    const int row0  = blockIdx.x * 128;
    const int lrow0 = wave * 32;

    for (int g = tid; g < 2048; g += 256)
        gload_lds16(bfrag + (size_t)g * 8, lds_b + (size_t)g * 8);
    __syncthreads();

    f32x4 acc[2][8];
#pragma unroll
    for (int t = 0; t < 2; ++t)
#pragma unroll
        for (int n = 0; n < 8; ++n) acc[t][n] = (f32x4){0.f, 0.f, 0.f, 0.f};

    const ushort_t* ap[2];
#pragma unroll
    for (int t = 0; t < 2; ++t) {
        int grow = row0 + lrow0 + t * 16 + l16;
        int rr = grow < rows ? grow : rows - 1;
        ap[t] = h + (size_t)rr * 128 + quad * 8;
    }
    for (int ks = 0; ks < 4; ++ks) {
        short8 af[2];
#pragma unroll
        for (int t = 0; t < 2; ++t) af[t] = *(const short8*)(ap[t] + ks * 32);
#pragma unroll
        for (int n = 0; n < 8; ++n) {
            short8 bf = *(const short8*)(lds_b + (size_t)((ks * 8 + n) * 64 + lane) * 8);
            acc[0][n] = __builtin_amdgcn_mfma_f32_16x16x32_bf16(af[0], bf, acc[0][n], 0, 0, 0);
            acc[1][n] = __builtin_amdgcn_mfma_f32_16x16x32_bf16(af[1], bf, acc[1][n], 0, 0, 0);
        }
    }

    {
        float bv[8], gv[8], btv[8];
#pragma unroll
        for (int n = 0; n < 8; ++n) {
            int col = n * 16 + l16;
            bv[n] = b2f(bias[col]); gv[n] = b2f(gamma[col]); btv[n] = b2f(betap[col]);
        }
#pragma unroll
        for (int t = 0; t < 2; ++t)
#pragma unroll
            for (int r = 0; r < 4; ++r) {
                int lrow = lrow0 + t * 16 + quad * 4 + r;
                float x[8];
#pragma unroll
                for (int n = 0; n < 8; ++n) x[n] = gelu_tanh(acc[t][n][r] + bv[n]);
                ln8(x, gv, btv);
#pragma unroll
                for (int n = 0; n < 8; ++n)
                    lds_x[lrow * XSTRIDE + n * 16 + l16] = f2b(x[n]);
            }
    }
    __syncthreads();

    // projection: 128 rows x 24 outputs = 3072 -> 12 per thread
#pragma unroll
    for (int it = 0; it < 12; ++it) {
        int idx  = it * 256 + tid;
        int lrow = idx / 24;
        int p    = idx - lrow * 24;
        int grow = row0 + lrow;
        if (grow < rows) {
            float a2 = ldf(pb, p, f32g);
            const ushort_t* xp = lds_x + lrow * XSTRIDE;
            const ushort_t* wp = wT + (size_t)p * 128;
#pragma unroll
            for (int k8 = 0; k8 < 16; ++k8) {
                short8 hv = *(const short8*)(xp + k8 * 8);
                short8 wv = *(const short8*)(wp + k8 * 8);
#pragma unroll
                for (int j = 0; j < 8; ++j)
                    a2 += b2f((ushort_t)hv[j]) * b2f((ushort_t)wv[j]);
            }
            if (f32g) ((float*)out)[(size_t)grow * 24 + p] = a2;
            else      ((ushort_t*)out)[(size_t)grow * 24 + p] = f2b(a2);
        }
    }
}

// ======== BK=32 chunked double-buffered pipeline (3 blocks/CU) ========
// Chunk = 32-K slice = 8 KB of B-fragments in lds_w[buf]. A-fragments prefetched one
// chunk ahead. Steady-state per-wave vmcnt ledger:
//   [af_cur(2), stage_cur(2), af_next(2), stage_next(2)] -> vmcnt(4)
// boundary chunks (no next-A): vmcnt(2); last X chunk: vmcnt(0).
// T5: s_setprio(1) around the MFMA cluster — with 3 blocks/CU the co-resident blocks
// are at different phases, so the CU scheduler can favor MFMA-entering waves.

#define STAGE(srcp, bufi) do {                                                   \
    const ushort_t* s__ = (srcp);                                                \
    _Pragma("unroll")                                                            \
    for (int it__ = 0; it__ < 2; ++it__) {                                       \
        int g__ = it__ * 256 + tid;                                              \
        gload_lds16(s__ + (size_t)g__ * 8, &lds_w[bufi][(size_t)g__ * 8]);       \
    } } while (0)

#define LOADA(dst, apv, kn) do {                                                 \
    _Pragma("unroll") for (int t_ = 0; t_ < 2; ++t_)                             \
        dst[t_] = *(const short8*)(apv[t_] + (kn) * 32);                         \
    } while (0)

#define PCH(AFU, AFN, apv, kn, bufi, nsrc, nbuf, VM, DO_A, DO_STAGE) do {        \
    if (DO_A) LOADA(AFN, apv, kn);                                               \
    __builtin_amdgcn_sched_barrier(0);                                           \
    if (DO_STAGE) STAGE(nsrc, nbuf);                                             \
    asm volatile("s_waitcnt vmcnt(" #VM ")" ::: "memory");                       \
    __builtin_amdgcn_s_barrier();                                                \
    __builtin_amdgcn_sched_barrier(0);                                           \
    __builtin_amdgcn_s_setprio(1);                                               \
    _Pragma("unroll") for (int n_ = 0; n_ < 8; ++n_) {                           \
        short8 bf_ = *(const short8*)(&lds_w[bufi][(size_t)(n_ * 64 + lane) * 8]); \
        acc[0][n_] = __builtin_amdgcn_mfma_f32_16x16x32_bf16(AFU[0], bf_, acc[0][n_], 0, 0, 0); \
        acc[1][n_] = __builtin_amdgcn_mfma_f32_16x16x32_bf16(AFU[1], bf_, acc[1][n_], 0, 0, 0); \
    }                                                                            \
    __builtin_amdgcn_s_setprio(0);                                               \
    __builtin_amdgcn_sched_barrier(0);                                           \
    __builtin_amdgcn_s_barrier();                                                \
} while (0)

#define XCHUNK(kx, bufi, DO_STAGE, nsrc, nbuf, VM) do {                          \
    if (DO_STAGE) STAGE(nsrc, nbuf);                                             \
    asm volatile("s_waitcnt vmcnt(" #VM ")" ::: "memory");                       \
    __builtin_amdgcn_s_barrier();                                                \
    __builtin_amdgcn_sched_barrier(0);                                           \
    {                                                                            \
        short8 af_[2];                                                           \
        _Pragma("unroll") for (int t_ = 0; t_ < 2; ++t_)                         \
            af_[t_] = *(const short8*)(lds_x + (size_t)(lrow0 + t_ * 16 + l16) * XSTRIDE \
                                       + (kx) * 32 + quad * 8);                  \
        __builtin_amdgcn_s_setprio(1);                                           \
        _Pragma("unroll") for (int n_ = 0; n_ < 8; ++n_) {                       \
            short8 bf_ = *(const short8*)(&lds_w[bufi][(size_t)(n_ * 64 + lane) * 8]); \
            acc[0][n_] = __builtin_amdgcn_mfma_f32_16x16x32_bf16(af_[0], bf_, acc[0][n_], 0, 0, 0); \
            acc[1][n_] = __builtin_amdgcn_mfma_f32_16x16x32_bf16(af_[1], bf_, acc[1][n_], 0, 0, 0); \
        }                                                                        \
        __builtin_amdgcn_s_setprio(0);                                           \
    }                                                                            \
    __builtin_amdgcn_sched_barrier(0);                                           \
    __builtin_amdgcn_s_barrier();                                                \
} while (0)

#define EPI_PROJ() do {                                                          \
    _Pragma("unroll") for (int t_ = 0; t_ < 2; ++t_)                             \
    _Pragma("unroll") for (int r_ = 0; r_ < 4; ++r_) {                           \
        int lr_ = lrow0 + t_ * 16 + quad * 4 + r_;                               \
        _Pragma("unroll") for (int n_ = 0; n_ < 8; ++n_)                         \
            lds_x[lr_ * XSTRIDE + n_ * 16 + l16] = f2b(acc[t_][n_][r_] + pbv[n_]); \
    }                                                                            \
    _Pragma("unroll") for (int t_ = 0; t_ < 2; ++t_)                             \
    _Pragma("unroll") for (int n_ = 0; n_ < 8; ++n_) acc[t_][n_] = (f32x4){0.f, 0.f, 0.f, 0.f}; \
} while (0)

#define EPI_LN(BV, GV, BEV) do {                                                 \
    _Pragma("unroll") for (int t_ = 0; t_ < 2; ++t_)                             \
    _Pragma("unroll") for (int r_ = 0; r_ < 4; ++r_) {                           \
        int lr_ = lrow0 + t_ * 16 + quad * 4 + r_;                               \
        float x_[8];                                                             \
        _Pragma("unroll") for (int n_ = 0; n_ < 8; ++n_) x_[n_] = gelu_tanh(acc[t_][n_][r_] + BV[n_]); \
        ln8(x_, GV, BEV);                                                        \
        _Pragma("unroll") for (int n_ = 0; n_ < 8; ++n_)                         \
            lds_x[lr_ * XSTRIDE + n_ * 16 + l16] = f2b(x_[n_]);                  \
    }                                                                            \
    _Pragma("unroll") for (int t_ = 0; t_ < 2; ++t_)                             \
    _Pragma("unroll") for (int n_ = 0; n_ < 8; ++n_) acc[t_][n_] = (f32x4){0.f, 0.f, 0.f, 0.f}; \
} while (0)

// ---------------- fused edge pipeline: [L0: inline e_init] proj(K=384) -> MLP1 -> MLP2 + residual ----------------
template<int L0>
__global__ __launch_bounds__(256, 3) void k_edge_fused(
    const ushort_t* __restrict__ bf_proj,
    const ushort_t* __restrict__ bf_w0,
    const ushort_t* __restrict__ bf_w1,
    ushort_t* e_glob,
    const ushort_t* __restrict__ h,
    const int* __restrict__ senders, const int* __restrict__ receivers,
    const void* __restrict__ edges_raw,        // raw edge features [E][2] (dual-dtype), L0 only
    const ushort_t* __restrict__ wedge_arena,  // bvec slots 33..35: w0[128] w1[128] be[128] bf16
    const ushort_t* __restrict__ pb,
    const ushort_t* __restrict__ b0, const ushort_t* __restrict__ g0, const ushort_t* __restrict__ be0,
    const ushort_t* __restrict__ b1, const ushort_t* __restrict__ g1, const ushort_t* __restrict__ be1,
    const int* __restrict__ dflag)
{
    __shared__ __align__(16) ushort_t lds_w[2][32 * 128];   // 2 x 8 KB
    __shared__ __align__(16) ushort_t lds_x[128 * XSTRIDE];
    __shared__ __align__(16) ushort_t wedge[512];   // 1 KB: w0|w1|be (+overread pad)
    const int tid  = threadIdx.x;
    const int wave = tid >> 6, lane = tid & 63;
    const int quad = lane >> 4, l16 = lane & 15;
    const int row0  = blockIdx.x * 128;   // 320000 % 128 == 0: all rows valid
    const int lrow0 = wave * 32;
    const bool f32g = L0 ? (*dflag != 0) : false;

    // hoist all epilogue constants so no stray VMEM perturbs vmcnt counting
    float pbv[8], b0v[8], g0v[8], be0v[8], b1v[8], g1v[8], be1v[8];
#pragma unroll
    for (int n = 0; n < 8; ++n) {
        int col = n * 16 + l16;
        pbv[n]  = b2f(pb[col]);
        b0v[n]  = b2f(b0[col]);  g0v[n] = b2f(g0[col]);  be0v[n] = b2f(be0[col]);
        b1v[n]  = b2f(b1[col]);  g1v[n] = b2f(g1[col]);  be1v[n] = b2f(be1[col]);
    }

    // A-source pointers (E-stage pointers only needed for L1)
    const ushort_t* apE[2]; const ushort_t* apS[2]; const ushort_t* apR[2];
#pragma unroll
    for (int t = 0; t < 2; ++t) {
        int grow = row0 + lrow0 + t * 16 + l16;
        apE[t] = e_glob + (size_t)grow * 128 + quad * 8;
        apS[t] = h + (size_t)clampi(senders[grow],   N_NODES) * 128 + quad * 8;
        apR[t] = h + (size_t)clampi(receivers[grow], N_NODES) * 128 + quad * 8;
    }

    // 32-K chunk pointers (8 KB = 4096 ushorts each)
    const ushort_t* pe0 = bf_proj;                const ushort_t* pe1 = bf_proj + 4096;
    const ushort_t* pe2 = bf_proj + 8192;         const ushort_t* pe3 = bf_proj + 12288;
    const ushort_t* ps0 = bf_proj + 16384;        const ushort_t* ps1 = bf_proj + 20480;
    const ushort_t* ps2 = bf_proj + 24576;        const ushort_t* ps3 = bf_proj + 28672;
    const ushort_t* pr0 = bf_proj + 32768;        const ushort_t* pr1 = bf_proj + 36864;
    const ushort_t* pr2 = bf_proj + 40960;        const ushort_t* pr3 = bf_proj + 45056;
    const ushort_t* w0c0 = bf_w0;                 const ushort_t* w0c1 = bf_w0 + 4096;
    const ushort_t* w0c2 = bf_w0 + 8192;          const ushort_t* w0c3 = bf_w0 + 12288;
    const ushort_t* w1c0 = bf_w1;                 const ushort_t* w1c1 = bf_w1 + 4096;
    const ushort_t* w1c2 = bf_w1 + 8192;          const ushort_t* w1c3 = bf_w1 + 12288;

    f32x4 acc[2][8];
#pragma unroll
    for (int t = 0; t < 2; ++t)
#pragma unroll
        for (int n = 0; n < 8; ++n) acc[t][n] = (f32x4){0.f, 0.f, 0.f, 0.f};

    short8 afA[2], afB[2];

    if (L0) {
        // stage wedge table (wave 0: 64 lanes x 16B = 1 KB, overreads into spare slot)
        if (wave == 0)
            gload_lds16(wedge_arena + (size_t)lane * 8, wedge + (size_t)lane * 8);
        // per-lane edge feature loads (2 rows)
        float a0f[2], a1f[2];
#pragma unroll
        for (int t = 0; t < 2; ++t) {
            int grow = row0 + lrow0 + t * 16 + l16;
            ldedge(edges_raw, grow, f32g, a0f[t], a1f[t]);
        }
        asm volatile("s_waitcnt vmcnt(0)" ::: "memory");
        __builtin_amdgcn_s_barrier();
        // compute all four e-chunk A-fragments in registers (no VMEM)
        short8 afE0[2], afE1[2], afE2[2], afE3[2];
#pragma unroll
        for (int t = 0; t < 2; ++t) {
            afE0[t] = einit8(wedge, 0 * 32 + quad * 8, a0f[t], a1f[t]);
            afE1[t] = einit8(wedge, 1 * 32 + quad * 8, a0f[t], a1f[t]);
            afE2[t] = einit8(wedge, 2 * 32 + quad * 8, a0f[t], a1f[t]);
            afE3[t] = einit8(wedge, 3 * 32 + quad * 8, a0f[t], a1f[t]);
        }
        STAGE(pe0, 0);
        // ledger: E0..E2 [S,S]->vmcnt2 | E3 [S,A,S]->vmcnt4 | S0..R2 steady->vmcnt4 | R3 ->vmcnt2
        PCH(afE0, afA, apS, 0, 0, pe1, 1, 2, 0, 1);
        PCH(afE1, afA, apS, 0, 1, pe2, 0, 2, 0, 1);
        PCH(afE2, afA, apS, 0, 0, pe3, 1, 2, 0, 1);
        PCH(afE3, afA, apS, 0, 1, ps0, 0, 4, 1, 1);
        PCH(afA,  afB, apS, 1, 0, ps1, 1, 4, 1, 1);
        PCH(afB,  afA, apS, 2, 1, ps2, 0, 4, 1, 1);
        PCH(afA,  afB, apS, 3, 0, ps3, 1, 4, 1, 1);
        PCH(afB,  afA, apR, 0, 1, pr0, 0, 4, 1, 1);
        PCH(afA,  afB, apR, 1, 0, pr1, 1, 4, 1, 1);
        PCH(afB,  afA, apR, 2, 1, pr2, 0, 4, 1, 1);
        PCH(afA,  afB, apR, 3, 0, pr3, 1, 4, 1, 1);
        PCH(afB,  afA, apR, 3, 1, w0c0, 0, 2, 0, 1);
    } else {
        LOADA(afA, apE, 0);
        __builtin_amdgcn_sched_barrier(0);
        STAGE(pe0, 0);
        PCH(afA, afB, apE, 1, 0, pe1, 1, 4, 1, 1);
        PCH(afB, afA, apE, 2, 1, pe2, 0, 4, 1, 1);
        PCH(afA, afB, apE, 3, 0, pe3, 1, 4, 1, 1);
        PCH(afB, afA, apS, 0, 1, ps0, 0, 4, 1, 1);
        PCH(afA, afB, apS, 1, 0, ps1, 1, 4, 1, 1);
        PCH(afB, afA, apS, 2, 1, ps2, 0, 4, 1, 1);
        PCH(afA, afB, apS, 3, 0, ps3, 1, 4, 1, 1);
        PCH(afB, afA, apR, 0, 1, pr0, 0, 4, 1, 1);
        PCH(afA, afB, apR, 1, 0, pr1, 1, 4, 1, 1);
        PCH(afB, afA, apR, 2, 1, pr2, 0, 4, 1, 1);
        PCH(afA, afB, apR, 3, 0, pr3, 1, 4, 1, 1);
        PCH(afB, afA, apR, 3, 1, w0c0, 0, 2, 0, 1);
    }
    EPI_PROJ();                          // wave-private lds_x; overlaps w0c0 flight
    XCHUNK(0, 0, 1, w0c1, 1, 2);
    XCHUNK(1, 1, 1, w0c2, 0, 2);
    XCHUNK(2, 0, 1, w0c3, 1, 2);
    XCHUNK(3, 1, 1, w1c0, 0, 2);
    EPI_LN(b0v, g0v, be0v);              // MLP1 epilogue; overlaps w1c0 flight
    XCHUNK(0, 0, 1, w1c1, 1, 2);
    XCHUNK(1, 1, 1, w1c2, 0, 2);
    XCHUNK(2, 0, 1, w1c3, 1, 2);
    XCHUNK(3, 1, 0, w1c3, 0, 0);
    EPI_LN(b1v, g1v, be1v);              // final LN -> lds_x

    __syncthreads();
#pragma unroll
    for (int it = 0; it < 8; ++it) {
        int idx  = it * 256 + tid;          // 0..2047 -> 128 rows x 16 chunks
        int lrow = idx >> 4;
        int c8   = (idx & 15) << 3;
        size_t goff = (size_t)(row0 + lrow) * 128 + c8;
        short8 xv = *(const short8*)(lds_x + lrow * XSTRIDE + c8);
        short8 yv;
        if (L0) {
            // residual base = e_init recomputed in f32 (never materialized)
            float ea0, ea1;
            ldedge(edges_raw, row0 + lrow, f32g, ea0, ea1);
            short8 w0 = *(const short8*)(wedge + c8);
            short8 w1 = *(const short8*)(wedge + 128 + c8);
            short8 bb = *(const short8*)(wedge + 256 + c8);
#pragma unroll
            for (int j = 0; j < 8; ++j) {
                float base = ea0 * b2f((ushort_t)w0[j]) + ea1 * b2f((ushort_t)w1[j]) + b2f((ushort_t)bb[j]);
                yv[j] = (short)f2b(base + b2f((ushort_t)xv[j]));
            }
        } else {
            short8 ev = *(const short8*)(e_glob + goff);
#pragma unroll
            for (int j = 0; j < 8; ++j)
                yv[j] = (short)f2b(b2f((ushort_t)ev[j]) + b2f((ushort_t)xv[j]));
        }
        *(short8*)(e_glob + goff) = yv;
    }
}

// ---------------- fused node pipeline: proj(K=256) -> MLP1 -> MLP2 + residual ----------------
__global__ __launch_bounds__(256, 3) void k_node_fused(
    const ushort_t* __restrict__ bf_proj,
    const ushort_t* __restrict__ bf_w0,
    const ushort_t* __restrict__ bf_w1,
    ushort_t* h,
    const ushort_t* __restrict__ agg,
    const ushort_t* __restrict__ pb,
    const ushort_t* __restrict__ b0, const ushort_t* __restrict__ g0, const ushort_t* __restrict__ be0,
    const ushort_t* __restrict__ b1, const ushort_t* __restrict__ g1, const ushort_t* __restrict__ be1,
    int rows)
{
    __shared__ __align__(16) ushort_t lds_w[2][32 * 128];   // 2 x 8 KB
    __shared__ __align__(16) ushort_t lds_x[128 * XSTRIDE];
    const int tid  = threadIdx.x;
    const int wave = tid >> 6, lane = tid & 63;
    const int quad = lane >> 4, l16 = lane & 15;
    const int row0  = blockIdx.x * 128;
    const int lrow0 = wave * 32;

    float pbv[8], b0v[8], g0v[8], be0v[8], b1v[8], g1v[8], be1v[8];
#pragma unroll
    for (int n = 0; n < 8; ++n) {
        int col = n * 16 + l16;
        pbv[n]  = b2f(pb[col]);
        b0v[n]  = b2f(b0[col]);  g0v[n] = b2f(g0[col]);  be0v[n] = b2f(be0[col]);
        b1v[n]  = b2f(b1[col]);  g1v[n] = b2f(g1[col]);  be1v[n] = b2f(be1[col]);
    }

    const ushort_t* apH[2]; const ushort_t* apA[2];
#pragma unroll
    for (int t = 0; t < 2; ++t) {
        int grow = row0 + lrow0 + t * 16 + l16;
        int rr = grow < rows ? grow : rows - 1;
        apH[t] = h   + (size_t)rr * 128 + quad * 8;
        apA[t] = agg + (size_t)rr * 128 + quad * 8;
    }

    const ushort_t* ph0 = bf_proj;            const ushort_t* ph1 = bf_proj + 4096;
    const ushort_t* ph2 = bf_proj + 8192;     const ushort_t* ph3 = bf_proj + 12288;
    const ushort_t* pa0 = bf_proj + 16384;    const ushort_t* pa1 = bf_proj + 20480;
    const ushort_t* pa2 = bf_proj + 24576;    const ushort_t* pa3 = bf_proj + 28672;
    const ushort_t* w0c0 = bf_w0;             const ushort_t* w0c1 = bf_w0 + 4096;
    const ushort_t* w0c2 = bf_w0 + 8192;      const ushort_t* w0c3 = bf_w0 + 12288;
    const ushort_t* w1c0 = bf_w1;             const ushort_t* w1c1 = bf_w1 + 4096;
    const ushort_t* w1c2 = bf_w1 + 8192;      const ushort_t* w1c3 = bf_w1 + 12288;

    f32x4 acc[2][8];
#pragma unroll
    for (int t = 0; t < 2; ++t)
#pragma unroll
        for (int n = 0; n < 8; ++n) acc[t][n] = (f32x4){0.f, 0.f, 0.f, 0.f};

    short8 afA[2], afB[2];
    LOADA(afA, apH, 0);
    __builtin_amdgcn_sched_barrier(0);
    STAGE(ph0, 0);
    PCH(afA, afB, apH, 1, 0, ph1, 1, 4, 1, 1);
    PCH(afB, afA, apH, 2, 1, ph2, 0, 4, 1, 1);
    PCH(afA, afB, apH, 3, 0, ph3, 1, 4, 1, 1);
    PCH(afB, afA, apA, 0, 1, pa0, 0, 4, 1, 1);
    PCH(afA, afB, apA, 1, 0, pa1, 1, 4, 1, 1);
    PCH(afB, afA, apA, 2, 1, pa2, 0, 4, 1, 1);
    PCH(afA, afB, apA, 3, 0, pa3, 1, 4, 1, 1);
    PCH(afB, afA, apA, 3, 1, w0c0, 0, 2, 0, 1);   // last P-chunk: no next-A -> vmcnt(2)
    EPI_PROJ();
    XCHUNK(0, 0, 1, w0c1, 1, 2);
    XCHUNK(1, 1, 1, w0c2, 0, 2);
    XCHUNK(2, 0, 1, w0c3, 1, 2);
    XCHUNK(3, 1, 1, w1c0, 0, 2);
    EPI_LN(b0v, g0v, be0v);
    XCHUNK(0, 0, 1, w1c1, 1, 2);
    XCHUNK(1, 1, 1, w1c2, 0, 2);
    XCHUNK(2, 0, 1, w1c3, 1, 2);
    XCHUNK(3, 1, 0, w1c3, 0, 0);
    EPI_LN(b1v, g1v, be1v);

    __syncthreads();
#pragma unroll
    for (int it = 0; it < 8; ++it) {
        int idx  = it * 256 + tid;
        int lrow = idx >> 4;
        int c8   = (idx & 15) << 3;
        int grow = row0 + lrow;
        if (grow < rows) {
            size_t goff = (size_t)grow * 128 + c8;
            short8 xv = *(const short8*)(lds_x + lrow * XSTRIDE + c8);
            short8 hv = *(const short8*)(h + goff);
            short8 yv;
#pragma unroll
            for (int j = 0; j < 8; ++j)
                yv[j] = (short)f2b(b2f((ushort_t)hv[j]) + b2f((ushort_t)xv[j]));
            *(short8*)(h + goff) = yv;
        }
    }
}

extern "C" void kernel_launch(void* const* d_in, const int* in_sizes, int n_in,
                              void* d_out, int out_size, void* d_ws, size_t ws_size,
                              hipStream_t stream) {
    const void* nodes        = d_in[0];
    const void* edges        = d_in[1];
    const int*  senders      = (const int*)d_in[2];
    const int*  receivers    = (const int*)d_in[3];
    const void* w_node_emb   = d_in[4];
    const void* b_node_emb   = d_in[5];
    const void* w_edge_emb   = d_in[6];
    const void* b_edge_emb   = d_in[7];
    const void* edge_proj_w  = d_in[8];
    const void* edge_proj_b  = d_in[9];
    const void* node_proj_w  = d_in[10];
    const void* node_proj_b  = d_in[11];
    const void* edge_mlp_w   = d_in[12];
    const void* edge_mlp_b   = d_in[13];
    const void* edge_ln_g    = d_in[14];
    const void* edge_ln_b    = d_in[15];
    const void* node_mlp_w   = d_in[16];
    const void* node_mlp_b   = d_in[17];
    const void* node_ln_g    = d_in[18];
    const void* node_ln_b    = d_in[19];
    const void* mlp_out_w    = d_in[20];
    const void* mlp_out_b    = d_in[21];
    const void* mlp_out_g    = d_in[22];
    const void* mlp_out_beta = d_in[23];
    const void* proj_w       = d_in[24];
    const void* proj_b       = d_in[25];

    char* ws = (char*)d_ws;
    ushort_t* bf_nodeemb  = (ushort_t*)ws;  ws += (size_t)288 * 128 * 2;   // frag arena start
    ushort_t* bf_edgeproj = (ushort_t*)ws;  ws += (size_t)768 * 128 * 2;
    ushort_t* bf_nodeproj = (ushort_t*)ws;  ws += (size_t)512 * 128 * 2;
    ushort_t* bf_edgemlp  = (ushort_t*)ws;  ws += (size_t)512 * 128 * 2;
    ushort_t* bf_nodemlp  = (ushort_t*)ws;  ws += (size_t)512 * 128 * 2;
    ushort_t* bf_mlpout   = (ushort_t*)ws;  ws += (size_t)128 * 128 * 2;
    ushort_t* h    = (ushort_t*)ws;         ws += (size_t)N_NODES * D * 2;
    ushort_t* e    = (ushort_t*)ws;         ws += (size_t)N_EDGES * D * 2;
    ushort_t* agg  = (ushort_t*)ws;         ws += (size_t)N_NODES * D * 2;
    int*      cnti = (int*)ws;              ws += (size_t)N_NODES * 4;
    int*      offs = (int*)ws;              ws += (size_t)N_NODES * 4;
    int*      curs = (int*)ws;              ws += (size_t)N_NODES * 4;
    int*      eid  = (int*)ws;              ws += (size_t)N_EDGES * 4;
    int*      flag = (int*)ws;              ws += 256;
    ushort_t* bvec = (ushort_t*)ws;         ws += (size_t)37 * 128 * 2;   // bf16 bias arena (+DMA overread pad)
    ushort_t* wT   = (ushort_t*)ws;         ws += (size_t)24 * 128 * 2;   // projT bf16

    hipMemsetAsync(flag, 0, 256, stream);
    k_detect<<<256, 256, 0, stream>>>((const uint32_t*)nodes, flag);

    // consolidated setup (bias packs + projT + all 6 B-fragment transforms in one launch)
    // bvec slots: 0 b_node_emb | 1 b_edge_emb | 2,3 edge_proj_b | 4,5 node_proj_b | 6..9 edge_mlp_b
    // 10..13 edge_ln_g | 14..17 edge_ln_b | 18..21 node_mlp_b | 22..25 node_ln_g
    // 26..29 node_ln_b | 30 mlp_out_b | 31 mlp_out_g | 32 mlp_out_beta
    // 33,34 w_edge_emb | 35 b_edge_emb (wedge table, contiguous for LDS-DMA) | 36 pad
    {
        SetupArgs sa;
        const void* ps[15] = { b_node_emb, b_edge_emb, edge_proj_b, node_proj_b,
                               edge_mlp_b, edge_ln_g, edge_ln_b,
                               node_mlp_b, node_ln_g, node_ln_b,
                               mlp_out_b, mlp_out_g, mlp_out_beta,
                               w_edge_emb, b_edge_emb };
        const int   pn[15] = { 128, 128, 256, 256, 512, 512, 512, 512, 512, 512, 128, 128, 128, 256, 128 };
        const int   pd[15] = { 0, 1, 2, 4, 6, 10, 14, 18, 22, 26, 30, 31, 32, 33, 35 };
        const void* fs[6]  = { w_node_emb, edge_proj_w, node_proj_w, edge_mlp_w, node_mlp_w, mlp_out_w };
        const int   fk[6]  = { 9, 24, 16, 16, 16, 4 };
        const int   fd[6]  = { 0, 36864, 135168, 200704, 266240, 331776 };  // ushort offsets, contiguous arena
        for (int i = 0; i < 15; ++i) { sa.psrc[i] = ps[i]; sa.pn[i] = pn[i]; sa.pdst[i] = pd[i]; }
        for (int i = 0; i < 6;  ++i) { sa.fsrc[i] = fs[i]; sa.fkb[i] = fk[i]; sa.fdst[i] = fd[i]; }
        sa.projw = proj_w;
        // total threads: 4608 (packs) + 3072 (projT) + 43520 (bfrag) = 51200 -> 200 blocks
        k_setup<<<200, 256, 0, stream>>>(sa, bvec, bf_nodeemb, wT, flag);
    }

    // CSR build (receivers constant across both layers)
    hipMemsetAsync(cnti, 0, (size_t)N_NODES * 4, stream);
    k_counti<<<(N_EDGES + 255) / 256, 256, 0, stream>>>(receivers, cnti, N_EDGES);
    k_scan<<<1, 1024, 0, stream>>>(cnti, offs, curs);
    k_fill<<<(N_EDGES + 255) / 256, 256, 0, stream>>>(receivers, curs, eid, N_EDGES);

    {
        const int grid = (N_NODES + 127) / 128;
        k_gemm<3, false><<<grid, 256, 0, stream>>>(
            bf_nodeemb,
            nodes, 1, 288, 0,   128,
            nodes, 1, 288, 128, 128,
            nodes, 1, 288, 256, 32,
            N_NODES, bvec + 0 * 128, nullptr, nullptr, h, flag);
    }

    const int gridE = N_EDGES / 128;           // 2500
    const int gridN = (N_NODES + 127) / 128;   // 157

    for (int l = 0; l < 2; ++l) {
        if (l == 0) {
            k_edge_fused<1><<<gridE, 256, 0, stream>>>(
                bf_edgeproj,
                bf_edgemlp + (size_t)0 * 128 * 128,
                bf_edgemlp + (size_t)1 * 128 * 128,
                e, h, senders, receivers,
                edges, bvec + 33 * 128,
                bvec + 2 * 128,
                bvec + 6 * 128,  bvec + 10 * 128, bvec + 14 * 128,
                bvec + 7 * 128,  bvec + 11 * 128, bvec + 15 * 128,
                flag);
        } else {
            k_edge_fused<0><<<gridE, 256, 0, stream>>>(
                bf_edgeproj + (size_t)384 * 128,
                bf_edgemlp + (size_t)2 * 128 * 128,
                bf_edgemlp + (size_t)3 * 128 * 128,
                e, h, senders, receivers,
                edges, bvec + 33 * 128,
                bvec + 3 * 128,
                bvec + 8 * 128,  bvec + 12 * 128, bvec + 16 * 128,
                bvec + 9 * 128,  bvec + 13 * 128, bvec + 17 * 128,
                flag);
        }
        k_agg<<<(N_NODES + 7) / 8, 256, 0, stream>>>(e, offs, cnti, eid, agg);
        k_node_fused<<<gridN, 256, 0, stream>>>(
            bf_nodeproj + (size_t)l * 256 * 128,
            bf_nodemlp + (size_t)(l * 2 + 0) * 128 * 128,
            bf_nodemlp + (size_t)(l * 2 + 1) * 128 * 128,
            h, agg,
            bvec + (size_t)(4 + l) * 128,
            bvec + (size_t)(18 + l * 2) * 128,     bvec + (size_t)(22 + l * 2) * 128,     bvec + (size_t)(26 + l * 2) * 128,
            bvec + (size_t)(18 + l * 2 + 1) * 128, bvec + (size_t)(22 + l * 2 + 1) * 128, bvec + (size_t)(26 + l * 2 + 1) * 128,
            N_NODES);
    }

    // fused: mlp_out GEMM + gelu + LN + projection straight to d_out
    k_out<<<gridN, 256, 0, stream>>>(
        bf_mlpout, h,
        bvec + 30 * 128, bvec + 31 * 128, bvec + 32 * 128,
        wT, proj_b, d_out, N_NODES, flag);
}

// Round 15
// 548.665 us; speedup vs baseline: 1.4909x; 1.0124x over previous
//
#include <hip/hip_runtime.h>
#include <hip/hip_bf16.h>
#include <stdint.h>

typedef unsigned short ushort_t;
typedef __attribute__((ext_vector_type(8))) short short8;
typedef __attribute__((ext_vector_type(4))) short short4v;
typedef __attribute__((ext_vector_type(4))) float f32x4;
typedef __attribute__((ext_vector_type(4))) int int4v;

#define N_NODES 20000
#define N_EDGES 320000
#define D 128
#define XSTRIDE 136   // padded LDS row stride (ushorts)

#define GAS __attribute__((address_space(1)))
#define LAS __attribute__((address_space(3)))

__device__ __forceinline__ float b2f(ushort_t u) {
    union { float f; uint32_t i; } v; v.i = ((uint32_t)u) << 16; return v.f;
}
// native RNE f32->bf16 (bit-identical to integer-trick RNE); compiler pairs adjacent
// casts into v_cvt_pk_bf16_f32
__device__ __forceinline__ ushort_t f2b(float f) {
    __bf16 h = (__bf16)f;
    return __builtin_bit_cast(ushort_t, h);
}
// dtype-flexible scalar load: raw input arrays may be f32 or bf16 (runtime-detected)
__device__ __forceinline__ float ldf(const void* p, size_t i, bool f32) {
    return f32 ? ((const float*)p)[i] : b2f(((const ushort_t*)p)[i]);
}
// dtype-flexible 8-element A-fragment load (8 consecutive elements, 8-aligned index)
__device__ __forceinline__ short8 lda8(const void* p, size_t i, bool f32) {
    if (f32) {
        const float* fp = (const float*)p + i;
        f32x4 v0 = *(const f32x4*)fp;
        f32x4 v1 = *(const f32x4*)(fp + 4);
        short8 a;
#pragma unroll
        for (int j = 0; j < 4; ++j) {
            a[j]     = (short)f2b(v0[j]);
            a[j + 4] = (short)f2b(v1[j]);
        }
        return a;
    }
    return *(const short8*)((const ushort_t*)p + i);
}
// tanh-gelu with fast reciprocal (v_rcp_f32, ~1ulp) instead of full-precision division
__device__ __forceinline__ float gelu_tanh(float x) {
    float u = 0.7978845608028654f * (x + 0.044715f * x * x * x);
    u = fminf(fmaxf(u, -15.f), 15.f);
    float e = __expf(2.f * u);
    float t = (e - 1.f) * __builtin_amdgcn_rcpf(e + 1.f);
    return 0.5f * x * (1.f + t);
}
__device__ __forceinline__ int clampi(int v, int hi) {  // [0, hi)
    return v < 0 ? 0 : (v >= hi ? hi - 1 : v);
}
// async 16B global->LDS (linear dest, lane-ordered — matches wave-uniform-base+lane*16)
__device__ __forceinline__ void gload_lds16(const void* g, void* l) {
    __builtin_amdgcn_global_load_lds((const GAS uint32_t*)g, (LAS uint32_t*)l, 16, 0, 0);
}
// dual-dtype edge row load (2 scalars)
__device__ __forceinline__ void ldedge(const void* edges, int row, bool f32, float& a0, float& a1) {
    if (f32) {
        const float* p = (const float*)edges + (size_t)row * 2;
        a0 = p[0]; a1 = p[1];
    } else {
        const ushort_t* p = (const ushort_t*)edges + (size_t)row * 2;
        a0 = b2f(p[0]); a1 = b2f(p[1]);
    }
}
// e_init fragment: 8 consecutive cols of a0*w0 + a1*w1 + b from the wedge LDS table
__device__ __forceinline__ short8 einit8(const ushort_t* wedge, int colbase, float a0, float a1) {
    short8 w0 = *(const short8*)(wedge + colbase);
    short8 w1 = *(const short8*)(wedge + 128 + colbase);
    short8 bb = *(const short8*)(wedge + 256 + colbase);
    short8 r;
#pragma unroll
    for (int j = 0; j < 8; ++j)
        r[j] = (short)f2b(a0 * b2f((ushort_t)w0[j]) + a1 * b2f((ushort_t)w1[j]) + b2f((ushort_t)bb[j]));
    return r;
}

// row-wise LN over 128 cols spread as x[n] on 16 lanes (same quad group)
__device__ __forceinline__ void ln8(float x[8], const float gv[8], const float bv[8]) {
    float s1 = 0.f, s2 = 0.f;
#pragma unroll
    for (int n = 0; n < 8; ++n) { s1 += x[n]; s2 += x[n] * x[n]; }
#pragma unroll
    for (int m = 1; m < 16; m <<= 1) {
        s1 += __shfl_xor(s1, m, 64);
        s2 += __shfl_xor(s2, m, 64);
    }
    float mean = s1 * (1.f / 128.f);
    float var  = fmaxf(s2 * (1.f / 128.f) - mean * mean, 0.f);
    float rs   = __builtin_amdgcn_rsqf(var + 1e-5f);
#pragma unroll
    for (int n = 0; n < 8; ++n) x[n] = (x[n] - mean) * rs * gv[n] + bv[n];
}

// Detect whether float inputs are f32 (flag=1) or bf16 (flag=0).
__global__ void k_detect(const uint32_t* __restrict__ raw, int* __restrict__ flag) {
    int t = blockIdx.x * blockDim.x + threadIdx.x;   // 65536 threads
    uint32_t u = raw[t];
    int e_lo = (u >> 7)  & 0xFF;
    int e_hi = (u >> 23) & 0xFF;
    if (e_lo == 0xFF || e_hi == 0xFF) atomicOr(flag, 1);
}

// ---------------- consolidated setup: bias packs + projT + all B-fragment transforms ----------------
struct SetupArgs {
    const void* psrc[15];
    int         pn[15];
    int         pdst[15];
    const void* fsrc[6];
    int         fkb[6];
    int         fdst[6];     // dst offset into frag arena (ushort units)
    const void* projw;
};

__global__ void k_setup(SetupArgs a, ushort_t* __restrict__ bvec, ushort_t* __restrict__ frag,
                        ushort_t* __restrict__ wT, const int* __restrict__ dflag) {
    const bool f32 = *dflag != 0;
    int t = blockIdx.x * blockDim.x + threadIdx.x;
    if (t < 4608) {                      // bias packs
        int i = t, d = 0;
        while (i >= a.pn[d]) { i -= a.pn[d]; ++d; }
        bvec[(size_t)a.pdst[d] * 128 + i] = f2b(ldf(a.psrc[d], i, f32));
        return;
    }
    t -= 4608;
    if (t < 3072) {                      // projT
        int p = t >> 7, k = t & 127;
        wT[p * 128 + k] = f2b(ldf(a.projw, (size_t)k * 24 + p, f32));
        return;
    }
    t -= 3072;
    if (t >= 43520) return;              // bfrag region: sum(fkb)=85 -> 85*512 groups
    int g = t, d = 0;
    while (g >= a.fkb[d] * 512) { g -= a.fkb[d] * 512; ++d; }
    const void* src = a.fsrc[d];
    int kblk = g >> 9;
    int rem  = g & 511;
    int nt   = rem >> 6;
    int lane = rem & 63;
    int krow = kblk * 32 + ((lane >> 4) << 3);
    int col  = nt * 16 + (lane & 15);
    short8 v;
#pragma unroll
    for (int j = 0; j < 8; ++j) v[j] = (short)f2b(ldf(src, (size_t)(krow + j) * 128 + col, f32));
    *(short8*)(frag + (size_t)a.fdst[d] + (size_t)g * 8) = v;
}

// ---------------- CSR build for receiver-side aggregation ----------------
__global__ void k_counti(const int* __restrict__ recv, int* __restrict__ cnti, int E) {
    int i = blockIdx.x * blockDim.x + threadIdx.x;
    if (i < E) atomicAdd(&cnti[clampi(recv[i], N_NODES)], 1);
}

// single-block exclusive scan of cnti -> offs (and cursor copy)
__global__ void k_scan(const int* __restrict__ cnti, int* __restrict__ offs,
                       int* __restrict__ cursor) {
    __shared__ int part[1024];
    const int t = threadIdx.x;           // blockDim = 1024
    const int base = t * 20;             // 1024*20 = 20480 >= N_NODES
    int s = 0;
#pragma unroll 4
    for (int j = 0; j < 20; ++j) {
        int idx = base + j;
        if (idx < N_NODES) s += cnti[idx];
    }
    part[t] = s;
    __syncthreads();
    for (int off = 1; off < 1024; off <<= 1) {
        int v = (t >= off) ? part[t - off] : 0;
        __syncthreads();
        part[t] += v;
        __syncthreads();
    }
    int run = (t == 0) ? 0 : part[t - 1];   // exclusive prefix
    for (int j = 0; j < 20; ++j) {
        int idx = base + j;
        if (idx < N_NODES) {
            offs[idx]   = run;
            cursor[idx] = run;
            run += cnti[idx];
        }
    }
}

__global__ void k_fill(const int* __restrict__ recv, int* __restrict__ cursor,
                       int* __restrict__ eid, int E) {
    int i = blockIdx.x * blockDim.x + threadIdx.x;
    if (i < E) {
        int r = clampi(recv[i], N_NODES);
        int pos = atomicAdd(&cursor[r], 1);
        eid[pos] = i;
    }
}

// gather-mean aggregation: agg[n] = mean over incident edges of e[eid] (bf16 out)
// 8-way unrolled: 8 independent eid loads + 8 independent row gathers in flight
// (deg ~ Poisson(16) -> ~2 latency rounds instead of 4 at 4-way)
__global__ void k_agg(const ushort_t* __restrict__ e, const int* __restrict__ offs,
                      const int* __restrict__ cnti, const int* __restrict__ eid,
                      ushort_t* __restrict__ agg) {
    const int tid = threadIdx.x;
    const int n = blockIdx.x * 8 + (tid >> 5);   // 8 nodes / 256-thread block
    const int l = tid & 31;                      // 32 lanes x 4 cols = 128 cols
    if (n >= N_NODES) return;
    const int start = offs[n], deg = cnti[n];
    float s0 = 0.f, s1 = 0.f, s2 = 0.f, s3 = 0.f;
    int j = 0;
    for (; j + 8 <= deg; j += 8) {
        int ii[8];
#pragma unroll
        for (int u = 0; u < 8; ++u) ii[u] = eid[start + j + u];
        short4v vv[8];
#pragma unroll
        for (int u = 0; u < 8; ++u) vv[u] = *(const short4v*)(e + (size_t)ii[u] * 128 + l * 4);
#pragma unroll
        for (int u = 0; u < 8; ++u) {
            s0 += b2f((ushort_t)vv[u][0]);
            s1 += b2f((ushort_t)vv[u][1]);
            s2 += b2f((ushort_t)vv[u][2]);
            s3 += b2f((ushort_t)vv[u][3]);
        }
    }
    for (; j < deg; ++j) {
        const ushort_t* row = e + (size_t)eid[start + j] * 128 + l * 4;
        short4v v = *(const short4v*)row;
        s0 += b2f((ushort_t)v[0]);
        s1 += b2f((ushort_t)v[1]);
        s2 += b2f((ushort_t)v[2]);
        s3 += b2f((ushort_t)v[3]);
    }
    const float inv = 1.f / (float)(deg < 1 ? 1 : deg);
    short4v o;
    o[0] = (short)f2b(s0 * inv);
    o[1] = (short)f2b(s1 * inv);
    o[2] = (short)f2b(s2 * inv);
    o[3] = (short)f2b(s3 * inv);
    *(short4v*)(agg + (size_t)n * 128 + l * 4) = o;
}

// ---------------- generic GEMM (node embedding) ----------------
template<int NC, bool LN>
__global__ __launch_bounds__(256, 2) void k_gemm(
    const ushort_t* __restrict__ bfrag,
    const void* s0, int isf0, int st0, int ko0, int kl0,
    const void* s1, int isf1, int st1, int ko1, int kl1,
    const void* s2, int isf2, int st2, int ko2, int kl2,
    int rows,
    const ushort_t* __restrict__ bias,
    const ushort_t* __restrict__ gamma,
    const ushort_t* __restrict__ betap,
    ushort_t* out,
    const int* __restrict__ dflag)
{
    __shared__ __align__(16) ushort_t lds_b[128 * 128];
    const bool f32g = *dflag != 0;
    const int tid  = threadIdx.x;
    const int wave = tid >> 6, lane = tid & 63;
    const int quad = lane >> 4, l16 = lane & 15;
    const int row0 = blockIdx.x * 128 + wave * 32;

    f32x4 acc[2][8];
#pragma unroll
    for (int t = 0; t < 2; ++t)
#pragma unroll
        for (int n = 0; n < 8; ++n) acc[t][n] = (f32x4){0.f, 0.f, 0.f, 0.f};

    const ushort_t* bptr = bfrag;
#pragma unroll
    for (int c = 0; c < NC; ++c) {
        const void* src  = (c == 0) ? s0 : ((c == 1) ? s1 : s2);
        const bool  eff  = (((c == 0) ? isf0 : ((c == 1) ? isf1 : isf2)) != 0) && f32g;
        const int stride = (c == 0) ? st0 : ((c == 1) ? st1 : st2);
        const int koff   = (c == 0) ? ko0 : ((c == 1) ? ko1 : ko2);
        const int klen   = (c == 0) ? kl0 : ((c == 1) ? kl1 : kl2);

        if (c) __syncthreads();
        {
            const int ngrp = klen * 16;
            for (int g = tid; g < ngrp; g += 256)
                gload_lds16(bptr + (size_t)g * 8, lds_b + (size_t)g * 8);
        }
        __syncthreads();   // full drain: staging resident

        size_t aoff[2];
#pragma unroll
        for (int t = 0; t < 2; ++t) {
            int r  = row0 + t * 16 + l16;
            int rr = r < rows ? r : rows - 1;
            aoff[t] = (size_t)rr * stride + koff + quad * 8;
        }
        const int ksteps = klen >> 5;
        for (int ks = 0; ks < ksteps; ++ks) {
            short8 af[2];
#pragma unroll
            for (int t = 0; t < 2; ++t)
                af[t] = lda8(src, aoff[t] + ks * 32, eff);
#pragma unroll
            for (int n = 0; n < 8; ++n) {
                short8 bf = *(const short8*)(lds_b + (size_t)((ks * 8 + n) * 64 + lane) * 8);
                acc[0][n] = __builtin_amdgcn_mfma_f32_16x16x32_bf16(af[0], bf, acc[0][n], 0, 0, 0);
                acc[1][n] = __builtin_amdgcn_mfma_f32_16x16x32_bf16(af[1], bf, acc[1][n], 0, 0, 0);
            }
        }
        bptr += (size_t)klen * 128;
    }

    float bv[8], gv[8], btv[8];
#pragma unroll
    for (int n = 0; n < 8; ++n) {
        int col = n * 16 + l16;
        bv[n] = b2f(bias[col]);
        if (LN) { gv[n] = b2f(gamma[col]); btv[n] = b2f(betap[col]); }
    }
#pragma unroll
    for (int t = 0; t < 2; ++t) {
#pragma unroll
        for (int r = 0; r < 4; ++r) {
            int row = row0 + t * 16 + quad * 4 + r;
            float x[8];
#pragma unroll
            for (int n = 0; n < 8; ++n) x[n] = acc[t][n][r] + bv[n];
            if (LN) {
#pragma unroll
                for (int n = 0; n < 8; ++n) x[n] = gelu_tanh(x[n]);
                ln8(x, gv, btv);
            }
            if (row < rows) {
#pragma unroll
                for (int n = 0; n < 8; ++n)
                    out[(size_t)row * 128 + n * 16 + l16] = f2b(x[n]);
            }
        }
    }
}

// ---------------- fused output: mlp_out GEMM + gelu + LN + projection to d_out ----------------
__global__ __launch_bounds__(256, 2) void k_out(
    const ushort_t* __restrict__ bfrag,     // bf_mlpout
    const ushort_t* __restrict__ h,
    const ushort_t* __restrict__ bias,
    const ushort_t* __restrict__ gamma,
    const ushort_t* __restrict__ betap,
    const ushort_t* __restrict__ wT,        // [24][128] bf16
    const void* __restrict__ pb,            // proj_b raw
    void* __restrict__ out, int rows,
    const int* __restrict__ dflag)
{
    __shared__ __align__(16) ushort_t lds_b[128 * 128];
    __shared__ __align__(16) ushort_t lds_x[128 * XSTRIDE];
    const bool f32g = *dflag != 0;
    const int tid  = threadIdx.x;
    const int wave = tid >> 6, lane = tid & 63;
    const int quad = lane >> 4, l16 = lane & 15;
    const int row0  = blockIdx.x * 128;
    const int lrow0 = wave * 32;

    for (int g = tid; g < 2048; g += 256)
        gload_lds16(bfrag + (size_t)g * 8, lds_b + (size_t)g * 8);
    __syncthreads();

    f32x4 acc[2][8];
#pragma unroll
    for (int t = 0; t < 2; ++t)
#pragma unroll
        for (int n = 0; n < 8; ++n) acc[t][n] = (f32x4){0.f, 0.f, 0.f, 0.f};

    const ushort_t* ap[2];
#pragma unroll
    for (int t = 0; t < 2; ++t) {
        int grow = row0 + lrow0 + t * 16 + l16;
        int rr = grow < rows ? grow : rows - 1;
        ap[t] = h + (size_t)rr * 128 + quad * 8;
    }
    for (int ks = 0; ks < 4; ++ks) {
        short8 af[2];
#pragma unroll
        for (int t = 0; t < 2; ++t) af[t] = *(const short8*)(ap[t] + ks * 32);
#pragma unroll
        for (int n = 0; n < 8; ++n) {
            short8 bf = *(const short8*)(lds_b + (size_t)((ks * 8 + n) * 64 + lane) * 8);
            acc[0][n] = __builtin_amdgcn_mfma_f32_16x16x32_bf16(af[0], bf, acc[0][n], 0, 0, 0);
            acc[1][n] = __builtin_amdgcn_mfma_f32_16x16x32_bf16(af[1], bf, acc[1][n], 0, 0, 0);
        }
    }

    {
        float bv[8], gv[8], btv[8];
#pragma unroll
        for (int n = 0; n < 8; ++n) {
            int col = n * 16 + l16;
            bv[n] = b2f(bias[col]); gv[n] = b2f(gamma[col]); btv[n] = b2f(betap[col]);
        }
#pragma unroll
        for (int t = 0; t < 2; ++t)
#pragma unroll
            for (int r = 0; r < 4; ++r) {
                int lrow = lrow0 + t * 16 + quad * 4 + r;
                float x[8];
#pragma unroll
                for (int n = 0; n < 8; ++n) x[n] = gelu_tanh(acc[t][n][r] + bv[n]);
                ln8(x, gv, btv);
#pragma unroll
                for (int n = 0; n < 8; ++n)
                    lds_x[lrow * XSTRIDE + n * 16 + l16] = f2b(x[n]);
            }
    }
    __syncthreads();

    // projection: 128 rows x 24 outputs = 3072 -> 12 per thread
#pragma unroll
    for (int it = 0; it < 12; ++it) {
        int idx  = it * 256 + tid;
        int lrow = idx / 24;
        int p    = idx - lrow * 24;
        int grow = row0 + lrow;
        if (grow < rows) {
            float a2 = ldf(pb, p, f32g);
            const ushort_t* xp = lds_x + lrow * XSTRIDE;
            const ushort_t* wp = wT + (size_t)p * 128;
#pragma unroll
            for (int k8 = 0; k8 < 16; ++k8) {
                short8 hv = *(const short8*)(xp + k8 * 8);
                short8 wv = *(const short8*)(wp + k8 * 8);
#pragma unroll
                for (int j = 0; j < 8; ++j)
                    a2 += b2f((ushort_t)hv[j]) * b2f((ushort_t)wv[j]);
            }
            if (f32g) ((float*)out)[(size_t)grow * 24 + p] = a2;
            else      ((ushort_t*)out)[(size_t)grow * 24 + p] = f2b(a2);
        }
    }
}

// ======== BK=32 chunked double-buffered pipeline (3 blocks/CU) ========
// Chunk = 32-K slice = 8 KB of B-fragments in lds_w[buf]. A-fragments prefetched one
// chunk ahead. Steady-state per-wave vmcnt ledger:
//   [af_cur(2), stage_cur(2), af_next(2), stage_next(2)] -> vmcnt(4)
// boundary chunks (no next-A): vmcnt(2); last X chunk: vmcnt(0).
// T5 setprio kept (measured neutral, zero cost).

#define STAGE(srcp, bufi) do {                                                   \
    const ushort_t* s__ = (srcp);                                                \
    _Pragma("unroll")                                                            \
    for (int it__ = 0; it__ < 2; ++it__) {                                       \
        int g__ = it__ * 256 + tid;                                              \
        gload_lds16(s__ + (size_t)g__ * 8, &lds_w[bufi][(size_t)g__ * 8]);       \
    } } while (0)

#define LOADA(dst, apv, kn) do {                                                 \
    _Pragma("unroll") for (int t_ = 0; t_ < 2; ++t_)                             \
        dst[t_] = *(const short8*)(apv[t_] + (kn) * 32);                         \
    } while (0)

#define PCH(AFU, AFN, apv, kn, bufi, nsrc, nbuf, VM, DO_A, DO_STAGE) do {        \
    if (DO_A) LOADA(AFN, apv, kn);                                               \
    __builtin_amdgcn_sched_barrier(0);                                           \
    if (DO_STAGE) STAGE(nsrc, nbuf);                                             \
    asm volatile("s_waitcnt vmcnt(" #VM ")" ::: "memory");                       \
    __builtin_amdgcn_s_barrier();                                                \
    __builtin_amdgcn_sched_barrier(0);                                           \
    __builtin_amdgcn_s_setprio(1);                                               \
    _Pragma("unroll") for (int n_ = 0; n_ < 8; ++n_) {                           \
        short8 bf_ = *(const short8*)(&lds_w[bufi][(size_t)(n_ * 64 + lane) * 8]); \
        acc[0][n_] = __builtin_amdgcn_mfma_f32_16x16x32_bf16(AFU[0], bf_, acc[0][n_], 0, 0, 0); \
        acc[1][n_] = __builtin_amdgcn_mfma_f32_16x16x32_bf16(AFU[1], bf_, acc[1][n_], 0, 0, 0); \
    }                                                                            \
    __builtin_amdgcn_s_setprio(0);                                               \
    __builtin_amdgcn_sched_barrier(0);                                           \
    __builtin_amdgcn_s_barrier();                                                \
} while (0)

#define XCHUNK(kx, bufi, DO_STAGE, nsrc, nbuf, VM) do {                          \
    if (DO_STAGE) STAGE(nsrc, nbuf);                                             \
    asm volatile("s_waitcnt vmcnt(" #VM ")" ::: "memory");                       \
    __builtin_amdgcn_s_barrier();                                                \
    __builtin_amdgcn_sched_barrier(0);                                           \
    {                                                                            \
        short8 af_[2];                                                           \
        _Pragma("unroll") for (int t_ = 0; t_ < 2; ++t_)                         \
            af_[t_] = *(const short8*)(lds_x + (size_t)(lrow0 + t_ * 16 + l16) * XSTRIDE \
                                       + (kx) * 32 + quad * 8);                  \
        __builtin_amdgcn_s_setprio(1);                                           \
        _Pragma("unroll") for (int n_ = 0; n_ < 8; ++n_) {                       \
            short8 bf_ = *(const short8*)(&lds_w[bufi][(size_t)(n_ * 64 + lane) * 8]); \
            acc[0][n_] = __builtin_amdgcn_mfma_f32_16x16x32_bf16(af_[0], bf_, acc[0][n_], 0, 0, 0); \
            acc[1][n_] = __builtin_amdgcn_mfma_f32_16x16x32_bf16(af_[1], bf_, acc[1][n_], 0, 0, 0); \
        }                                                                        \
        __builtin_amdgcn_s_setprio(0);                                           \
    }                                                                            \
    __builtin_amdgcn_sched_barrier(0);                                           \
    __builtin_amdgcn_s_barrier();                                                \
} while (0)

#define EPI_PROJ() do {                                                          \
    _Pragma("unroll") for (int t_ = 0; t_ < 2; ++t_)                             \
    _Pragma("unroll") for (int r_ = 0; r_ < 4; ++r_) {                           \
        int lr_ = lrow0 + t_ * 16 + quad * 4 + r_;                               \
        _Pragma("unroll") for (int n_ = 0; n_ < 8; ++n_)                         \
            lds_x[lr_ * XSTRIDE + n_ * 16 + l16] = f2b(acc[t_][n_][r_] + pbv[n_]); \
    }                                                                            \
    _Pragma("unroll") for (int t_ = 0; t_ < 2; ++t_)                             \
    _Pragma("unroll") for (int n_ = 0; n_ < 8; ++n_) acc[t_][n_] = (f32x4){0.f, 0.f, 0.f, 0.f}; \
} while (0)

#define EPI_LN(BV, GV, BEV) do {                                                 \
    _Pragma("unroll") for (int t_ = 0; t_ < 2; ++t_)                             \
    _Pragma("unroll") for (int r_ = 0; r_ < 4; ++r_) {                           \
        int lr_ = lrow0 + t_ * 16 + quad * 4 + r_;                               \
        float x_[8];                                                             \
        _Pragma("unroll") for (int n_ = 0; n_ < 8; ++n_) x_[n_] = gelu_tanh(acc[t_][n_][r_] + BV[n_]); \
        ln8(x_, GV, BEV);                                                        \
        _Pragma("unroll") for (int n_ = 0; n_ < 8; ++n_)                         \
            lds_x[lr_ * XSTRIDE + n_ * 16 + l16] = f2b(x_[n_]);                  \
    }                                                                            \
    _Pragma("unroll") for (int t_ = 0; t_ < 2; ++t_)                             \
    _Pragma("unroll") for (int n_ = 0; n_ < 8; ++n_) acc[t_][n_] = (f32x4){0.f, 0.f, 0.f, 0.f}; \
} while (0)

// ---------------- fused edge pipeline: [L0: inline e_init] proj(K=384) -> MLP1 -> MLP2 + residual ----------------
template<int L0>
__global__ __launch_bounds__(256, 3) void k_edge_fused(
    const ushort_t* __restrict__ bf_proj,
    const ushort_t* __restrict__ bf_w0,
    const ushort_t* __restrict__ bf_w1,
    ushort_t* e_glob,
    const ushort_t* __restrict__ h,
    const int* __restrict__ senders, const int* __restrict__ receivers,
    const void* __restrict__ edges_raw,        // raw edge features [E][2] (dual-dtype), L0 only
    const ushort_t* __restrict__ wedge_arena,  // bvec slots 33..35: w0[128] w1[128] be[128] bf16
    const ushort_t* __restrict__ pb,
    const ushort_t* __restrict__ b0, const ushort_t* __restrict__ g0, const ushort_t* __restrict__ be0,
    const ushort_t* __restrict__ b1, const ushort_t* __restrict__ g1, const ushort_t* __restrict__ be1,
    const int* __restrict__ dflag)
{
    __shared__ __align__(16) ushort_t lds_w[2][32 * 128];   // 2 x 8 KB
    __shared__ __align__(16) ushort_t lds_x[128 * XSTRIDE];
    __shared__ __align__(16) ushort_t wedge[512];   // 1 KB: w0|w1|be (+overread pad)
    const int tid  = threadIdx.x;
    const int wave = tid >> 6, lane = tid & 63;
    const int quad = lane >> 4, l16 = lane & 15;
    // bijective XCD swizzle (T1): 8 XCDs, grid 2500 (2500 % 8 = 4) — m204 formula.
    // Each XCD gets a contiguous e-row slice -> better per-XCD L2 reuse for the
    // linear e reads/writes; weight arena is L2-resident per XCD either way.
    const int NWG = N_EDGES / 128, q8 = NWG >> 3, r8 = NWG & 7;
    const int xcd = (int)blockIdx.x & 7, bidx = (int)blockIdx.x >> 3;
    const int swz = (xcd < r8) ? (xcd * (q8 + 1) + bidx)
                               : (r8 * (q8 + 1) + (xcd - r8) * q8 + bidx);
    const int row0  = swz * 128;          // 320000 % 128 == 0: all rows valid
    const int lrow0 = wave * 32;
    const bool f32g = L0 ? (*dflag != 0) : false;

    // hoist all epilogue constants so no stray VMEM perturbs vmcnt counting
    float pbv[8], b0v[8], g0v[8], be0v[8], b1v[8], g1v[8], be1v[8];
#pragma unroll
    for (int n = 0; n < 8; ++n) {
        int col = n * 16 + l16;
        pbv[n]  = b2f(pb[col]);
        b0v[n]  = b2f(b0[col]);  g0v[n] = b2f(g0[col]);  be0v[n] = b2f(be0[col]);
        b1v[n]  = b2f(b1[col]);  g1v[n] = b2f(g1[col]);  be1v[n] = b2f(be1[col]);
    }

    // A-source pointers (E-stage pointers only needed for L1)
    const ushort_t* apE[2]; const ushort_t* apS[2]; const ushort_t* apR[2];
#pragma unroll
    for (int t = 0; t < 2; ++t) {
        int grow = row0 + lrow0 + t * 16 + l16;
        apE[t] = e_glob + (size_t)grow * 128 + quad * 8;
        apS[t] = h + (size_t)clampi(senders[grow],   N_NODES) * 128 + quad * 8;
        apR[t] = h + (size_t)clampi(receivers[grow], N_NODES) * 128 + quad * 8;
    }

    // 32-K chunk pointers (8 KB = 4096 ushorts each)
    const ushort_t* pe0 = bf_proj;                const ushort_t* pe1 = bf_proj + 4096;
    const ushort_t* pe2 = bf_proj + 8192;         const ushort_t* pe3 = bf_proj + 12288;
    const ushort_t* ps0 = bf_proj + 16384;        const ushort_t* ps1 = bf_proj + 20480;
    const ushort_t* ps2 = bf_proj + 24576;        const ushort_t* ps3 = bf_proj + 28672;
    const ushort_t* pr0 = bf_proj + 32768;        const ushort_t* pr1 = bf_proj + 36864;
    const ushort_t* pr2 = bf_proj + 40960;        const ushort_t* pr3 = bf_proj + 45056;
    const ushort_t* w0c0 = bf_w0;                 const ushort_t* w0c1 = bf_w0 + 4096;
    const ushort_t* w0c2 = bf_w0 + 8192;          const ushort_t* w0c3 = bf_w0 + 12288;
    const ushort_t* w1c0 = bf_w1;                 const ushort_t* w1c1 = bf_w1 + 4096;
    const ushort_t* w1c2 = bf_w1 + 8192;          const ushort_t* w1c3 = bf_w1 + 12288;

    f32x4 acc[2][8];
#pragma unroll
    for (int t = 0; t < 2; ++t)
#pragma unroll
        for (int n = 0; n < 8; ++n) acc[t][n] = (f32x4){0.f, 0.f, 0.f, 0.f};

    short8 afA[2], afB[2];

    if (L0) {
        // stage wedge table (wave 0: 64 lanes x 16B = 1 KB, overreads into spare slot)
        if (wave == 0)
            gload_lds16(wedge_arena + (size_t)lane * 8, wedge + (size_t)lane * 8);
        // per-lane edge feature loads (2 rows)
        float a0f[2], a1f[2];
#pragma unroll
        for (int t = 0; t < 2; ++t) {
            int grow = row0 + lrow0 + t * 16 + l16;
            ldedge(edges_raw, grow, f32g, a0f[t], a1f[t]);
        }
        asm volatile("s_waitcnt vmcnt(0)" ::: "memory");
        __builtin_amdgcn_s_barrier();
        // compute all four e-chunk A-fragments in registers (no VMEM)
        short8 afE0[2], afE1[2], afE2[2], afE3[2];
#pragma unroll
        for (int t = 0; t < 2; ++t) {
            afE0[t] = einit8(wedge, 0 * 32 + quad * 8, a0f[t], a1f[t]);
            afE1[t] = einit8(wedge, 1 * 32 + quad * 8, a0f[t], a1f[t]);
            afE2[t] = einit8(wedge, 2 * 32 + quad * 8, a0f[t], a1f[t]);
            afE3[t] = einit8(wedge, 3 * 32 + quad * 8, a0f[t], a1f[t]);
        }
        STAGE(pe0, 0);
        // ledger: E0..E2 [S,S]->vmcnt2 | E3 [S,A,S]->vmcnt4 | S0..R2 steady->vmcnt4 | R3 ->vmcnt2
        PCH(afE0, afA, apS, 0, 0, pe1, 1, 2, 0, 1);
        PCH(afE1, afA, apS, 0, 1, pe2, 0, 2, 0, 1);
        PCH(afE2, afA, apS, 0, 0, pe3, 1, 2, 0, 1);
        PCH(afE3, afA, apS, 0, 1, ps0, 0, 4, 1, 1);
        PCH(afA,  afB, apS, 1, 0, ps1, 1, 4, 1, 1);
        PCH(afB,  afA, apS, 2, 1, ps2, 0, 4, 1, 1);
        PCH(afA,  afB, apS, 3, 0, ps3, 1, 4, 1, 1);
        PCH(afB,  afA, apR, 0, 1, pr0, 0, 4, 1, 1);
        PCH(afA,  afB, apR, 1, 0, pr1, 1, 4, 1, 1);
        PCH(afB,  afA, apR, 2, 1, pr2, 0, 4, 1, 1);
        PCH(afA,  afB, apR, 3, 0, pr3, 1, 4, 1, 1);
        PCH(afB,  afA, apR, 3, 1, w0c0, 0, 2, 0, 1);
    } else {
        LOADA(afA, apE, 0);
        __builtin_amdgcn_sched_barrier(0);
        STAGE(pe0, 0);
        PCH(afA, afB, apE, 1, 0, pe1, 1, 4, 1, 1);
        PCH(afB, afA, apE, 2, 1, pe2, 0, 4, 1, 1);
        PCH(afA, afB, apE, 3, 0, pe3, 1, 4, 1, 1);
        PCH(afB, afA, apS, 0, 1, ps0, 0, 4, 1, 1);
        PCH(afA, afB, apS, 1, 0, ps1, 1, 4, 1, 1);
        PCH(afB, afA, apS, 2, 1, ps2, 0, 4, 1, 1);
        PCH(afA, afB, apS, 3, 0, ps3, 1, 4, 1, 1);
        PCH(afB, afA, apR, 0, 1, pr0, 0, 4, 1, 1);
        PCH(afA, afB, apR, 1, 0, pr1, 1, 4, 1, 1);
        PCH(afB, afA, apR, 2, 1, pr2, 0, 4, 1, 1);
        PCH(afA, afB, apR, 3, 0, pr3, 1, 4, 1, 1);
        PCH(afB, afA, apR, 3, 1, w0c0, 0, 2, 0, 1);
    }
    EPI_PROJ();                          // wave-private lds_x; overlaps w0c0 flight
    XCHUNK(0, 0, 1, w0c1, 1, 2);
    XCHUNK(1, 1, 1, w0c2, 0, 2);
    XCHUNK(2, 0, 1, w0c3, 1, 2);
    XCHUNK(3, 1, 1, w1c0, 0, 2);
    EPI_LN(b0v, g0v, be0v);              // MLP1 epilogue; overlaps w1c0 flight
    XCHUNK(0, 0, 1, w1c1, 1, 2);
    XCHUNK(1, 1, 1, w1c2, 0, 2);
    XCHUNK(2, 0, 1, w1c3, 1, 2);
    XCHUNK(3, 1, 0, w1c3, 0, 0);
    EPI_LN(b1v, g1v, be1v);              // final LN -> lds_x

    __syncthreads();
#pragma unroll
    for (int it = 0; it < 8; ++it) {
        int idx  = it * 256 + tid;          // 0..2047 -> 128 rows x 16 chunks
        int lrow = idx >> 4;
        int c8   = (idx & 15) << 3;
        size_t goff = (size_t)(row0 + lrow) * 128 + c8;
        short8 xv = *(const short8*)(lds_x + lrow * XSTRIDE + c8);
        short8 yv;
        if (L0) {
            // residual base = e_init recomputed in f32 (never materialized)
            float ea0, ea1;
            ldedge(edges_raw, row0 + lrow, f32g, ea0, ea1);
            short8 w0 = *(const short8*)(wedge + c8);
            short8 w1 = *(const short8*)(wedge + 128 + c8);
            short8 bb = *(const short8*)(wedge + 256 + c8);
#pragma unroll
            for (int j = 0; j < 8; ++j) {
                float base = ea0 * b2f((ushort_t)w0[j]) + ea1 * b2f((ushort_t)w1[j]) + b2f((ushort_t)bb[j]);
                yv[j] = (short)f2b(base + b2f((ushort_t)xv[j]));
            }
        } else {
            short8 ev = *(const short8*)(e_glob + goff);
#pragma unroll
            for (int j = 0; j < 8; ++j)
                yv[j] = (short)f2b(b2f((ushort_t)ev[j]) + b2f((ushort_t)xv[j]));
        }
        *(short8*)(e_glob + goff) = yv;
    }
}

// ---------------- fused node pipeline: proj(K=256) -> MLP1 -> MLP2 + residual ----------------
__global__ __launch_bounds__(256, 3) void k_node_fused(
    const ushort_t* __restrict__ bf_proj,
    const ushort_t* __restrict__ bf_w0,
    const ushort_t* __restrict__ bf_w1,
    ushort_t* h,
    const ushort_t* __restrict__ agg,
    const ushort_t* __restrict__ pb,
    const ushort_t* __restrict__ b0, const ushort_t* __restrict__ g0, const ushort_t* __restrict__ be0,
    const ushort_t* __restrict__ b1, const ushort_t* __restrict__ g1, const ushort_t* __restrict__ be1,
    int rows)
{
    __shared__ __align__(16) ushort_t lds_w[2][32 * 128];   // 2 x 8 KB
    __shared__ __align__(16) ushort_t lds_x[128 * XSTRIDE];
    const int tid  = threadIdx.x;
    const int wave = tid >> 6, lane = tid & 63;
    const int quad = lane >> 4, l16 = lane & 15;
    const int row0  = blockIdx.x * 128;
    const int lrow0 = wave * 32;

    float pbv[8], b0v[8], g0v[8], be0v[8], b1v[8], g1v[8], be1v[8];
#pragma unroll
    for (int n = 0; n < 8; ++n) {
        int col = n * 16 + l16;
        pbv[n]  = b2f(pb[col]);
        b0v[n]  = b2f(b0[col]);  g0v[n] = b2f(g0[col]);  be0v[n] = b2f(be0[col]);
        b1v[n]  = b2f(b1[col]);  g1v[n] = b2f(g1[col]);  be1v[n] = b2f(be1[col]);
    }

    const ushort_t* apH[2]; const ushort_t* apA[2];
#pragma unroll
    for (int t = 0; t < 2; ++t) {
        int grow = row0 + lrow0 + t * 16 + l16;
        int rr = grow < rows ? grow : rows - 1;
        apH[t] = h   + (size_t)rr * 128 + quad * 8;
        apA[t] = agg + (size_t)rr * 128 + quad * 8;
    }

    const ushort_t* ph0 = bf_proj;            const ushort_t* ph1 = bf_proj + 4096;
    const ushort_t* ph2 = bf_proj + 8192;     const ushort_t* ph3 = bf_proj + 12288;
    const ushort_t* pa0 = bf_proj + 16384;    const ushort_t* pa1 = bf_proj + 20480;
    const ushort_t* pa2 = bf_proj + 24576;    const ushort_t* pa3 = bf_proj + 28672;
    const ushort_t* w0c0 = bf_w0;             const ushort_t* w0c1 = bf_w0 + 4096;
    const ushort_t* w0c2 = bf_w0 + 8192;      const ushort_t* w0c3 = bf_w0 + 12288;
    const ushort_t* w1c0 = bf_w1;             const ushort_t* w1c1 = bf_w1 + 4096;
    const ushort_t* w1c2 = bf_w1 + 8192;      const ushort_t* w1c3 = bf_w1 + 12288;

    f32x4 acc[2][8];
#pragma unroll
    for (int t = 0; t < 2; ++t)
#pragma unroll
        for (int n = 0; n < 8; ++n) acc[t][n] = (f32x4){0.f, 0.f, 0.f, 0.f};

    short8 afA[2], afB[2];
    LOADA(afA, apH, 0);
    __builtin_amdgcn_sched_barrier(0);
    STAGE(ph0, 0);
    PCH(afA, afB, apH, 1, 0, ph1, 1, 4, 1, 1);
    PCH(afB, afA, apH, 2, 1, ph2, 0, 4, 1, 1);
    PCH(afA, afB, apH, 3, 0, ph3, 1, 4, 1, 1);
    PCH(afB, afA, apA, 0, 1, pa0, 0, 4, 1, 1);
    PCH(afA, afB, apA, 1, 0, pa1, 1, 4, 1, 1);
    PCH(afB, afA, apA, 2, 1, pa2, 0, 4, 1, 1);
    PCH(afA, afB, apA, 3, 0, pa3, 1, 4, 1, 1);
    PCH(afB, afA, apA, 3, 1, w0c0, 0, 2, 0, 1);   // last P-chunk: no next-A -> vmcnt(2)
    EPI_PROJ();
    XCHUNK(0, 0, 1, w0c1, 1, 2);
    XCHUNK(1, 1, 1, w0c2, 0, 2);
    XCHUNK(2, 0, 1, w0c3, 1, 2);
    XCHUNK(3, 1, 1, w1c0, 0, 2);
    EPI_LN(b0v, g0v, be0v);
    XCHUNK(0, 0, 1, w1c1, 1, 2);
    XCHUNK(1, 1, 1, w1c2, 0, 2);
    XCHUNK(2, 0, 1, w1c3, 1, 2);
    XCHUNK(3, 1, 0, w1c3, 0, 0);
    EPI_LN(b1v, g1v, be1v);

    __syncthreads();
#pragma unroll
    for (int it = 0; it < 8; ++it) {
        int idx  = it * 256 + tid;
        int lrow = idx >> 4;
        int c8   = (idx & 15) << 3;
        int grow = row0 + lrow;
        if (grow < rows) {
            size_t goff = (size_t)grow * 128 + c8;
            short8 xv = *(const short8*)(lds_x + lrow * XSTRIDE + c8);
            short8 hv = *(const short8*)(h + goff);
            short8 yv;
#pragma unroll
            for (int j = 0; j < 8; ++j)
                yv[j] = (short)f2b(b2f((ushort_t)hv[j]) + b2f((ushort_t)xv[j]));
            *(short8*)(h + goff) = yv;
        }
    }
}

extern "C" void kernel_launch(void* const* d_in, const int* in_sizes, int n_in,
                              void* d_out, int out_size, void* d_ws, size_t ws_size,
                              hipStream_t stream) {
    const void* nodes        = d_in[0];
    const void* edges        = d_in[1];
    const int*  senders      = (const int*)d_in[2];
    const int*  receivers    = (const int*)d_in[3];
    const void* w_node_emb   = d_in[4];
    const void* b_node_emb   = d_in[5];
    const void* w_edge_emb   = d_in[6];
    const void* b_edge_emb   = d_in[7];
    const void* edge_proj_w  = d_in[8];
    const void* edge_proj_b  = d_in[9];
    const void* node_proj_w  = d_in[10];
    const void* node_proj_b  = d_in[11];
    const void* edge_mlp_w   = d_in[12];
    const void* edge_mlp_b   = d_in[13];
    const void* edge_ln_g    = d_in[14];
    const void* edge_ln_b    = d_in[15];
    const void* node_mlp_w   = d_in[16];
    const void* node_mlp_b   = d_in[17];
    const void* node_ln_g    = d_in[18];
    const void* node_ln_b    = d_in[19];
    const void* mlp_out_w    = d_in[20];
    const void* mlp_out_b    = d_in[21];
    const void* mlp_out_g    = d_in[22];
    const void* mlp_out_beta = d_in[23];
    const void* proj_w       = d_in[24];
    const void* proj_b       = d_in[25];

    char* ws = (char*)d_ws;
    ushort_t* bf_nodeemb  = (ushort_t*)ws;  ws += (size_t)288 * 128 * 2;   // frag arena start
    ushort_t* bf_edgeproj = (ushort_t*)ws;  ws += (size_t)768 * 128 * 2;
    ushort_t* bf_nodeproj = (ushort_t*)ws;  ws += (size_t)512 * 128 * 2;
    ushort_t* bf_edgemlp  = (ushort_t*)ws;  ws += (size_t)512 * 128 * 2;
    ushort_t* bf_nodemlp  = (ushort_t*)ws;  ws += (size_t)512 * 128 * 2;
    ushort_t* bf_mlpout   = (ushort_t*)ws;  ws += (size_t)128 * 128 * 2;
    ushort_t* h    = (ushort_t*)ws;         ws += (size_t)N_NODES * D * 2;
    ushort_t* e    = (ushort_t*)ws;         ws += (size_t)N_EDGES * D * 2;
    ushort_t* agg  = (ushort_t*)ws;         ws += (size_t)N_NODES * D * 2;
    int*      cnti = (int*)ws;              ws += (size_t)N_NODES * 4;
    int*      offs = (int*)ws;              ws += (size_t)N_NODES * 4;
    int*      curs = (int*)ws;              ws += (size_t)N_NODES * 4;
    int*      eid  = (int*)ws;              ws += (size_t)N_EDGES * 4;
    int*      flag = (int*)ws;              ws += 256;
    ushort_t* bvec = (ushort_t*)ws;         ws += (size_t)37 * 128 * 2;   // bf16 bias arena (+DMA overread pad)
    ushort_t* wT   = (ushort_t*)ws;         ws += (size_t)24 * 128 * 2;   // projT bf16

    hipMemsetAsync(flag, 0, 256, stream);
    k_detect<<<256, 256, 0, stream>>>((const uint32_t*)nodes, flag);

    // consolidated setup (bias packs + projT + all 6 B-fragment transforms in one launch)
    // bvec slots: 0 b_node_emb | 1 b_edge_emb | 2,3 edge_proj_b | 4,5 node_proj_b | 6..9 edge_mlp_b
    // 10..13 edge_ln_g | 14..17 edge_ln_b | 18..21 node_mlp_b | 22..25 node_ln_g
    // 26..29 node_ln_b | 30 mlp_out_b | 31 mlp_out_g | 32 mlp_out_beta
    // 33,34 w_edge_emb | 35 b_edge_emb (wedge table, contiguous for LDS-DMA) | 36 pad
    {
        SetupArgs sa;
        const void* ps[15] = { b_node_emb, b_edge_emb, edge_proj_b, node_proj_b,
                               edge_mlp_b, edge_ln_g, edge_ln_b,
                               node_mlp_b, node_ln_g, node_ln_b,
                               mlp_out_b, mlp_out_g, mlp_out_beta,
                               w_edge_emb, b_edge_emb };
        const int   pn[15] = { 128, 128, 256, 256, 512, 512, 512, 512, 512, 512, 128, 128, 128, 256, 128 };
        const int   pd[15] = { 0, 1, 2, 4, 6, 10, 14, 18, 22, 26, 30, 31, 32, 33, 35 };
        const void* fs[6]  = { w_node_emb, edge_proj_w, node_proj_w, edge_mlp_w, node_mlp_w, mlp_out_w };
        const int   fk[6]  = { 9, 24, 16, 16, 16, 4 };
        const int   fd[6]  = { 0, 36864, 135168, 200704, 266240, 331776 };  // ushort offsets, contiguous arena
        for (int i = 0; i < 15; ++i) { sa.psrc[i] = ps[i]; sa.pn[i] = pn[i]; sa.pdst[i] = pd[i]; }
        for (int i = 0; i < 6;  ++i) { sa.fsrc[i] = fs[i]; sa.fkb[i] = fk[i]; sa.fdst[i] = fd[i]; }
        sa.projw = proj_w;
        // total threads: 4608 (packs) + 3072 (projT) + 43520 (bfrag) = 51200 -> 200 blocks
        k_setup<<<200, 256, 0, stream>>>(sa, bvec, bf_nodeemb, wT, flag);
    }

    // CSR build (receivers constant across both layers)
    hipMemsetAsync(cnti, 0, (size_t)N_NODES * 4, stream);
    k_counti<<<(N_EDGES + 255) / 256, 256, 0, stream>>>(receivers, cnti, N_EDGES);
    k_scan<<<1, 1024, 0, stream>>>(cnti, offs, curs);
    k_fill<<<(N_EDGES + 255) / 256, 256, 0, stream>>>(receivers, curs, eid, N_EDGES);

    {
        const int grid = (N_NODES + 127) / 128;
        k_gemm<3, false><<<grid, 256, 0, stream>>>(
            bf_nodeemb,
            nodes, 1, 288, 0,   128,
            nodes, 1, 288, 128, 128,
            nodes, 1, 288, 256, 32,
            N_NODES, bvec + 0 * 128, nullptr, nullptr, h, flag);
    }

    const int gridE = N_EDGES / 128;           // 2500
    const int gridN = (N_NODES + 127) / 128;   // 157

    for (int l = 0; l < 2; ++l) {
        if (l == 0) {
            k_edge_fused<1><<<gridE, 256, 0, stream>>>(
                bf_edgeproj,
                bf_edgemlp + (size_t)0 * 128 * 128,
                bf_edgemlp + (size_t)1 * 128 * 128,
                e, h, senders, receivers,
                edges, bvec + 33 * 128,
                bvec + 2 * 128,
                bvec + 6 * 128,  bvec + 10 * 128, bvec + 14 * 128,
                bvec + 7 * 128,  bvec + 11 * 128, bvec + 15 * 128,
                flag);
        } else {
            k_edge_fused<0><<<gridE, 256, 0, stream>>>(
                bf_edgeproj + (size_t)384 * 128,
                bf_edgemlp + (size_t)2 * 128 * 128,
                bf_edgemlp + (size_t)3 * 128 * 128,
                e, h, senders, receivers,
                edges, bvec + 33 * 128,
                bvec + 3 * 128,
                bvec + 8 * 128,  bvec + 12 * 128, bvec + 16 * 128,
                bvec + 9 * 128,  bvec + 13 * 128, bvec + 17 * 128,
                flag);
        }
        k_agg<<<(N_NODES + 7) / 8, 256, 0, stream>>>(e, offs, cnti, eid, agg);
        k_node_fused<<<gridN, 256, 0, stream>>>(
            bf_nodeproj + (size_t)l * 256 * 128,
            bf_nodemlp + (size_t)(l * 2 + 0) * 128 * 128,
            bf_nodemlp + (size_t)(l * 2 + 1) * 128 * 128,
            h, agg,
            bvec + (size_t)(4 + l) * 128,
            bvec + (size_t)(18 + l * 2) * 128,     bvec + (size_t)(22 + l * 2) * 128,     bvec + (size_t)(26 + l * 2) * 128,
            bvec + (size_t)(18 + l * 2 + 1) * 128, bvec + (size_t)(22 + l * 2 + 1) * 128, bvec + (size_t)(26 + l * 2 + 1) * 128,
            N_NODES);
    }

    // fused: mlp_out GEMM + gelu + LN + projection straight to d_out
    k_out<<<gridN, 256, 0, stream>>>(
        bf_mlpout, h,
        bvec + 30 * 128, bvec + 31 * 128, bvec + 32 * 128,
        wT, proj_b, d_out, N_NODES, flag);
}